// Round 5
// baseline (574.212 us; speedup 1.0000x reference)
//
#include <hip/hip_runtime.h>

typedef __bf16 bf16;
typedef __bf16 bf16x8 __attribute__((ext_vector_type(8)));
typedef __bf16 bf16x4 __attribute__((ext_vector_type(4)));
typedef float  f32x4  __attribute__((ext_vector_type(4)));

#define BN_EPS 1e-5f
#define MFMA(a, b, c) __builtin_amdgcn_mfma_f32_16x16x32_bf16((a), (b), (c), 0, 0, 0)

// Fragment-linear offset for MFMA B-operand matrix [N][K] (16x16x32 tiles):
// tile = (k/32)*ntiles + n/16 ; within tile: lane = ((k%32)/8)*16 + n%16, elem = k%8
__device__ __host__ __forceinline__ size_t frag_off(int n, int k, int ntiles) {
  return ((size_t)((k >> 5) * ntiles + (n >> 4)) << 9)
       + (size_t)((((k >> 3) & 3) << 4) + (n & 15)) * 8 + (k & 7);
}

// ---------------- prep kernels ----------------

__global__ void prep_w1main(const float* __restrict__ l1w, const float* __restrict__ l1g, const float* __restrict__ l1v,
                            const float* __restrict__ g1w, const float* __restrict__ g1g, const float* __restrict__ g1v,
                            bf16* __restrict__ W1f) {
  int gid = blockIdx.x * blockDim.x + threadIdx.x;   // 512*1024
  int n = gid >> 10, k = gid & 1023;
  float s, w;
  if (n < 256) { s = l1g[n] * rsqrtf(l1v[n] + BN_EPS); w = l1w[(size_t)n * 1024 + k]; }
  else { int nn = n - 256; s = g1g[nn] * rsqrtf(g1v[nn] + BN_EPS); w = g1w[(size_t)nn * 1024 + k]; }
  W1f[frag_off(n, k, 32)] = (bf16)(w * s);
}

__global__ __launch_bounds__(512)
void prep_w1tail(const float* __restrict__ l1w, const float* __restrict__ l1b, const float* __restrict__ l1g,
                 const float* __restrict__ l1be, const float* __restrict__ l1m, const float* __restrict__ l1v,
                 const float* __restrict__ g1w, const float* __restrict__ g1b, const float* __restrict__ g1g,
                 const float* __restrict__ g1be, const float* __restrict__ g1m, const float* __restrict__ g1v,
                 const float* __restrict__ cw, const float* __restrict__ cb,
                 bf16* __restrict__ W1f, float* __restrict__ b1cat) {
  int n = blockIdx.x;
  int kc = threadIdx.x & 63, js = threadIdx.x >> 6;
  const float* wrow; float s, bb, mm, be;
  if (n < 256) { s = l1g[n] * rsqrtf(l1v[n] + BN_EPS); wrow = l1w + (size_t)n * 1024;
                 bb = l1b[n]; mm = l1m[n]; be = l1be[n]; }
  else { int nn = n - 256; s = g1g[nn] * rsqrtf(g1v[nn] + BN_EPS); wrow = g1w + (size_t)nn * 1024;
         bb = g1b[nn]; mm = g1m[nn]; be = g1be[nn]; }
  float a = 0.f;
  if (kc < 49) {
    #pragma unroll 4
    for (int jj = 0; jj < 128; ++jj) {
      int j = js * 128 + jj;
      float cv = (kc < 48) ? cw[(size_t)j * 48 + kc] : cb[j];
      a += wrow[j] * cv;
    }
  }
  __shared__ float red[8][64];
  red[js][kc] = a;
  __syncthreads();
  if (threadIdx.x < 64) {
    float v = 0.f;
    #pragma unroll
    for (int r = 0; r < 8; ++r) v += red[r][threadIdx.x];
    W1f[frag_off(n, 1024 + threadIdx.x, 32)] = (bf16)((threadIdx.x < 49) ? v * s : 0.f);
  }
  if (threadIdx.x == 0) b1cat[n] = s * (bb - mm) + be;
}

__global__ void prep_w2(const float* __restrict__ l2w, const float* __restrict__ l2b, const float* __restrict__ l2g,
                        const float* __restrict__ l2be, const float* __restrict__ l2m, const float* __restrict__ l2v,
                        const float* __restrict__ g2w, const float* __restrict__ g2b, const float* __restrict__ g2g,
                        const float* __restrict__ g2be, const float* __restrict__ g2m, const float* __restrict__ g2v,
                        bf16* __restrict__ W2f, float* __restrict__ b2sum) {
  int gid = blockIdx.x * blockDim.x + threadIdx.x;   // 1024*512
  int n = gid >> 9, k = gid & 511;
  float w;
  if (k < 256) { float s = l2g[n] * rsqrtf(l2v[n] + BN_EPS); w = l2w[(size_t)n * 256 + k] * s; }
  else { float s = g2g[n] * rsqrtf(g2v[n] + BN_EPS); w = g2w[(size_t)n * 256 + (k - 256)] * s; }
  W2f[frag_off(n, k, 64)] = (bf16)w;
  if (k == 0) {
    float sl = l2g[n] * rsqrtf(l2v[n] + BN_EPS), sg = g2g[n] * rsqrtf(g2v[n] + BN_EPS);
    b2sum[n] = sl * (l2b[n] - l2m[n]) + l2be[n] + sg * (g2b[n] - g2m[n]) + g2be[n];
  }
}

__global__ void prep_cwf(const float* __restrict__ cw, const float* __restrict__ cb, bf16* __restrict__ CWf) {
  int gid = blockIdx.x * blockDim.x + threadIdx.x;   // 1024*64
  int n = gid >> 6, kc = gid & 63;
  float v = (kc < 48) ? cw[(size_t)n * 48 + kc] : (kc == 48 ? cb[n] : 0.f);
  CWf[frag_off(n, kc, 64)] = (bf16)v;
}

__global__ void prep_f1f(const float* __restrict__ fw1, bf16* __restrict__ F1f) {
  int gid = blockIdx.x * blockDim.x + threadIdx.x;   // 256*2048
  int n = gid >> 11, k = gid & 2047;
  F1f[frag_off(n, k, 16)] = (bf16)fw1[(size_t)n * 2048 + k];
}

// ---------------- K1: gemm1 — h = relu(e @ W1catT + b1cat), M=128, N=256 ----------------
// grid 512 = 8 xcd * 64; xcd-paired n-halves so both nb of one (t,mb) share the e-stream in L2.

__global__ __launch_bounds__(1024, 4)
void gemm1(const float* __restrict__ name1, const float* __restrict__ type1, const float* __restrict__ coor1,
           const float* __restrict__ name2, const float* __restrict__ type2, const float* __restrict__ coor2,
           const bf16* __restrict__ W1f, const float* __restrict__ b1cat, bf16* __restrict__ h_ws) {
  const int bid = blockIdx.x;
  const int xcd = bid & 7, slot = bid >> 3;
  const int nb = slot & 1;
  const int lg = xcd * 32 + (slot >> 1);   // 0..255 bijective
  const int tt = lg >> 7;
  const int mb = lg & 127;
  const float* __restrict__ name = tt ? name2 : name1;
  const float* __restrict__ typ  = tt ? type2 : type1;
  const float* __restrict__ coor = tt ? coor2 : coor1;
  const int b0 = mb * 128;
  const int tid = threadIdx.x;
  const int lane = tid & 63;
  const int wv = tid >> 6;           // 0..15
  const int wm = wv >> 2;            // 0..3: 32-row group
  const int wn = wv & 3;             // 0..3: 4 ntiles each
  const int arow = lane & 15;
  const int q = lane >> 4;
  const int kgrp = q << 3;

  __shared__ __align__(16) char SM[67584];
  bf16 (*chunk)[128][40] = reinterpret_cast<bf16 (*)[128][40]>(SM);  // 4 regions, 40,960 B
  bf16 (*hb)[264] = reinterpret_cast<bf16 (*)[264]>(SM);             // overlay after k-loop

  const int srow = tid >> 3;         // 0..127
  const int cq = tid & 7;            // float4 slot within 32-k chunk

  const float4* name4 = reinterpret_cast<const float4*>(name);
  const float4* typ4  = reinterpret_cast<const float4*>(typ);
  const float4* coor4 = reinterpret_cast<const float4*>(coor);

  float4 nr[3], tr[3];
  auto LOADC = [&](int j, int s) {
    if (j < 32) {
      nr[s] = name4[(size_t)(b0 + srow) * 256 + j * 8 + cq];
      tr[s] = typ4[(size_t)(b0 + srow) * 256 + j * 8 + cq];
    } else {                                   // tail: [coor(48) | 1 | 0...]
      int idx = (j - 32) * 8 + cq;
      float4 v;
      if (idx < 12)       v = coor4[(size_t)(b0 + srow) * 12 + idx];
      else if (idx == 12) v = make_float4(1.f, 0.f, 0.f, 0.f);
      else                v = make_float4(0.f, 0.f, 0.f, 0.f);
      nr[s] = v;
      tr[s] = make_float4(0.f, 0.f, 0.f, 0.f);
    }
  };
  auto WRITEC = [&](int j, int s) {
    bf16x4 e;
    e[0] = (bf16)(nr[s].x + tr[s].x); e[1] = (bf16)(nr[s].y + tr[s].y);
    e[2] = (bf16)(nr[s].z + tr[s].z); e[3] = (bf16)(nr[s].w + tr[s].w);
    *reinterpret_cast<bf16x4*>(&chunk[j & 3][srow][cq * 4]) = e;
  };

  LOADC(0, 0); LOADC(1, 1); LOADC(2, 2);

  f32x4 acc[2][4] = {};
  #pragma unroll 1
  for (int j = 0; j < 34; ++j) {
    int s = j % 3;
    WRITEC(j, s);
    if (j + 3 < 34) LOADC(j + 3, s);
    __builtin_amdgcn_sched_barrier(0);
    asm volatile("s_waitcnt lgkmcnt(0)" ::: "memory");
    __builtin_amdgcn_s_barrier();
    __builtin_amdgcn_sched_barrier(0);
    bf16x8 a0 = *reinterpret_cast<const bf16x8*>(&chunk[j & 3][wm * 32 + arow][kgrp]);
    bf16x8 a1 = *reinterpret_cast<const bf16x8*>(&chunk[j & 3][wm * 32 + 16 + arow][kgrp]);
    #pragma unroll
    for (int u = 0; u < 4; ++u) {
      bf16x8 b = *reinterpret_cast<const bf16x8*>(W1f + (((size_t)(j * 32 + nb * 16 + wn * 4 + u)) << 9) + lane * 8);
      acc[0][u] = MFMA(a0, b, acc[0][u]);
      acc[1][u] = MFMA(a1, b, acc[1][u]);
    }
  }
  __syncthreads();   // chunk regions dead; hb overlay begins

  #pragma unroll
  for (int u = 0; u < 4; ++u) {
    int col = (wn * 4 + u) * 16 + arow;
    float bb = b1cat[nb * 256 + col];
    #pragma unroll
    for (int m = 0; m < 2; ++m) {
      #pragma unroll
      for (int i = 0; i < 4; ++i)
        hb[wm * 32 + m * 16 + q * 4 + i][col] = (bf16)fmaxf(acc[m][u][i] + bb, 0.f);
    }
  }
  __syncthreads();

  #pragma unroll
  for (int g = 0; g < 4; ++g) {
    int idx = g * 1024 + tid;
    int row = idx >> 5, cg = idx & 31;
    *reinterpret_cast<bf16x8*>(h_ws + ((size_t)tt * 16384 + b0 + row) * 512 + nb * 256 + cg * 8) =
      *reinterpret_cast<const bf16x8*>(&hb[row][cg * 8]);
  }
}

// ---------------- K2: gemm2 + combine — r = 2e + 2*sigmoid(h@W2T+b2)*(c-e), M=128 ----------------

__global__ __launch_bounds__(512, 4)
void gemm2(const float* __restrict__ name1, const float* __restrict__ type1, const float* __restrict__ coor1,
           const float* __restrict__ name2, const float* __restrict__ type2, const float* __restrict__ coor2,
           const bf16* __restrict__ W2f, const bf16* __restrict__ CWf, const float* __restrict__ b2sum,
           const bf16* __restrict__ h_ws, bf16* __restrict__ r_ws) {
  const int mb = blockIdx.x;           // 0..127
  const int nb = blockIdx.y;           // 0..1 (512-col half)
  const int tt = blockIdx.z;           // 0..1
  const float* __restrict__ name = tt ? name2 : name1;
  const float* __restrict__ typ  = tt ? type2 : type1;
  const float* __restrict__ coor = tt ? coor2 : coor1;
  const int b0 = mb * 128;
  const int tid = threadIdx.x;
  const int lane = tid & 63;
  const int wv = tid >> 6;             // 0..7
  const int wm = wv >> 1;              // 0..3: 32-row group
  const int wn2 = wv & 1;              // 0..1: 32-col group within 64-col chunk
  const int arow = lane & 15;
  const int q = lane >> 4;
  const int kgrp = q << 3;

  __shared__ bf16 Ct[128][72];         // [coor | 1 | 0] : 18,432 B
  __shared__ float xs[128][72];        // wei f32 bounce : 36,864 B
  __shared__ bf16 cs[128][72];         // c bf16 bounce  : 18,432 B   (73,728 total -> 2 blk/CU)

  // stage Ct
  {
    const float4* coor4 = reinterpret_cast<const float4*>(coor);
    int row = tid >> 2, cq = tid & 3;
    #pragma unroll
    for (int v = 0; v < 5; ++v) {
      int c4 = v * 4 + cq;
      if (c4 < 18) {
        float4 cv;
        if (c4 < 12)       cv = coor4[(size_t)(b0 + row) * 12 + c4];
        else if (c4 == 12) cv = make_float4(1.f, 0.f, 0.f, 0.f);
        else               cv = make_float4(0.f, 0.f, 0.f, 0.f);
        bf16x4 e; e[0] = (bf16)cv.x; e[1] = (bf16)cv.y; e[2] = (bf16)cv.z; e[3] = (bf16)cv.w;
        *reinterpret_cast<bf16x4*>(&Ct[row][c4 * 4]) = e;
      }
    }
  }
  __syncthreads();

  const bf16* hbase = h_ws + ((size_t)tt * 16384 + b0) * 512;

  #pragma unroll 1
  for (int nc = 0; nc < 8; ++nc) {     // 8 chunks of 64 cols
    const int ntg0 = nb * 32 + nc * 4 + wn2 * 2;   // global ntile base (of 64)

    // c-tile (K=64 over [coor|1|0])
    f32x4 cacc[2][2] = {};
    #pragma unroll
    for (int j = 0; j < 2; ++j) {
      bf16x8 a0 = *reinterpret_cast<const bf16x8*>(&Ct[wm * 32 + arow][j * 32 + kgrp]);
      bf16x8 a1 = *reinterpret_cast<const bf16x8*>(&Ct[wm * 32 + 16 + arow][j * 32 + kgrp]);
      #pragma unroll
      for (int uu = 0; uu < 2; ++uu) {
        bf16x8 b = *reinterpret_cast<const bf16x8*>(CWf + (((size_t)(j * 64 + ntg0 + uu)) << 9) + lane * 8);
        cacc[0][uu] = MFMA(a0, b, cacc[0][uu]);
        cacc[1][uu] = MFMA(a1, b, cacc[1][uu]);
      }
    }

    // x-tile (K=512 over h, gathered from global; L2-resident after chunk 0)
    f32x4 acc2[2][2] = {};
    #pragma unroll 4
    for (int ks = 0; ks < 16; ++ks) {
      bf16x8 a0 = *reinterpret_cast<const bf16x8*>(hbase + (size_t)(wm * 32 + arow) * 512 + ks * 32 + kgrp);
      bf16x8 a1 = *reinterpret_cast<const bf16x8*>(hbase + (size_t)(wm * 32 + 16 + arow) * 512 + ks * 32 + kgrp);
      #pragma unroll
      for (int uu = 0; uu < 2; ++uu) {
        bf16x8 b = *reinterpret_cast<const bf16x8*>(W2f + (((size_t)(ks * 64 + ntg0 + uu)) << 9) + lane * 8);
        acc2[0][uu] = MFMA(a0, b, acc2[0][uu]);
        acc2[1][uu] = MFMA(a1, b, acc2[1][uu]);
      }
    }

    // bounce wei (f32) and c (bf16) to LDS
    #pragma unroll
    for (int uu = 0; uu < 2; ++uu) {
      int col_l = (wn2 * 2 + uu) * 16 + arow;          // 0..63
      float b2 = b2sum[nb * 512 + nc * 64 + col_l];
      #pragma unroll
      for (int m = 0; m < 2; ++m) {
        #pragma unroll
        for (int i = 0; i < 4; ++i) {
          int row_l = wm * 32 + m * 16 + q * 4 + i;
          float x = acc2[m][uu][i] + b2;
          xs[row_l][col_l] = 1.f / (1.f + __expf(-x));
          cs[row_l][col_l] = (bf16)cacc[m][uu][i];
        }
      }
    }
    __syncthreads();

    // combine pass: vectorized e recompute + r store (coalesced)
    {
      int row_l = tid >> 2, sub = tid & 3;
      size_t rowoff = (size_t)(b0 + row_l) * 1024;
      #pragma unroll
      for (int h = 0; h < 2; ++h) {
        int lcol = sub * 16 + h * 8;
        int gcol = nb * 512 + nc * 64 + lcol;
        float4 n0 = *reinterpret_cast<const float4*>(name + rowoff + gcol);
        float4 n1 = *reinterpret_cast<const float4*>(name + rowoff + gcol + 4);
        float4 t0 = *reinterpret_cast<const float4*>(typ + rowoff + gcol);
        float4 t1 = *reinterpret_cast<const float4*>(typ + rowoff + gcol + 4);
        f32x4 w0 = *reinterpret_cast<const f32x4*>(&xs[row_l][lcol]);
        f32x4 w1 = *reinterpret_cast<const f32x4*>(&xs[row_l][lcol + 4]);
        bf16x8 cv = *reinterpret_cast<const bf16x8*>(&cs[row_l][lcol]);
        float ev[8] = {n0.x + t0.x, n0.y + t0.y, n0.z + t0.z, n0.w + t0.w,
                       n1.x + t1.x, n1.y + t1.y, n1.z + t1.z, n1.w + t1.w};
        float wv8[8] = {w0[0], w0[1], w0[2], w0[3], w1[0], w1[1], w1[2], w1[3]};
        bf16x8 rv;
        #pragma unroll
        for (int jj = 0; jj < 8; ++jj) {
          float e = ev[jj], c = (float)cv[jj];
          rv[jj] = (bf16)(2.f * (e + wv8[jj] * (c - e)));
        }
        *reinterpret_cast<bf16x8*>(r_ws + (size_t)(b0 + row_l) * 2048 + (size_t)tt * 1024 + gcol) = rv;
      }
    }
    __syncthreads();
  }
}

// ---------------- K3: final — out = sigmoid(relu(r@fw1T+fb1)@fw2T+fb2), M=64 ----------------

__global__ __launch_bounds__(512, 4)
void fused_final(const bf16* __restrict__ r_ws, const bf16* __restrict__ F1f,
                 const float* __restrict__ fb1, const float* __restrict__ fw2,
                 const float* __restrict__ fb2, float* __restrict__ out) {
  const int b0 = blockIdx.x * 64;
  const int tid = threadIdx.x;
  const int lane = tid & 63;
  const int wv = tid >> 6;
  const int arow = lane & 15;
  const int q    = lane >> 4;
  const int kgrp = q << 3;

  __shared__ bf16 RT[2][64][264];
  float (*H2)[260] = reinterpret_cast<float (*)[260]>(&RT[0][0][0]);

  bf16x8 sv[4];
  auto SLOAD = [&](int kc) {
    #pragma unroll
    for (int g = 0; g < 4; ++g) {
      int f = g * 512 + tid;
      int row = f >> 5, colg = f & 31;
      sv[g] = *reinterpret_cast<const bf16x8*>(r_ws + (size_t)(b0 + row) * 2048 + kc * 256 + colg * 8);
    }
  };
  auto SWRITE = [&](int buf) {
    #pragma unroll
    for (int g = 0; g < 4; ++g) {
      int f = g * 512 + tid;
      int row = f >> 5, colg = f & 31;
      *reinterpret_cast<bf16x8*>(&RT[buf][row][colg * 8]) = sv[g];
    }
  };

  SLOAD(0); SWRITE(0);
  __syncthreads();

  f32x4 acc[4][2] = {};
  #pragma unroll 1
  for (int kc = 0; kc < 8; ++kc) {
    if (kc < 7) SLOAD(kc + 1);
    #pragma unroll
    for (int ks = 0; ks < 8; ++ks) {
      int ksg = kc * 8 + ks;
      bf16x8 a[4];
      #pragma unroll
      for (int m = 0; m < 4; ++m)
        a[m] = *reinterpret_cast<const bf16x8*>(&RT[kc & 1][m * 16 + arow][ks * 32 + kgrp]);
      #pragma unroll
      for (int u = 0; u < 2; ++u) {
        bf16x8 b = *reinterpret_cast<const bf16x8*>(F1f + (((size_t)(ksg * 16 + wv * 2 + u)) << 9) + lane * 8);
        #pragma unroll
        for (int m = 0; m < 4; ++m)
          acc[m][u] = MFMA(a[m], b, acc[m][u]);
      }
    }
    if (kc < 7) SWRITE((kc + 1) & 1);
    __syncthreads();
  }

  #pragma unroll
  for (int u = 0; u < 2; ++u) {
    int col = (wv * 2 + u) * 16 + arow;
    float bb = fb1[col];
    #pragma unroll
    for (int m = 0; m < 4; ++m) {
      #pragma unroll
      for (int i2 = 0; i2 < 4; ++i2) {
        int row = m * 16 + q * 4 + i2;
        H2[row][col] = fmaxf(acc[m][u][i2] + bb, 0.f);
      }
    }
  }
  __syncthreads();

  int row = tid >> 3, sub = tid & 7;
  float p = 0.f;
  #pragma unroll
  for (int c = 0; c < 32; ++c) p += H2[row][sub * 32 + c] * fw2[sub * 32 + c];
  p += __shfl_xor(p, 1, 8);
  p += __shfl_xor(p, 2, 8);
  p += __shfl_xor(p, 4, 8);
  if (sub == 0) out[b0 + row] = 1.f / (1.f + __expf(-(p + fb2[0])));
}

// ---------------- launcher ----------------

extern "C" void kernel_launch(void* const* d_in, const int* in_sizes, int n_in,
                              void* d_out, int out_size, void* d_ws, size_t ws_size,
                              hipStream_t stream) {
  const float* name1 = (const float*)d_in[0];
  const float* type1 = (const float*)d_in[1];
  const float* coor1 = (const float*)d_in[2];
  const float* name2 = (const float*)d_in[3];
  const float* type2 = (const float*)d_in[4];
  const float* coor2 = (const float*)d_in[5];
  const float* cw    = (const float*)d_in[6];
  const float* cb    = (const float*)d_in[7];
  const float* l1w = (const float*)d_in[8];  const float* l1b = (const float*)d_in[9];
  const float* l1g = (const float*)d_in[10]; const float* l1be = (const float*)d_in[11];
  const float* l1m = (const float*)d_in[12]; const float* l1v = (const float*)d_in[13];
  const float* l2w = (const float*)d_in[14]; const float* l2b = (const float*)d_in[15];
  const float* l2g = (const float*)d_in[16]; const float* l2be = (const float*)d_in[17];
  const float* l2m = (const float*)d_in[18]; const float* l2v = (const float*)d_in[19];
  const float* g1w = (const float*)d_in[20]; const float* g1b = (const float*)d_in[21];
  const float* g1g = (const float*)d_in[22]; const float* g1be = (const float*)d_in[23];
  const float* g1m = (const float*)d_in[24]; const float* g1v = (const float*)d_in[25];
  const float* g2w = (const float*)d_in[26]; const float* g2b = (const float*)d_in[27];
  const float* g2g = (const float*)d_in[28]; const float* g2be = (const float*)d_in[29];
  const float* g2m = (const float*)d_in[30]; const float* g2v = (const float*)d_in[31];
  const float* fw1 = (const float*)d_in[32]; const float* fb1 = (const float*)d_in[33];
  const float* fw2 = (const float*)d_in[34]; const float* fb2 = (const float*)d_in[35];

  char* ws = (char*)d_ws;
  bf16*  W1f   = (bf16*)(ws + 0);          // 512*1088 bf16   = 1,114,112 B
  bf16*  W2f   = (bf16*)(ws + 1114112);    // 1024*512 bf16   = 1,048,576 B
  bf16*  CWf   = (bf16*)(ws + 2162688);    // 1024*64  bf16   =   131,072 B
  bf16*  F1f   = (bf16*)(ws + 2293760);    // 256*2048 bf16   = 1,048,576 B
  float* b1cat = (float*)(ws + 3342336);   // 512 f32
  float* b2sum = (float*)(ws + 3344384);   // 1024 f32
  bf16*  h_ws  = (bf16*)(ws + 3407872);    // [2][16384][512]  = 33,554,432 B
  bf16*  r_ws  = (bf16*)(ws + 36962304);   // [16384][2048]    = 67,108,864 B  (end ~104 MB)

  prep_w1main<<<2048, 256, 0, stream>>>(l1w, l1g, l1v, g1w, g1g, g1v, W1f);
  prep_w1tail<<<512, 512, 0, stream>>>(l1w, l1b, l1g, l1be, l1m, l1v,
                                       g1w, g1b, g1g, g1be, g1m, g1v, cw, cb, W1f, b1cat);
  prep_w2<<<2048, 256, 0, stream>>>(l2w, l2b, l2g, l2be, l2m, l2v,
                                    g2w, g2b, g2g, g2be, g2m, g2v, W2f, b2sum);
  prep_cwf<<<256, 256, 0, stream>>>(cw, cb, CWf);
  prep_f1f<<<2048, 256, 0, stream>>>(fw1, F1f);

  gemm1<<<512, 1024, 0, stream>>>(name1, type1, coor1, name2, type2, coor2, W1f, b1cat, h_ws);
  gemm2<<<dim3(128, 2, 2), 512, 0, stream>>>(name1, type1, coor1, name2, type2, coor2,
                                             W2f, CWf, b2sum, h_ws, r_ws);
  fused_final<<<256, 512, 0, stream>>>(r_ws, F1f, fb1, fw2, fb2, (float*)d_out);
}

// Round 6
// 374.901 us; speedup vs baseline: 1.5316x; 1.5316x over previous
//
#include <hip/hip_runtime.h>

typedef __bf16 bf16;
typedef __bf16 bf16x8 __attribute__((ext_vector_type(8)));
typedef __bf16 bf16x4 __attribute__((ext_vector_type(4)));
typedef float  f32x4  __attribute__((ext_vector_type(4)));

#define BN_EPS 1e-5f
#define MFMA(a, b, c) __builtin_amdgcn_mfma_f32_16x16x32_bf16((a), (b), (c), 0, 0, 0)

// Fragment-linear offset for MFMA B-operand matrix [N][K] (16x16x32 tiles):
// tile = (k/32)*ntiles + n/16 ; within tile: lane = ((k%32)/8)*16 + n%16, elem = k%8
__device__ __host__ __forceinline__ size_t frag_off(int n, int k, int ntiles) {
  return ((size_t)((k >> 5) * ntiles + (n >> 4)) << 9)
       + (size_t)((((k >> 3) & 3) << 4) + (n & 15)) * 8 + (k & 7);
}

// ---------------- prep kernels ----------------

__global__ void prep_w1main(const float* __restrict__ l1w, const float* __restrict__ l1g, const float* __restrict__ l1v,
                            const float* __restrict__ g1w, const float* __restrict__ g1g, const float* __restrict__ g1v,
                            bf16* __restrict__ W1f) {
  int gid = blockIdx.x * blockDim.x + threadIdx.x;   // 512*1024
  int n = gid >> 10, k = gid & 1023;
  float s, w;
  if (n < 256) { s = l1g[n] * rsqrtf(l1v[n] + BN_EPS); w = l1w[(size_t)n * 1024 + k]; }
  else { int nn = n - 256; s = g1g[nn] * rsqrtf(g1v[nn] + BN_EPS); w = g1w[(size_t)nn * 1024 + k]; }
  W1f[frag_off(n, k, 32)] = (bf16)(w * s);
}

__global__ __launch_bounds__(512)
void prep_w1tail(const float* __restrict__ l1w, const float* __restrict__ l1b, const float* __restrict__ l1g,
                 const float* __restrict__ l1be, const float* __restrict__ l1m, const float* __restrict__ l1v,
                 const float* __restrict__ g1w, const float* __restrict__ g1b, const float* __restrict__ g1g,
                 const float* __restrict__ g1be, const float* __restrict__ g1m, const float* __restrict__ g1v,
                 const float* __restrict__ cw, const float* __restrict__ cb,
                 bf16* __restrict__ W1f, float* __restrict__ b1cat) {
  int n = blockIdx.x;
  int kc = threadIdx.x & 63, js = threadIdx.x >> 6;
  const float* wrow; float s, bb, mm, be;
  if (n < 256) { s = l1g[n] * rsqrtf(l1v[n] + BN_EPS); wrow = l1w + (size_t)n * 1024;
                 bb = l1b[n]; mm = l1m[n]; be = l1be[n]; }
  else { int nn = n - 256; s = g1g[nn] * rsqrtf(g1v[nn] + BN_EPS); wrow = g1w + (size_t)nn * 1024;
         bb = g1b[nn]; mm = g1m[nn]; be = g1be[nn]; }
  float a = 0.f;
  if (kc < 49) {
    #pragma unroll 4
    for (int jj = 0; jj < 128; ++jj) {
      int j = js * 128 + jj;
      float cv = (kc < 48) ? cw[(size_t)j * 48 + kc] : cb[j];
      a += wrow[j] * cv;
    }
  }
  __shared__ float red[8][64];
  red[js][kc] = a;
  __syncthreads();
  if (threadIdx.x < 64) {
    float v = 0.f;
    #pragma unroll
    for (int r = 0; r < 8; ++r) v += red[r][threadIdx.x];
    W1f[frag_off(n, 1024 + threadIdx.x, 32)] = (bf16)((threadIdx.x < 49) ? v * s : 0.f);
  }
  if (threadIdx.x == 0) b1cat[n] = s * (bb - mm) + be;
}

__global__ void prep_w2(const float* __restrict__ l2w, const float* __restrict__ l2b, const float* __restrict__ l2g,
                        const float* __restrict__ l2be, const float* __restrict__ l2m, const float* __restrict__ l2v,
                        const float* __restrict__ g2w, const float* __restrict__ g2b, const float* __restrict__ g2g,
                        const float* __restrict__ g2be, const float* __restrict__ g2m, const float* __restrict__ g2v,
                        bf16* __restrict__ W2f, float* __restrict__ b2sum) {
  int gid = blockIdx.x * blockDim.x + threadIdx.x;   // 1024*512
  int n = gid >> 9, k = gid & 511;
  float w;
  if (k < 256) { float s = l2g[n] * rsqrtf(l2v[n] + BN_EPS); w = l2w[(size_t)n * 256 + k] * s; }
  else { float s = g2g[n] * rsqrtf(g2v[n] + BN_EPS); w = g2w[(size_t)n * 256 + (k - 256)] * s; }
  W2f[frag_off(n, k, 64)] = (bf16)w;
  if (k == 0) {
    float sl = l2g[n] * rsqrtf(l2v[n] + BN_EPS), sg = g2g[n] * rsqrtf(g2v[n] + BN_EPS);
    b2sum[n] = sl * (l2b[n] - l2m[n]) + l2be[n] + sg * (g2b[n] - g2m[n]) + g2be[n];
  }
}

__global__ void prep_cwf(const float* __restrict__ cw, const float* __restrict__ cb, bf16* __restrict__ CWf) {
  int gid = blockIdx.x * blockDim.x + threadIdx.x;   // 1024*64
  int n = gid >> 6, kc = gid & 63;
  float v = (kc < 48) ? cw[(size_t)n * 48 + kc] : (kc == 48 ? cb[n] : 0.f);
  CWf[frag_off(n, kc, 64)] = (bf16)v;
}

__global__ void prep_f1f(const float* __restrict__ fw1, bf16* __restrict__ F1f) {
  int gid = blockIdx.x * blockDim.x + threadIdx.x;   // 256*2048
  int n = gid >> 11, k = gid & 2047;
  F1f[frag_off(n, k, 16)] = (bf16)fw1[(size_t)n * 2048 + k];
}

// ---------------- K1: gemm1 — h = relu(e @ W1catT + b1cat); also emits e (bf16) to r_ws ----------------
// M=128, N=256 per block; 1024 thr; 17 phases of 64 k; 2-phase T3/T14 pipeline with NAMED regs.

__global__ __launch_bounds__(1024, 4)
void gemm1(const float* __restrict__ name1, const float* __restrict__ type1, const float* __restrict__ coor1,
           const float* __restrict__ name2, const float* __restrict__ type2, const float* __restrict__ coor2,
           const bf16* __restrict__ W1f, const float* __restrict__ b1cat,
           bf16* __restrict__ h_ws, bf16* __restrict__ r_ws) {
  const int bid = blockIdx.x;
  const int xcd = bid & 7, slot = bid >> 3;
  const int nb = slot & 1;
  const int lg = xcd * 32 + (slot >> 1);   // 0..255 bijective
  const int tt = lg >> 7;
  const int mb = lg & 127;
  const float* __restrict__ name = tt ? name2 : name1;
  const float* __restrict__ typ  = tt ? type2 : type1;
  const float* __restrict__ coor = tt ? coor2 : coor1;
  const int b0 = mb * 128;
  const int tid = threadIdx.x;
  const int lane = tid & 63;
  const int wv = tid >> 6;           // 0..15
  const int wm = wv >> 2;            // 0..3: 32-row group
  const int wn = wv & 3;             // 0..3: 4 ntiles each
  const int arow = lane & 15;
  const int q = lane >> 4;
  const int kgrp = q << 3;

  __shared__ __align__(16) char SM[67584];
  bf16 (*EB)[128][72] = reinterpret_cast<bf16 (*)[128][72]>(SM);   // 2 bufs x 18,432 B
  bf16 (*hb)[264] = reinterpret_cast<bf16 (*)[264]>(SM);           // overlay after k-loop

  const int srow = tid >> 3;         // 0..127
  const int scg = tid & 7;           // float4 slot (2 per thread: scg, scg+8)

  const float4* name4 = reinterpret_cast<const float4*>(name);
  const float4* typ4  = reinterpret_cast<const float4*>(typ);
  const float4* coor4 = reinterpret_cast<const float4*>(coor);

  // NAMED pipeline registers (rule #20: no runtime-indexed arrays)
  float4 n0, t0, n1, t1;

  auto REGLOAD = [&](int pp) {
    if (pp < 16) {
      size_t base = (size_t)(b0 + srow) * 256 + (size_t)pp * 16 + scg;
      n0 = name4[base];     t0 = typ4[base];
      n1 = name4[base + 8]; t1 = typ4[base + 8];
    } else {                              // tail phase: [coor(48) | 1 | 0...]
      n0 = coor4[(size_t)(b0 + srow) * 12 + scg];            // cols 0..31: always coor
      t0 = make_float4(0.f, 0.f, 0.f, 0.f);
      int idx = 8 + scg;                                      // cols 32..63
      if (idx < 12)       n1 = coor4[(size_t)(b0 + srow) * 12 + idx];
      else if (idx == 12) n1 = make_float4(1.f, 0.f, 0.f, 0.f);
      else                n1 = make_float4(0.f, 0.f, 0.f, 0.f);
      t1 = make_float4(0.f, 0.f, 0.f, 0.f);
    }
  };
  auto WRITEB = [&](int buf) {
    bf16x4 e0, e1;
    e0[0] = (bf16)(n0.x + t0.x); e0[1] = (bf16)(n0.y + t0.y);
    e0[2] = (bf16)(n0.z + t0.z); e0[3] = (bf16)(n0.w + t0.w);
    e1[0] = (bf16)(n1.x + t1.x); e1[1] = (bf16)(n1.y + t1.y);
    e1[2] = (bf16)(n1.z + t1.z); e1[3] = (bf16)(n1.w + t1.w);
    *reinterpret_cast<bf16x4*>(&EB[buf][srow][scg * 4]) = e0;
    *reinterpret_cast<bf16x4*>(&EB[buf][srow][32 + scg * 4]) = e1;
  };
  auto EWRITE = [&](int pp) {   // emit e (bf16) for gemm2's combine; phases 0..15 only
    bf16x4 e0, e1;
    e0[0] = (bf16)(n0.x + t0.x); e0[1] = (bf16)(n0.y + t0.y);
    e0[2] = (bf16)(n0.z + t0.z); e0[3] = (bf16)(n0.w + t0.w);
    e1[0] = (bf16)(n1.x + t1.x); e1[1] = (bf16)(n1.y + t1.y);
    e1[2] = (bf16)(n1.z + t1.z); e1[3] = (bf16)(n1.w + t1.w);
    size_t rb = (size_t)(b0 + srow) * 2048 + (size_t)tt * 1024 + pp * 64;
    *reinterpret_cast<bf16x4*>(r_ws + rb + scg * 4) = e0;
    *reinterpret_cast<bf16x4*>(r_ws + rb + 32 + scg * 4) = e1;
  };

  REGLOAD(0);
  WRITEB(0);
  EWRITE(0);
  __syncthreads();

  f32x4 acc[2][4] = {};
  #pragma unroll 1
  for (int p = 0; p < 17; ++p) {
    if (p < 16) REGLOAD(p + 1);            // issue next-phase HBM loads (T14 issue-early)
    #pragma unroll
    for (int ks2 = 0; ks2 < 2; ++ks2) {
      int kk = p * 2 + ks2;
      bf16x8 a0 = *reinterpret_cast<const bf16x8*>(&EB[p & 1][wm * 32 + arow][ks2 * 32 + kgrp]);
      bf16x8 a1 = *reinterpret_cast<const bf16x8*>(&EB[p & 1][wm * 32 + 16 + arow][ks2 * 32 + kgrp]);
      #pragma unroll
      for (int u = 0; u < 4; ++u) {
        bf16x8 b = *reinterpret_cast<const bf16x8*>(W1f + (((size_t)(kk * 32 + nb * 16 + wn * 4 + u)) << 9) + lane * 8);
        acc[0][u] = MFMA(a0, b, acc[0][u]);
        acc[1][u] = MFMA(a1, b, acc[1][u]);
      }
    }
    if (p < 16) {
      WRITEB((p + 1) & 1);                 // vmcnt dependency -> loads covered by MFMA phase
      if (p < 15) EWRITE(p + 1);
    }
    __syncthreads();
  }

  // ---- h = relu(acc + b1cat) via LDS bounce, then coalesced store ----
  #pragma unroll
  for (int u = 0; u < 4; ++u) {
    int col = (wn * 4 + u) * 16 + arow;
    float bb = b1cat[nb * 256 + col];
    #pragma unroll
    for (int m = 0; m < 2; ++m) {
      #pragma unroll
      for (int i = 0; i < 4; ++i)
        hb[wm * 32 + m * 16 + q * 4 + i][col] = (bf16)fmaxf(acc[m][u][i] + bb, 0.f);
    }
  }
  __syncthreads();

  #pragma unroll
  for (int g = 0; g < 4; ++g) {
    int idx = g * 1024 + tid;
    int row = idx >> 5, cg = idx & 31;
    *reinterpret_cast<bf16x8*>(h_ws + ((size_t)tt * 16384 + b0 + row) * 512 + nb * 256 + cg * 8) =
      *reinterpret_cast<const bf16x8*>(&hb[row][cg * 8]);
  }
}

// ---------------- K2: gemm2 + combine — r = 2e + 2*sigmoid(h@W2T+b2)*(c-e); e read as bf16 from r_ws ----------------

__global__ __launch_bounds__(512, 4)
void gemm2(const float* __restrict__ coor1, const float* __restrict__ coor2,
           const bf16* __restrict__ W2f, const bf16* __restrict__ CWf, const float* __restrict__ b2sum,
           const bf16* __restrict__ h_ws, bf16* __restrict__ r_ws) {
  const int mb = blockIdx.x;           // 0..127
  const int nb = blockIdx.y;           // 0..1 (512-col half)
  const int tt = blockIdx.z;           // 0..1
  const float* __restrict__ coor = tt ? coor2 : coor1;
  const int b0 = mb * 128;
  const int tid = threadIdx.x;
  const int lane = tid & 63;
  const int wv = tid >> 6;             // 0..7
  const int wm = wv >> 1;              // 0..3: 32-row group
  const int wn2 = wv & 1;              // 0..1: 32-col group within 64-col chunk
  const int arow = lane & 15;
  const int q = lane >> 4;
  const int kgrp = q << 3;

  __shared__ bf16 Ct[128][72];         // [coor | 1 | 0] : 18,432 B
  __shared__ float xs[128][72];        // wei f32 bounce : 36,864 B
  __shared__ bf16 cs[128][72];         // c bf16 bounce  : 18,432 B   (73,728 total -> 2 blk/CU)

  // stage Ct
  {
    const float4* coor4 = reinterpret_cast<const float4*>(coor);
    int row = tid >> 2, cq = tid & 3;
    #pragma unroll
    for (int v = 0; v < 5; ++v) {
      int c4 = v * 4 + cq;
      if (c4 < 18) {
        float4 cv;
        if (c4 < 12)       cv = coor4[(size_t)(b0 + row) * 12 + c4];
        else if (c4 == 12) cv = make_float4(1.f, 0.f, 0.f, 0.f);
        else               cv = make_float4(0.f, 0.f, 0.f, 0.f);
        bf16x4 e; e[0] = (bf16)cv.x; e[1] = (bf16)cv.y; e[2] = (bf16)cv.z; e[3] = (bf16)cv.w;
        *reinterpret_cast<bf16x4*>(&Ct[row][c4 * 4]) = e;
      }
    }
  }
  __syncthreads();

  const bf16* hbase = h_ws + ((size_t)tt * 16384 + b0) * 512;

  #pragma unroll 1
  for (int nc = 0; nc < 8; ++nc) {     // 8 chunks of 64 cols
    const int ntg0 = nb * 32 + nc * 4 + wn2 * 2;   // global ntile base (of 64)

    // c-tile (K=64 over [coor|1|0])
    f32x4 cacc[2][2] = {};
    #pragma unroll
    for (int j = 0; j < 2; ++j) {
      bf16x8 a0 = *reinterpret_cast<const bf16x8*>(&Ct[wm * 32 + arow][j * 32 + kgrp]);
      bf16x8 a1 = *reinterpret_cast<const bf16x8*>(&Ct[wm * 32 + 16 + arow][j * 32 + kgrp]);
      #pragma unroll
      for (int uu = 0; uu < 2; ++uu) {
        bf16x8 b = *reinterpret_cast<const bf16x8*>(CWf + (((size_t)(j * 64 + ntg0 + uu)) << 9) + lane * 8);
        cacc[0][uu] = MFMA(a0, b, cacc[0][uu]);
        cacc[1][uu] = MFMA(a1, b, cacc[1][uu]);
      }
    }

    // x-tile (K=512 over h, gathered from global; L2-resident after chunk 0)
    f32x4 acc2[2][2] = {};
    #pragma unroll 4
    for (int ks = 0; ks < 16; ++ks) {
      bf16x8 a0 = *reinterpret_cast<const bf16x8*>(hbase + (size_t)(wm * 32 + arow) * 512 + ks * 32 + kgrp);
      bf16x8 a1 = *reinterpret_cast<const bf16x8*>(hbase + (size_t)(wm * 32 + 16 + arow) * 512 + ks * 32 + kgrp);
      #pragma unroll
      for (int uu = 0; uu < 2; ++uu) {
        bf16x8 b = *reinterpret_cast<const bf16x8*>(W2f + (((size_t)(ks * 64 + ntg0 + uu)) << 9) + lane * 8);
        acc2[0][uu] = MFMA(a0, b, acc2[0][uu]);
        acc2[1][uu] = MFMA(a1, b, acc2[1][uu]);
      }
    }

    // bounce wei (f32) and c (bf16) to LDS
    #pragma unroll
    for (int uu = 0; uu < 2; ++uu) {
      int col_l = (wn2 * 2 + uu) * 16 + arow;          // 0..63
      float b2 = b2sum[nb * 512 + nc * 64 + col_l];
      #pragma unroll
      for (int m = 0; m < 2; ++m) {
        #pragma unroll
        for (int i = 0; i < 4; ++i) {
          int row_l = wm * 32 + m * 16 + q * 4 + i;
          float x = acc2[m][uu][i] + b2;
          xs[row_l][col_l] = 1.f / (1.f + __expf(-x));
          cs[row_l][col_l] = (bf16)cacc[m][uu][i];
        }
      }
    }
    __syncthreads();

    // combine pass: e read back as bf16 from r_ws, r written in place (coalesced bf16x8)
    {
      int row_l = tid >> 2, sub = tid & 3;
      size_t rowoff = (size_t)(b0 + row_l) * 2048 + (size_t)tt * 1024;
      #pragma unroll
      for (int h = 0; h < 2; ++h) {
        int lcol = sub * 16 + h * 8;
        int gcol = nb * 512 + nc * 64 + lcol;
        bf16x8 ebv = *reinterpret_cast<const bf16x8*>(r_ws + rowoff + gcol);
        f32x4 w0 = *reinterpret_cast<const f32x4*>(&xs[row_l][lcol]);
        f32x4 w1 = *reinterpret_cast<const f32x4*>(&xs[row_l][lcol + 4]);
        bf16x8 cv = *reinterpret_cast<const bf16x8*>(&cs[row_l][lcol]);
        bf16x8 rv;
        #pragma unroll
        for (int jj = 0; jj < 8; ++jj) {
          float e = (float)ebv[jj], c = (float)cv[jj];
          float w = (jj < 4) ? w0[jj] : w1[jj - 4];
          rv[jj] = (bf16)(2.f * (e + w * (c - e)));
        }
        *reinterpret_cast<bf16x8*>(r_ws + rowoff + gcol) = rv;
      }
    }
    __syncthreads();
  }
}

// ---------------- K3: final — out = sigmoid(relu(r@fw1T+fb1)@fw2T+fb2), M=64 ----------------

__global__ __launch_bounds__(512, 4)
void fused_final(const bf16* __restrict__ r_ws, const bf16* __restrict__ F1f,
                 const float* __restrict__ fb1, const float* __restrict__ fw2,
                 const float* __restrict__ fb2, float* __restrict__ out) {
  const int b0 = blockIdx.x * 64;
  const int tid = threadIdx.x;
  const int lane = tid & 63;
  const int wv = tid >> 6;
  const int arow = lane & 15;
  const int q    = lane >> 4;
  const int kgrp = q << 3;

  __shared__ bf16 RT[2][64][264];
  float (*H2)[260] = reinterpret_cast<float (*)[260]>(&RT[0][0][0]);

  bf16x8 sv[4];
  auto SLOAD = [&](int kc) {
    #pragma unroll
    for (int g = 0; g < 4; ++g) {
      int f = g * 512 + tid;
      int row = f >> 5, colg = f & 31;
      sv[g] = *reinterpret_cast<const bf16x8*>(r_ws + (size_t)(b0 + row) * 2048 + kc * 256 + colg * 8);
    }
  };
  auto SWRITE = [&](int buf) {
    #pragma unroll
    for (int g = 0; g < 4; ++g) {
      int f = g * 512 + tid;
      int row = f >> 5, colg = f & 31;
      *reinterpret_cast<bf16x8*>(&RT[buf][row][colg * 8]) = sv[g];
    }
  };

  SLOAD(0); SWRITE(0);
  __syncthreads();

  f32x4 acc[4][2] = {};
  #pragma unroll 1
  for (int kc = 0; kc < 8; ++kc) {
    if (kc < 7) SLOAD(kc + 1);
    #pragma unroll
    for (int ks = 0; ks < 8; ++ks) {
      int ksg = kc * 8 + ks;
      bf16x8 a[4];
      #pragma unroll
      for (int m = 0; m < 4; ++m)
        a[m] = *reinterpret_cast<const bf16x8*>(&RT[kc & 1][m * 16 + arow][ks * 32 + kgrp]);
      #pragma unroll
      for (int u = 0; u < 2; ++u) {
        bf16x8 b = *reinterpret_cast<const bf16x8*>(F1f + (((size_t)(ksg * 16 + wv * 2 + u)) << 9) + lane * 8);
        #pragma unroll
        for (int m = 0; m < 4; ++m)
          acc[m][u] = MFMA(a[m], b, acc[m][u]);
      }
    }
    if (kc < 7) SWRITE((kc + 1) & 1);
    __syncthreads();
  }

  #pragma unroll
  for (int u = 0; u < 2; ++u) {
    int col = (wv * 2 + u) * 16 + arow;
    float bb = fb1[col];
    #pragma unroll
    for (int m = 0; m < 4; ++m) {
      #pragma unroll
      for (int i2 = 0; i2 < 4; ++i2) {
        int row = m * 16 + q * 4 + i2;
        H2[row][col] = fmaxf(acc[m][u][i2] + bb, 0.f);
      }
    }
  }
  __syncthreads();

  int row = tid >> 3, sub = tid & 7;
  float p = 0.f;
  #pragma unroll
  for (int c = 0; c < 32; ++c) p += H2[row][sub * 32 + c] * fw2[sub * 32 + c];
  p += __shfl_xor(p, 1, 8);
  p += __shfl_xor(p, 2, 8);
  p += __shfl_xor(p, 4, 8);
  if (sub == 0) out[b0 + row] = 1.f / (1.f + __expf(-(p + fb2[0])));
}

// ---------------- launcher ----------------

extern "C" void kernel_launch(void* const* d_in, const int* in_sizes, int n_in,
                              void* d_out, int out_size, void* d_ws, size_t ws_size,
                              hipStream_t stream) {
  const float* name1 = (const float*)d_in[0];
  const float* type1 = (const float*)d_in[1];
  const float* coor1 = (const float*)d_in[2];
  const float* name2 = (const float*)d_in[3];
  const float* type2 = (const float*)d_in[4];
  const float* coor2 = (const float*)d_in[5];
  const float* cw    = (const float*)d_in[6];
  const float* cb    = (const float*)d_in[7];
  const float* l1w = (const float*)d_in[8];  const float* l1b = (const float*)d_in[9];
  const float* l1g = (const float*)d_in[10]; const float* l1be = (const float*)d_in[11];
  const float* l1m = (const float*)d_in[12]; const float* l1v = (const float*)d_in[13];
  const float* l2w = (const float*)d_in[14]; const float* l2b = (const float*)d_in[15];
  const float* l2g = (const float*)d_in[16]; const float* l2be = (const float*)d_in[17];
  const float* l2m = (const float*)d_in[18]; const float* l2v = (const float*)d_in[19];
  const float* g1w = (const float*)d_in[20]; const float* g1b = (const float*)d_in[21];
  const float* g1g = (const float*)d_in[22]; const float* g1be = (const float*)d_in[23];
  const float* g1m = (const float*)d_in[24]; const float* g1v = (const float*)d_in[25];
  const float* g2w = (const float*)d_in[26]; const float* g2b = (const float*)d_in[27];
  const float* g2g = (const float*)d_in[28]; const float* g2be = (const float*)d_in[29];
  const float* g2m = (const float*)d_in[30]; const float* g2v = (const float*)d_in[31];
  const float* fw1 = (const float*)d_in[32]; const float* fb1 = (const float*)d_in[33];
  const float* fw2 = (const float*)d_in[34]; const float* fb2 = (const float*)d_in[35];

  char* ws = (char*)d_ws;
  bf16*  W1f   = (bf16*)(ws + 0);          // 512*1088 bf16   = 1,114,112 B
  bf16*  W2f   = (bf16*)(ws + 1114112);    // 1024*512 bf16   = 1,048,576 B
  bf16*  CWf   = (bf16*)(ws + 2162688);    // 1024*64  bf16   =   131,072 B
  bf16*  F1f   = (bf16*)(ws + 2293760);    // 256*2048 bf16   = 1,048,576 B
  float* b1cat = (float*)(ws + 3342336);   // 512 f32
  float* b2sum = (float*)(ws + 3344384);   // 1024 f32
  bf16*  h_ws  = (bf16*)(ws + 3407872);    // [2][16384][512]  = 33,554,432 B
  bf16*  r_ws  = (bf16*)(ws + 36962304);   // [16384][2048]    = 67,108,864 B (holds e, then r)

  prep_w1main<<<2048, 256, 0, stream>>>(l1w, l1g, l1v, g1w, g1g, g1v, W1f);
  prep_w1tail<<<512, 512, 0, stream>>>(l1w, l1b, l1g, l1be, l1m, l1v,
                                       g1w, g1b, g1g, g1be, g1m, g1v, cw, cb, W1f, b1cat);
  prep_w2<<<2048, 256, 0, stream>>>(l2w, l2b, l2g, l2be, l2m, l2v,
                                    g2w, g2b, g2g, g2be, g2m, g2v, W2f, b2sum);
  prep_cwf<<<256, 256, 0, stream>>>(cw, cb, CWf);
  prep_f1f<<<2048, 256, 0, stream>>>(fw1, F1f);

  gemm1<<<512, 1024, 0, stream>>>(name1, type1, coor1, name2, type2, coor2, W1f, b1cat, h_ws, r_ws);
  gemm2<<<dim3(128, 2, 2), 512, 0, stream>>>(coor1, coor2, W2f, CWf, b2sum, h_ws, r_ws);
  fused_final<<<256, 512, 0, stream>>>(r_ws, F1f, fb1, fw2, fb2, (float*)d_out);
}

// Round 7
// 352.961 us; speedup vs baseline: 1.6268x; 1.0622x over previous
//
#include <hip/hip_runtime.h>

typedef __bf16 bf16;
typedef __bf16 bf16x8 __attribute__((ext_vector_type(8)));
typedef __bf16 bf16x4 __attribute__((ext_vector_type(4)));
typedef float  f32x4  __attribute__((ext_vector_type(4)));

#define BN_EPS 1e-5f
#define MFMA(a, b, c) __builtin_amdgcn_mfma_f32_16x16x32_bf16((a), (b), (c), 0, 0, 0)
#define BAR() do { __builtin_amdgcn_sched_barrier(0); \
                   asm volatile("s_waitcnt lgkmcnt(0)" ::: "memory"); \
                   __builtin_amdgcn_s_barrier(); \
                   __builtin_amdgcn_sched_barrier(0); } while (0)

// Fragment-linear offset for MFMA B-operand matrix [N][K] (16x16x32 tiles):
// tile = (k/32)*ntiles + n/16 ; within tile: lane = ((k%32)/8)*16 + n%16, elem = k%8
__device__ __host__ __forceinline__ size_t frag_off(int n, int k, int ntiles) {
  return ((size_t)((k >> 5) * ntiles + (n >> 4)) << 9)
       + (size_t)((((k >> 3) & 3) << 4) + (n & 15)) * 8 + (k & 7);
}

// ---------------- prep kernels ----------------

__global__ void prep_w1main(const float* __restrict__ l1w, const float* __restrict__ l1g, const float* __restrict__ l1v,
                            const float* __restrict__ g1w, const float* __restrict__ g1g, const float* __restrict__ g1v,
                            bf16* __restrict__ W1f) {
  int gid = blockIdx.x * blockDim.x + threadIdx.x;   // 512*1024
  int n = gid >> 10, k = gid & 1023;
  float s, w;
  if (n < 256) { s = l1g[n] * rsqrtf(l1v[n] + BN_EPS); w = l1w[(size_t)n * 1024 + k]; }
  else { int nn = n - 256; s = g1g[nn] * rsqrtf(g1v[nn] + BN_EPS); w = g1w[(size_t)nn * 1024 + k]; }
  W1f[frag_off(n, k, 32)] = (bf16)(w * s);
}

__global__ __launch_bounds__(512)
void prep_w1tail(const float* __restrict__ l1w, const float* __restrict__ l1b, const float* __restrict__ l1g,
                 const float* __restrict__ l1be, const float* __restrict__ l1m, const float* __restrict__ l1v,
                 const float* __restrict__ g1w, const float* __restrict__ g1b, const float* __restrict__ g1g,
                 const float* __restrict__ g1be, const float* __restrict__ g1m, const float* __restrict__ g1v,
                 const float* __restrict__ cw, const float* __restrict__ cb,
                 bf16* __restrict__ W1f, float* __restrict__ b1cat) {
  int n = blockIdx.x;
  int kc = threadIdx.x & 63, js = threadIdx.x >> 6;
  const float* wrow; float s, bb, mm, be;
  if (n < 256) { s = l1g[n] * rsqrtf(l1v[n] + BN_EPS); wrow = l1w + (size_t)n * 1024;
                 bb = l1b[n]; mm = l1m[n]; be = l1be[n]; }
  else { int nn = n - 256; s = g1g[nn] * rsqrtf(g1v[nn] + BN_EPS); wrow = g1w + (size_t)nn * 1024;
         bb = g1b[nn]; mm = g1m[nn]; be = g1be[nn]; }
  float a = 0.f;
  if (kc < 49) {
    #pragma unroll 4
    for (int jj = 0; jj < 128; ++jj) {
      int j = js * 128 + jj;
      float cv = (kc < 48) ? cw[(size_t)j * 48 + kc] : cb[j];
      a += wrow[j] * cv;
    }
  }
  __shared__ float red[8][64];
  red[js][kc] = a;
  __syncthreads();
  if (threadIdx.x < 64) {
    float v = 0.f;
    #pragma unroll
    for (int r = 0; r < 8; ++r) v += red[r][threadIdx.x];
    W1f[frag_off(n, 1024 + threadIdx.x, 32)] = (bf16)((threadIdx.x < 49) ? v * s : 0.f);
  }
  if (threadIdx.x == 0) b1cat[n] = s * (bb - mm) + be;
}

__global__ void prep_w2(const float* __restrict__ l2w, const float* __restrict__ l2b, const float* __restrict__ l2g,
                        const float* __restrict__ l2be, const float* __restrict__ l2m, const float* __restrict__ l2v,
                        const float* __restrict__ g2w, const float* __restrict__ g2b, const float* __restrict__ g2g,
                        const float* __restrict__ g2be, const float* __restrict__ g2m, const float* __restrict__ g2v,
                        bf16* __restrict__ W2f, float* __restrict__ b2sum) {
  int gid = blockIdx.x * blockDim.x + threadIdx.x;   // 1024*512
  int n = gid >> 9, k = gid & 511;
  float w;
  if (k < 256) { float s = l2g[n] * rsqrtf(l2v[n] + BN_EPS); w = l2w[(size_t)n * 256 + k] * s; }
  else { float s = g2g[n] * rsqrtf(g2v[n] + BN_EPS); w = g2w[(size_t)n * 256 + (k - 256)] * s; }
  W2f[frag_off(n, k, 64)] = (bf16)w;
  if (k == 0) {
    float sl = l2g[n] * rsqrtf(l2v[n] + BN_EPS), sg = g2g[n] * rsqrtf(g2v[n] + BN_EPS);
    b2sum[n] = sl * (l2b[n] - l2m[n]) + l2be[n] + sg * (g2b[n] - g2m[n]) + g2be[n];
  }
}

__global__ void prep_cwf(const float* __restrict__ cw, const float* __restrict__ cb, bf16* __restrict__ CWf) {
  int gid = blockIdx.x * blockDim.x + threadIdx.x;   // 1024*64
  int n = gid >> 6, kc = gid & 63;
  float v = (kc < 48) ? cw[(size_t)n * 48 + kc] : (kc == 48 ? cb[n] : 0.f);
  CWf[frag_off(n, kc, 64)] = (bf16)v;
}

__global__ void prep_f1f(const float* __restrict__ fw1, bf16* __restrict__ F1f) {
  int gid = blockIdx.x * blockDim.x + threadIdx.x;   // 256*2048
  int n = gid >> 11, k = gid & 2047;
  F1f[frag_off(n, k, 16)] = (bf16)fw1[(size_t)n * 2048 + k];
}

// ---------------- K1: gemm1 — h = relu(e @ W1catT + b1cat); emits e (bf16) to r_ws ----------------
// M=128, N=256; 1024 thr; 17 phases of 64 k; depth-2 named-reg pipeline, raw barrier (NO vmcnt drain).

__global__ __launch_bounds__(1024, 4)
void gemm1(const float* __restrict__ name1, const float* __restrict__ type1, const float* __restrict__ coor1,
           const float* __restrict__ name2, const float* __restrict__ type2, const float* __restrict__ coor2,
           const bf16* __restrict__ W1f, const float* __restrict__ b1cat,
           bf16* __restrict__ h_ws, bf16* __restrict__ r_ws) {
  const int bid = blockIdx.x;
  const int xcd = bid & 7, slot = bid >> 3;
  const int nb = slot & 1;
  const int lg = xcd * 32 + (slot >> 1);   // 0..255 bijective
  const int tt = lg >> 7;
  const int mb = lg & 127;
  const float* __restrict__ name = tt ? name2 : name1;
  const float* __restrict__ typ  = tt ? type2 : type1;
  const float* __restrict__ coor = tt ? coor2 : coor1;
  const int b0 = mb * 128;
  const int tid = threadIdx.x;
  const int lane = tid & 63;
  const int wv = tid >> 6;           // 0..15
  const int wm = wv >> 2;            // 0..3: 32-row group
  const int wn = wv & 3;             // 0..3: 4 ntiles each
  const int arow = lane & 15;
  const int q = lane >> 4;
  const int kgrp = q << 3;

  __shared__ __align__(16) char SM[67584];
  bf16 (*EB)[128][72] = reinterpret_cast<bf16 (*)[128][72]>(SM);   // 2 bufs x 18,432 B
  bf16 (*hb)[264] = reinterpret_cast<bf16 (*)[264]>(SM);           // overlay after k-loop

  const int srow = tid >> 3;         // 0..127
  const int scg = tid & 7;

  const float4* name4 = reinterpret_cast<const float4*>(name);
  const float4* typ4  = reinterpret_cast<const float4*>(typ);
  const float4* coor4 = reinterpret_cast<const float4*>(coor);

  // two NAMED register sets (rule #20): A = even phases (+tail 16), B = odd phases
  float4 nA0, tA0, nA1, tA1, nB0, tB0, nB1, tB1;

  auto REGLOAD_A = [&](int pp) {
    if (pp < 16) {
      size_t base = (size_t)(b0 + srow) * 256 + (size_t)pp * 16 + scg;
      nA0 = name4[base];     tA0 = typ4[base];
      nA1 = name4[base + 8]; tA1 = typ4[base + 8];
    } else {                              // tail: [coor(48) | 1 | 0...]
      nA0 = coor4[(size_t)(b0 + srow) * 12 + scg];
      tA0 = make_float4(0.f, 0.f, 0.f, 0.f);
      int idx = 8 + scg;
      if (idx < 12)       nA1 = coor4[(size_t)(b0 + srow) * 12 + idx];
      else if (idx == 12) nA1 = make_float4(1.f, 0.f, 0.f, 0.f);
      else                nA1 = make_float4(0.f, 0.f, 0.f, 0.f);
      tA1 = make_float4(0.f, 0.f, 0.f, 0.f);
    }
  };
  auto REGLOAD_B = [&](int pp) {
    size_t base = (size_t)(b0 + srow) * 256 + (size_t)pp * 16 + scg;
    nB0 = name4[base];     tB0 = typ4[base];
    nB1 = name4[base + 8]; tB1 = typ4[base + 8];
  };
  auto PACK = [&](const float4& nv, const float4& tv) {
    bf16x4 e;
    e[0] = (bf16)(nv.x + tv.x); e[1] = (bf16)(nv.y + tv.y);
    e[2] = (bf16)(nv.z + tv.z); e[3] = (bf16)(nv.w + tv.w);
    return e;
  };
  auto WRITEB_A = [&](int buf) {
    *reinterpret_cast<bf16x4*>(&EB[buf][srow][scg * 4]) = PACK(nA0, tA0);
    *reinterpret_cast<bf16x4*>(&EB[buf][srow][32 + scg * 4]) = PACK(nA1, tA1);
  };
  auto WRITEB_B = [&](int buf) {
    *reinterpret_cast<bf16x4*>(&EB[buf][srow][scg * 4]) = PACK(nB0, tB0);
    *reinterpret_cast<bf16x4*>(&EB[buf][srow][32 + scg * 4]) = PACK(nB1, tB1);
  };
  auto EWRITE_A = [&](int pp) {
    size_t rb = (size_t)(b0 + srow) * 2048 + (size_t)tt * 1024 + pp * 64;
    *reinterpret_cast<bf16x4*>(r_ws + rb + scg * 4) = PACK(nA0, tA0);
    *reinterpret_cast<bf16x4*>(r_ws + rb + 32 + scg * 4) = PACK(nA1, tA1);
  };
  auto EWRITE_B = [&](int pp) {
    size_t rb = (size_t)(b0 + srow) * 2048 + (size_t)tt * 1024 + pp * 64;
    *reinterpret_cast<bf16x4*>(r_ws + rb + scg * 4) = PACK(nB0, tB0);
    *reinterpret_cast<bf16x4*>(r_ws + rb + 32 + scg * 4) = PACK(nB1, tB1);
  };

  f32x4 acc[2][4] = {};
  auto MFMA_PHASE = [&](int p, int buf) {
    #pragma unroll
    for (int ks2 = 0; ks2 < 2; ++ks2) {
      int kk = p * 2 + ks2;
      bf16x8 a0 = *reinterpret_cast<const bf16x8*>(&EB[buf][wm * 32 + arow][ks2 * 32 + kgrp]);
      bf16x8 a1 = *reinterpret_cast<const bf16x8*>(&EB[buf][wm * 32 + 16 + arow][ks2 * 32 + kgrp]);
      #pragma unroll
      for (int u = 0; u < 4; ++u) {
        bf16x8 b = *reinterpret_cast<const bf16x8*>(W1f + (((size_t)(kk * 32 + nb * 16 + wn * 4 + u)) << 9) + lane * 8);
        acc[0][u] = MFMA(a0, b, acc[0][u]);
        acc[1][u] = MFMA(a1, b, acc[1][u]);
      }
    }
  };

  // prologue: EB[0]=phase0 visible; B holds ph1; A holds ph2 (in flight)
  REGLOAD_A(0); REGLOAD_B(1);
  WRITEB_A(0); EWRITE_A(0);
  REGLOAD_A(2);
  BAR();

  #pragma unroll 1
  for (int j = 0; j < 8; ++j) {
    const int p0 = 2 * j;
    WRITEB_B(1); EWRITE_B(p0 + 1);           // p0+1 <= 15 always
    if (p0 + 3 < 16) REGLOAD_B(p0 + 3);
    MFMA_PHASE(p0, 0);
    BAR();                                   // EB[1] visible; loads stay in flight
    WRITEB_A(0);
    if (p0 + 2 <= 15) EWRITE_A(p0 + 2);
    if (p0 + 4 <= 16) REGLOAD_A(p0 + 4);
    MFMA_PHASE(p0 + 1, 1);
    BAR();                                   // EB[0] visible (phase p0+2)
  }
  MFMA_PHASE(16, 0);                          // coor tail
  __syncthreads();                            // full drain before hb overlay

  // ---- h = relu(acc + b1cat) via LDS bounce, then coalesced store ----
  #pragma unroll
  for (int u = 0; u < 4; ++u) {
    int col = (wn * 4 + u) * 16 + arow;
    float bb = b1cat[nb * 256 + col];
    #pragma unroll
    for (int m = 0; m < 2; ++m) {
      #pragma unroll
      for (int i = 0; i < 4; ++i)
        hb[wm * 32 + m * 16 + q * 4 + i][col] = (bf16)fmaxf(acc[m][u][i] + bb, 0.f);
    }
  }
  __syncthreads();

  #pragma unroll
  for (int g = 0; g < 4; ++g) {
    int idx = g * 1024 + tid;
    int row = idx >> 5, cg = idx & 31;
    *reinterpret_cast<bf16x8*>(h_ws + ((size_t)tt * 16384 + b0 + row) * 512 + nb * 256 + cg * 8) =
      *reinterpret_cast<const bf16x8*>(&hb[row][cg * 8]);
  }
}

// ---------------- K2: gemm2 + combine — r = 2e + 2*sigmoid(h@W2T+b2)*(c-e) ----------------
// M=128, N=256 per block; h k-chunks LDS-staged with depth-2 named-reg pipeline, raw barriers.
// bid mapping co-locates the 4 nb-blocks of one (mb,tt) on one XCD for h L2 reuse.

__global__ __launch_bounds__(512, 4)
void gemm2(const float* __restrict__ coor1, const float* __restrict__ coor2,
           const bf16* __restrict__ W2f, const bf16* __restrict__ CWf, const float* __restrict__ b2sum,
           const bf16* __restrict__ h_ws, bf16* __restrict__ r_ws) {
  const int bid = blockIdx.x;            // 1024 blocks
  const int xcd = bid & 7, s = bid >> 3; // s: [tt(1)][nb(2)][mhi(4)]
  const int mb = xcd + 8 * (s & 15);     // 0..127 ; mb%8 == xcd -> nb-quad shares XCD
  const int nb = (s >> 4) & 3;           // 0..3 (256-col quarter)
  const int tt = s >> 6;
  const float* __restrict__ coor = tt ? coor2 : coor1;
  const int b0 = mb * 128;
  const int tid = threadIdx.x;
  const int lane = tid & 63;
  const int wv = tid >> 6;               // 0..7
  const int wm = wv >> 1;                // 0..3: 32-row group
  const int wn2 = wv & 1;                // 0..1: 128-col half of the 256
  const int arow = lane & 15;
  const int q = lane >> 4;
  const int kgrp = q << 3;

  __shared__ __align__(16) char SM[73728];
  bf16 (*HB)[128][72] = reinterpret_cast<bf16 (*)[128][72]>(SM);            // 2 x 18,432 B
  bf16 (*Ct)[72] = reinterpret_cast<bf16 (*)[72]>(SM + 36864);               // 18,432 B
  bf16 (*cs)[72] = reinterpret_cast<bf16 (*)[72]>(SM + 36864 + 18432);       // 18,432 B
  float (*xs)[72] = reinterpret_cast<float (*)[72]>(SM);                     // overlay HB post k-loop

  // stage Ct
  {
    const float4* coor4 = reinterpret_cast<const float4*>(coor);
    int row = tid >> 2, cq = tid & 3;
    #pragma unroll
    for (int v = 0; v < 5; ++v) {
      int c4 = v * 4 + cq;
      if (c4 < 18) {
        float4 cv;
        if (c4 < 12)       cv = coor4[(size_t)(b0 + row) * 12 + c4];
        else if (c4 == 12) cv = make_float4(1.f, 0.f, 0.f, 0.f);
        else               cv = make_float4(0.f, 0.f, 0.f, 0.f);
        bf16x4 e; e[0] = (bf16)cv.x; e[1] = (bf16)cv.y; e[2] = (bf16)cv.z; e[3] = (bf16)cv.w;
        *reinterpret_cast<bf16x4*>(&Ct[row][c4 * 4]) = e;
      }
    }
  }

  const bf16* hbase = h_ws + ((size_t)tt * 16384 + b0) * 512;
  const int srow = tid >> 2, scg = tid & 3;

  bf16x8 hA0, hA1, hB0, hB1;                 // named staging regs
  auto LOADH_A = [&](int kc) {
    const bf16* p = hbase + (size_t)srow * 512 + kc * 64 + scg * 16;
    hA0 = *reinterpret_cast<const bf16x8*>(p);
    hA1 = *reinterpret_cast<const bf16x8*>(p + 8);
  };
  auto LOADH_B = [&](int kc) {
    const bf16* p = hbase + (size_t)srow * 512 + kc * 64 + scg * 16;
    hB0 = *reinterpret_cast<const bf16x8*>(p);
    hB1 = *reinterpret_cast<const bf16x8*>(p + 8);
  };
  auto WRITEH_A = [&](int buf) {
    *reinterpret_cast<bf16x8*>(&HB[buf][srow][scg * 16]) = hA0;
    *reinterpret_cast<bf16x8*>(&HB[buf][srow][scg * 16 + 8]) = hA1;
  };
  auto WRITEH_B = [&](int buf) {
    *reinterpret_cast<bf16x8*>(&HB[buf][srow][scg * 16]) = hB0;
    *reinterpret_cast<bf16x8*>(&HB[buf][srow][scg * 16 + 8]) = hB1;
  };

  f32x4 acc[2][8] = {};
  auto MFMA_CHUNK = [&](int kc, int buf) {
    #pragma unroll
    for (int kt = 0; kt < 2; ++kt) {
      bf16x8 a0 = *reinterpret_cast<const bf16x8*>(&HB[buf][wm * 32 + arow][kt * 32 + kgrp]);
      bf16x8 a1 = *reinterpret_cast<const bf16x8*>(&HB[buf][wm * 32 + 16 + arow][kt * 32 + kgrp]);
      #pragma unroll
      for (int u = 0; u < 8; ++u) {
        bf16x8 b = *reinterpret_cast<const bf16x8*>(
            W2f + (((size_t)((kc * 2 + kt) * 64 + nb * 16 + wn2 * 8 + u)) << 9) + lane * 8);
        acc[0][u] = MFMA(a0, b, acc[0][u]);
        acc[1][u] = MFMA(a1, b, acc[1][u]);
      }
    }
  };

  // prologue: HB[0]=chunk0; B holds c1; A holds c2
  LOADH_A(0); LOADH_B(1);
  WRITEH_A(0);
  LOADH_A(2);
  BAR();                                     // also covers Ct writes

  #pragma unroll 1
  for (int j = 0; j < 4; ++j) {
    const int c0 = 2 * j;
    WRITEH_B(1);
    if (c0 + 3 < 8) LOADH_B(c0 + 3);
    MFMA_CHUNK(c0, 0);
    BAR();
    if (c0 + 2 < 8) WRITEH_A(0);
    if (c0 + 4 < 8) LOADH_A(c0 + 4);
    MFMA_CHUNK(c0 + 1, 1);
    BAR();                                   // last iter: all LDS reads done -> xs overlay safe
  }

  // ---- combine: 4 chunks of 64 cols (unrolled for static acc indexing) ----
  #pragma unroll
  for (int nc = 0; nc < 4; ++nc) {
    if (wn2 == (nc >> 1)) {                  // wave-uniform branch
      f32x4 cacc[2][4] = {};
      #pragma unroll
      for (int kt = 0; kt < 2; ++kt) {
        bf16x8 ca0 = *reinterpret_cast<const bf16x8*>(&Ct[wm * 32 + arow][kt * 32 + kgrp]);
        bf16x8 ca1 = *reinterpret_cast<const bf16x8*>(&Ct[wm * 32 + 16 + arow][kt * 32 + kgrp]);
        #pragma unroll
        for (int uu = 0; uu < 4; ++uu) {
          bf16x8 cb = *reinterpret_cast<const bf16x8*>(
              CWf + (((size_t)(kt * 64 + nb * 16 + nc * 4 + uu)) << 9) + lane * 8);
          cacc[0][uu] = MFMA(ca0, cb, cacc[0][uu]);
          cacc[1][uu] = MFMA(ca1, cb, cacc[1][uu]);
        }
      }
      #pragma unroll
      for (int uu = 0; uu < 4; ++uu) {
        int col_l = uu * 16 + arow;          // 0..63
        float b2 = b2sum[nb * 256 + nc * 64 + col_l];
        #pragma unroll
        for (int m = 0; m < 2; ++m) {
          #pragma unroll
          for (int i = 0; i < 4; ++i) {
            int row_l = wm * 32 + m * 16 + q * 4 + i;
            float x = acc[m][(nc & 1) * 4 + uu][i] + b2;
            xs[row_l][col_l] = 1.f / (1.f + __expf(-x));
            cs[row_l][col_l] = (bf16)cacc[m][uu][i];
          }
        }
      }
    }
    __syncthreads();
    {  // combine pass: all threads, coalesced e read / r write
      int row_l = tid >> 2, sub = tid & 3;
      size_t rowoff = (size_t)(b0 + row_l) * 2048 + (size_t)tt * 1024;
      #pragma unroll
      for (int h = 0; h < 2; ++h) {
        int lcol = sub * 16 + h * 8;
        int gcol = nb * 256 + nc * 64 + lcol;
        bf16x8 ebv = *reinterpret_cast<const bf16x8*>(r_ws + rowoff + gcol);
        f32x4 w0 = *reinterpret_cast<const f32x4*>(&xs[row_l][lcol]);
        f32x4 w1 = *reinterpret_cast<const f32x4*>(&xs[row_l][lcol + 4]);
        bf16x8 cv = *reinterpret_cast<const bf16x8*>(&cs[row_l][lcol]);
        bf16x8 rv;
        #pragma unroll
        for (int jj = 0; jj < 8; ++jj) {
          float e = (float)ebv[jj], c = (float)cv[jj];
          float w = (jj < 4) ? w0[jj] : w1[jj - 4];
          rv[jj] = (bf16)(2.f * (e + w * (c - e)));
        }
        *reinterpret_cast<bf16x8*>(r_ws + rowoff + gcol) = rv;
      }
    }
    __syncthreads();
  }
}

// ---------------- K3: final — out = sigmoid(relu(r@fw1T+fb1)@fw2T+fb2), M=64 ----------------

__global__ __launch_bounds__(512, 4)
void fused_final(const bf16* __restrict__ r_ws, const bf16* __restrict__ F1f,
                 const float* __restrict__ fb1, const float* __restrict__ fw2,
                 const float* __restrict__ fb2, float* __restrict__ out) {
  const int b0 = blockIdx.x * 64;
  const int tid = threadIdx.x;
  const int lane = tid & 63;
  const int wv = tid >> 6;
  const int arow = lane & 15;
  const int q    = lane >> 4;
  const int kgrp = q << 3;

  __shared__ bf16 RT[2][64][264];
  float (*H2)[260] = reinterpret_cast<float (*)[260]>(&RT[0][0][0]);

  bf16x8 sv[4];
  auto SLOAD = [&](int kc) {
    #pragma unroll
    for (int g = 0; g < 4; ++g) {
      int f = g * 512 + tid;
      int row = f >> 5, colg = f & 31;
      sv[g] = *reinterpret_cast<const bf16x8*>(r_ws + (size_t)(b0 + row) * 2048 + kc * 256 + colg * 8);
    }
  };
  auto SWRITE = [&](int buf) {
    #pragma unroll
    for (int g = 0; g < 4; ++g) {
      int f = g * 512 + tid;
      int row = f >> 5, colg = f & 31;
      *reinterpret_cast<bf16x8*>(&RT[buf][row][colg * 8]) = sv[g];
    }
  };

  SLOAD(0); SWRITE(0);
  __syncthreads();

  f32x4 acc[4][2] = {};
  #pragma unroll 1
  for (int kc = 0; kc < 8; ++kc) {
    if (kc < 7) SLOAD(kc + 1);
    #pragma unroll
    for (int ks = 0; ks < 8; ++ks) {
      int ksg = kc * 8 + ks;
      bf16x8 a[4];
      #pragma unroll
      for (int m = 0; m < 4; ++m)
        a[m] = *reinterpret_cast<const bf16x8*>(&RT[kc & 1][m * 16 + arow][ks * 32 + kgrp]);
      #pragma unroll
      for (int u = 0; u < 2; ++u) {
        bf16x8 b = *reinterpret_cast<const bf16x8*>(F1f + (((size_t)(ksg * 16 + wv * 2 + u)) << 9) + lane * 8);
        #pragma unroll
        for (int m = 0; m < 4; ++m)
          acc[m][u] = MFMA(a[m], b, acc[m][u]);
      }
    }
    if (kc < 7) SWRITE((kc + 1) & 1);
    __syncthreads();
  }

  #pragma unroll
  for (int u = 0; u < 2; ++u) {
    int col = (wv * 2 + u) * 16 + arow;
    float bb = fb1[col];
    #pragma unroll
    for (int m = 0; m < 4; ++m) {
      #pragma unroll
      for (int i2 = 0; i2 < 4; ++i2) {
        int row = m * 16 + q * 4 + i2;
        H2[row][col] = fmaxf(acc[m][u][i2] + bb, 0.f);
      }
    }
  }
  __syncthreads();

  int row = tid >> 3, sub = tid & 7;
  float p = 0.f;
  #pragma unroll
  for (int c = 0; c < 32; ++c) p += H2[row][sub * 32 + c] * fw2[sub * 32 + c];
  p += __shfl_xor(p, 1, 8);
  p += __shfl_xor(p, 2, 8);
  p += __shfl_xor(p, 4, 8);
  if (sub == 0) out[b0 + row] = 1.f / (1.f + __expf(-(p + fb2[0])));
}

// ---------------- launcher ----------------

extern "C" void kernel_launch(void* const* d_in, const int* in_sizes, int n_in,
                              void* d_out, int out_size, void* d_ws, size_t ws_size,
                              hipStream_t stream) {
  const float* name1 = (const float*)d_in[0];
  const float* type1 = (const float*)d_in[1];
  const float* coor1 = (const float*)d_in[2];
  const float* name2 = (const float*)d_in[3];
  const float* type2 = (const float*)d_in[4];
  const float* coor2 = (const float*)d_in[5];
  const float* cw    = (const float*)d_in[6];
  const float* cb    = (const float*)d_in[7];
  const float* l1w = (const float*)d_in[8];  const float* l1b = (const float*)d_in[9];
  const float* l1g = (const float*)d_in[10]; const float* l1be = (const float*)d_in[11];
  const float* l1m = (const float*)d_in[12]; const float* l1v = (const float*)d_in[13];
  const float* l2w = (const float*)d_in[14]; const float* l2b = (const float*)d_in[15];
  const float* l2g = (const float*)d_in[16]; const float* l2be = (const float*)d_in[17];
  const float* l2m = (const float*)d_in[18]; const float* l2v = (const float*)d_in[19];
  const float* g1w = (const float*)d_in[20]; const float* g1b = (const float*)d_in[21];
  const float* g1g = (const float*)d_in[22]; const float* g1be = (const float*)d_in[23];
  const float* g1m = (const float*)d_in[24]; const float* g1v = (const float*)d_in[25];
  const float* g2w = (const float*)d_in[26]; const float* g2b = (const float*)d_in[27];
  const float* g2g = (const float*)d_in[28]; const float* g2be = (const float*)d_in[29];
  const float* g2m = (const float*)d_in[30]; const float* g2v = (const float*)d_in[31];
  const float* fw1 = (const float*)d_in[32]; const float* fb1 = (const float*)d_in[33];
  const float* fw2 = (const float*)d_in[34]; const float* fb2 = (const float*)d_in[35];

  char* ws = (char*)d_ws;
  bf16*  W1f   = (bf16*)(ws + 0);          // 512*1088 bf16   = 1,114,112 B
  bf16*  W2f   = (bf16*)(ws + 1114112);    // 1024*512 bf16   = 1,048,576 B
  bf16*  CWf   = (bf16*)(ws + 2162688);    // 1024*64  bf16   =   131,072 B
  bf16*  F1f   = (bf16*)(ws + 2293760);    // 256*2048 bf16   = 1,048,576 B
  float* b1cat = (float*)(ws + 3342336);   // 512 f32
  float* b2sum = (float*)(ws + 3344384);   // 1024 f32
  bf16*  h_ws  = (bf16*)(ws + 3407872);    // [2][16384][512]  = 33,554,432 B
  bf16*  r_ws  = (bf16*)(ws + 36962304);   // [16384][2048]    = 67,108,864 B (holds e, then r)

  prep_w1main<<<2048, 256, 0, stream>>>(l1w, l1g, l1v, g1w, g1g, g1v, W1f);
  prep_w1tail<<<512, 512, 0, stream>>>(l1w, l1b, l1g, l1be, l1m, l1v,
                                       g1w, g1b, g1g, g1be, g1m, g1v, cw, cb, W1f, b1cat);
  prep_w2<<<2048, 256, 0, stream>>>(l2w, l2b, l2g, l2be, l2m, l2v,
                                    g2w, g2b, g2g, g2be, g2m, g2v, W2f, b2sum);
  prep_cwf<<<256, 256, 0, stream>>>(cw, cb, CWf);
  prep_f1f<<<2048, 256, 0, stream>>>(fw1, F1f);

  gemm1<<<512, 1024, 0, stream>>>(name1, type1, coor1, name2, type2, coor2, W1f, b1cat, h_ws, r_ws);
  gemm2<<<1024, 512, 0, stream>>>(coor1, coor2, W2f, CWf, b2sum, h_ws, r_ws);
  fused_final<<<256, 512, 0, stream>>>(r_ws, F1f, fb1, fw2, fb2, (float*)d_out);
}

// Round 8
// 349.847 us; speedup vs baseline: 1.6413x; 1.0089x over previous
//
#include <hip/hip_runtime.h>

typedef __bf16 bf16;
typedef __bf16 bf16x8 __attribute__((ext_vector_type(8)));
typedef __bf16 bf16x4 __attribute__((ext_vector_type(4)));
typedef float  f32x4  __attribute__((ext_vector_type(4)));

#define BN_EPS 1e-5f
#define MFMA(a, b, c) __builtin_amdgcn_mfma_f32_16x16x32_bf16((a), (b), (c), 0, 0, 0)
#define BAR() do { __builtin_amdgcn_sched_barrier(0); \
                   asm volatile("s_waitcnt lgkmcnt(0)" ::: "memory"); \
                   __builtin_amdgcn_s_barrier(); \
                   __builtin_amdgcn_sched_barrier(0); } while (0)

// Fragment-linear offset for MFMA B-operand matrix [N][K] (16x16x32 tiles):
// tile = (k/32)*ntiles + n/16 ; within tile: lane = ((k%32)/8)*16 + n%16, elem = k%8
__device__ __host__ __forceinline__ size_t frag_off(int n, int k, int ntiles) {
  return ((size_t)((k >> 5) * ntiles + (n >> 4)) << 9)
       + (size_t)((((k >> 3) & 3) << 4) + (n & 15)) * 8 + (k & 7);
}

// ---------------- prep kernels ----------------

__global__ void prep_w1main(const float* __restrict__ l1w, const float* __restrict__ l1g, const float* __restrict__ l1v,
                            const float* __restrict__ g1w, const float* __restrict__ g1g, const float* __restrict__ g1v,
                            bf16* __restrict__ W1f) {
  int gid = blockIdx.x * blockDim.x + threadIdx.x;   // 512*1024
  int n = gid >> 10, k = gid & 1023;
  float s, w;
  if (n < 256) { s = l1g[n] * rsqrtf(l1v[n] + BN_EPS); w = l1w[(size_t)n * 1024 + k]; }
  else { int nn = n - 256; s = g1g[nn] * rsqrtf(g1v[nn] + BN_EPS); w = g1w[(size_t)nn * 1024 + k]; }
  W1f[frag_off(n, k, 32)] = (bf16)(w * s);
}

__global__ __launch_bounds__(512)
void prep_w1tail(const float* __restrict__ l1w, const float* __restrict__ l1b, const float* __restrict__ l1g,
                 const float* __restrict__ l1be, const float* __restrict__ l1m, const float* __restrict__ l1v,
                 const float* __restrict__ g1w, const float* __restrict__ g1b, const float* __restrict__ g1g,
                 const float* __restrict__ g1be, const float* __restrict__ g1m, const float* __restrict__ g1v,
                 const float* __restrict__ cw, const float* __restrict__ cb,
                 bf16* __restrict__ W1f, float* __restrict__ b1cat) {
  int n = blockIdx.x;
  int kc = threadIdx.x & 63, js = threadIdx.x >> 6;
  const float* wrow; float s, bb, mm, be;
  if (n < 256) { s = l1g[n] * rsqrtf(l1v[n] + BN_EPS); wrow = l1w + (size_t)n * 1024;
                 bb = l1b[n]; mm = l1m[n]; be = l1be[n]; }
  else { int nn = n - 256; s = g1g[nn] * rsqrtf(g1v[nn] + BN_EPS); wrow = g1w + (size_t)nn * 1024;
         bb = g1b[nn]; mm = g1m[nn]; be = g1be[nn]; }
  float a = 0.f;
  if (kc < 49) {
    #pragma unroll 4
    for (int jj = 0; jj < 128; ++jj) {
      int j = js * 128 + jj;
      float cv = (kc < 48) ? cw[(size_t)j * 48 + kc] : cb[j];
      a += wrow[j] * cv;
    }
  }
  __shared__ float red[8][64];
  red[js][kc] = a;
  __syncthreads();
  if (threadIdx.x < 64) {
    float v = 0.f;
    #pragma unroll
    for (int r = 0; r < 8; ++r) v += red[r][threadIdx.x];
    W1f[frag_off(n, 1024 + threadIdx.x, 32)] = (bf16)((threadIdx.x < 49) ? v * s : 0.f);
  }
  if (threadIdx.x == 0) b1cat[n] = s * (bb - mm) + be;
}

__global__ void prep_w2(const float* __restrict__ l2w, const float* __restrict__ l2b, const float* __restrict__ l2g,
                        const float* __restrict__ l2be, const float* __restrict__ l2m, const float* __restrict__ l2v,
                        const float* __restrict__ g2w, const float* __restrict__ g2b, const float* __restrict__ g2g,
                        const float* __restrict__ g2be, const float* __restrict__ g2m, const float* __restrict__ g2v,
                        bf16* __restrict__ W2f, float* __restrict__ b2sum) {
  int gid = blockIdx.x * blockDim.x + threadIdx.x;   // 1024*512
  int n = gid >> 9, k = gid & 511;
  float w;
  if (k < 256) { float s = l2g[n] * rsqrtf(l2v[n] + BN_EPS); w = l2w[(size_t)n * 256 + k] * s; }
  else { float s = g2g[n] * rsqrtf(g2v[n] + BN_EPS); w = g2w[(size_t)n * 256 + (k - 256)] * s; }
  W2f[frag_off(n, k, 64)] = (bf16)w;
  if (k == 0) {
    float sl = l2g[n] * rsqrtf(l2v[n] + BN_EPS), sg = g2g[n] * rsqrtf(g2v[n] + BN_EPS);
    b2sum[n] = sl * (l2b[n] - l2m[n]) + l2be[n] + sg * (g2b[n] - g2m[n]) + g2be[n];
  }
}

__global__ void prep_cwf(const float* __restrict__ cw, const float* __restrict__ cb, bf16* __restrict__ CWf) {
  int gid = blockIdx.x * blockDim.x + threadIdx.x;   // 1024*64
  int n = gid >> 6, kc = gid & 63;
  float v = (kc < 48) ? cw[(size_t)n * 48 + kc] : (kc == 48 ? cb[n] : 0.f);
  CWf[frag_off(n, kc, 64)] = (bf16)v;
}

__global__ void prep_f1f(const float* __restrict__ fw1, bf16* __restrict__ F1f) {
  int gid = blockIdx.x * blockDim.x + threadIdx.x;   // 256*2048
  int n = gid >> 11, k = gid & 2047;
  F1f[frag_off(n, k, 16)] = (bf16)fw1[(size_t)n * 2048 + k];
}

// ---------------- K1: gemm1 — h = relu(e @ W1catT + b1cat); emits e (bf16) to r_ws and c to c_ws ----------------
// M=128, N=256 (h) + 512 (c); 1024 thr; depth-2 named-reg pipeline, raw barrier (no vmcnt drain).

__global__ __launch_bounds__(1024, 4)
void gemm1(const float* __restrict__ name1, const float* __restrict__ type1, const float* __restrict__ coor1,
           const float* __restrict__ name2, const float* __restrict__ type2, const float* __restrict__ coor2,
           const bf16* __restrict__ W1f, const bf16* __restrict__ CWf, const float* __restrict__ b1cat,
           bf16* __restrict__ h_ws, bf16* __restrict__ c_ws, bf16* __restrict__ r_ws) {
  const int bid = blockIdx.x;
  const int xcd = bid & 7, slot = bid >> 3;
  const int nb = slot & 1;
  const int lg = xcd * 32 + (slot >> 1);   // 0..255 bijective
  const int tt = lg >> 7;
  const int mb = lg & 127;
  const float* __restrict__ name = tt ? name2 : name1;
  const float* __restrict__ typ  = tt ? type2 : type1;
  const float* __restrict__ coor = tt ? coor2 : coor1;
  const int b0 = mb * 128;
  const int tid = threadIdx.x;
  const int lane = tid & 63;
  const int wv = tid >> 6;           // 0..15
  const int wm = wv >> 2;            // 0..3: 32-row group
  const int wn = wv & 3;             // 0..3
  const int arow = lane & 15;
  const int q = lane >> 4;
  const int kgrp = q << 3;

  __shared__ __align__(16) char SM[67584];
  bf16 (*EB)[128][72] = reinterpret_cast<bf16 (*)[128][72]>(SM);   // 2 bufs x 18,432 B
  bf16 (*hb)[264] = reinterpret_cast<bf16 (*)[264]>(SM);           // overlay after k-loop

  const int srow = tid >> 3;         // 0..127
  const int scg = tid & 7;

  const float4* name4 = reinterpret_cast<const float4*>(name);
  const float4* typ4  = reinterpret_cast<const float4*>(typ);
  const float4* coor4 = reinterpret_cast<const float4*>(coor);

  // two NAMED register sets (rule #20): A = even phases (+tail 16), B = odd phases
  float4 nA0, tA0, nA1, tA1, nB0, tB0, nB1, tB1;

  auto REGLOAD_A = [&](int pp) {
    if (pp < 16) {
      size_t base = (size_t)(b0 + srow) * 256 + (size_t)pp * 16 + scg;
      nA0 = name4[base];     tA0 = typ4[base];
      nA1 = name4[base + 8]; tA1 = typ4[base + 8];
    } else {                              // tail: [coor(48) | 1 | 0...]
      nA0 = coor4[(size_t)(b0 + srow) * 12 + scg];
      tA0 = make_float4(0.f, 0.f, 0.f, 0.f);
      int idx = 8 + scg;
      if (idx < 12)       nA1 = coor4[(size_t)(b0 + srow) * 12 + idx];
      else if (idx == 12) nA1 = make_float4(1.f, 0.f, 0.f, 0.f);
      else                nA1 = make_float4(0.f, 0.f, 0.f, 0.f);
      tA1 = make_float4(0.f, 0.f, 0.f, 0.f);
    }
  };
  auto REGLOAD_B = [&](int pp) {
    size_t base = (size_t)(b0 + srow) * 256 + (size_t)pp * 16 + scg;
    nB0 = name4[base];     tB0 = typ4[base];
    nB1 = name4[base + 8]; tB1 = typ4[base + 8];
  };
  auto PACK = [&](const float4& nv, const float4& tv) {
    bf16x4 e;
    e[0] = (bf16)(nv.x + tv.x); e[1] = (bf16)(nv.y + tv.y);
    e[2] = (bf16)(nv.z + tv.z); e[3] = (bf16)(nv.w + tv.w);
    return e;
  };
  auto WRITEB_A = [&](int buf) {
    *reinterpret_cast<bf16x4*>(&EB[buf][srow][scg * 4]) = PACK(nA0, tA0);
    *reinterpret_cast<bf16x4*>(&EB[buf][srow][32 + scg * 4]) = PACK(nA1, tA1);
  };
  auto WRITEB_B = [&](int buf) {
    *reinterpret_cast<bf16x4*>(&EB[buf][srow][scg * 4]) = PACK(nB0, tB0);
    *reinterpret_cast<bf16x4*>(&EB[buf][srow][32 + scg * 4]) = PACK(nB1, tB1);
  };
  auto EWRITE_A = [&](int pp) {
    size_t rb = (size_t)(b0 + srow) * 2048 + (size_t)tt * 1024 + pp * 64;
    *reinterpret_cast<bf16x4*>(r_ws + rb + scg * 4) = PACK(nA0, tA0);
    *reinterpret_cast<bf16x4*>(r_ws + rb + 32 + scg * 4) = PACK(nA1, tA1);
  };
  auto EWRITE_B = [&](int pp) {
    size_t rb = (size_t)(b0 + srow) * 2048 + (size_t)tt * 1024 + pp * 64;
    *reinterpret_cast<bf16x4*>(r_ws + rb + scg * 4) = PACK(nB0, tB0);
    *reinterpret_cast<bf16x4*>(r_ws + rb + 32 + scg * 4) = PACK(nB1, tB1);
  };

  f32x4 acc[2][4] = {};
  auto MFMA_PHASE = [&](int p, int buf) {
    #pragma unroll
    for (int ks2 = 0; ks2 < 2; ++ks2) {
      int kk = p * 2 + ks2;
      bf16x8 a0 = *reinterpret_cast<const bf16x8*>(&EB[buf][wm * 32 + arow][ks2 * 32 + kgrp]);
      bf16x8 a1 = *reinterpret_cast<const bf16x8*>(&EB[buf][wm * 32 + 16 + arow][ks2 * 32 + kgrp]);
      #pragma unroll
      for (int u = 0; u < 4; ++u) {
        bf16x8 b = *reinterpret_cast<const bf16x8*>(W1f + (((size_t)(kk * 32 + nb * 16 + wn * 4 + u)) << 9) + lane * 8);
        acc[0][u] = MFMA(a0, b, acc[0][u]);
        acc[1][u] = MFMA(a1, b, acc[1][u]);
      }
    }
  };

  // prologue
  REGLOAD_A(0); REGLOAD_B(1);
  WRITEB_A(0); EWRITE_A(0);
  REGLOAD_A(2);
  BAR();

  #pragma unroll 1
  for (int j = 0; j < 8; ++j) {
    const int p0 = 2 * j;
    WRITEB_B(1); EWRITE_B(p0 + 1);
    if (p0 + 3 < 16) REGLOAD_B(p0 + 3);
    MFMA_PHASE(p0, 0);
    BAR();
    WRITEB_A(0);
    if (p0 + 2 <= 15) EWRITE_A(p0 + 2);
    if (p0 + 4 <= 16) REGLOAD_A(p0 + 4);
    MFMA_PHASE(p0 + 1, 1);
    BAR();
  }
  MFMA_PHASE(16, 0);                          // coor tail (EB[0] holds [coor|1|0])

  // hoist coor-tail fragments to registers before hb overlays EB[0]
  bf16x8 ca00 = *reinterpret_cast<const bf16x8*>(&EB[0][wm * 32 + arow][kgrp]);
  bf16x8 ca01 = *reinterpret_cast<const bf16x8*>(&EB[0][wm * 32 + arow][32 + kgrp]);
  bf16x8 ca10 = *reinterpret_cast<const bf16x8*>(&EB[0][wm * 32 + 16 + arow][kgrp]);
  bf16x8 ca11 = *reinterpret_cast<const bf16x8*>(&EB[0][wm * 32 + 16 + arow][32 + kgrp]);
  BAR();                                      // all EB reads drained before overlay

  // ---- h = relu(acc + b1cat) via LDS bounce, then coalesced store (acc dies here) ----
  #pragma unroll
  for (int u = 0; u < 4; ++u) {
    int col = (wn * 4 + u) * 16 + arow;
    float bb = b1cat[nb * 256 + col];
    #pragma unroll
    for (int m = 0; m < 2; ++m) {
      #pragma unroll
      for (int i = 0; i < 4; ++i)
        hb[wm * 32 + m * 16 + q * 4 + i][col] = (bf16)fmaxf(acc[m][u][i] + bb, 0.f);
    }
  }
  BAR();
  #pragma unroll
  for (int g = 0; g < 4; ++g) {
    int idx = g * 1024 + tid;
    int row = idx >> 5, cg = idx & 31;
    *reinterpret_cast<bf16x8*>(h_ws + ((size_t)tt * 16384 + b0 + row) * 512 + nb * 256 + cg * 8) =
      *reinterpret_cast<const bf16x8*>(&hb[row][cg * 8]);
  }

  // ---- c = [coor|1|0] @ CWfT : 512 cols (nb half of 1024); cacc after acc dead ----
  f32x4 cacc[2][8] = {};
  #pragma unroll
  for (int u = 0; u < 8; ++u) {
    int ntile = nb * 32 + wn * 8 + u;
    bf16x8 cb0 = *reinterpret_cast<const bf16x8*>(CWf + (((size_t)ntile) << 9) + lane * 8);
    bf16x8 cb1 = *reinterpret_cast<const bf16x8*>(CWf + (((size_t)(64 + ntile)) << 9) + lane * 8);
    cacc[0][u] = MFMA(ca00, cb0, cacc[0][u]);
    cacc[0][u] = MFMA(ca01, cb1, cacc[0][u]);
    cacc[1][u] = MFMA(ca10, cb0, cacc[1][u]);
    cacc[1][u] = MFMA(ca11, cb1, cacc[1][u]);
  }

  // ---- bounce c through hb in two 256-col passes, coalesced store to c_ws ----
  #pragma unroll
  for (int p = 0; p < 2; ++p) {
    BAR();                                   // prior hb readers done
    if ((wn >> 1) == p) {                    // wave-uniform
      #pragma unroll
      for (int u = 0; u < 8; ++u) {
        int col = (wn & 1) * 128 + u * 16 + arow;   // 0..255 within pass
        #pragma unroll
        for (int m = 0; m < 2; ++m) {
          #pragma unroll
          for (int i = 0; i < 4; ++i)
            hb[wm * 32 + m * 16 + q * 4 + i][col] = (bf16)cacc[m][u][i];
        }
      }
    }
    BAR();
    #pragma unroll
    for (int g = 0; g < 4; ++g) {
      int idx = g * 1024 + tid;
      int row = idx >> 5, cg = idx & 31;
      *reinterpret_cast<bf16x8*>(c_ws + ((size_t)tt * 16384 + b0 + row) * 1024 + nb * 512 + p * 256 + cg * 8) =
        *reinterpret_cast<const bf16x8*>(&hb[row][cg * 8]);
    }
  }
}

// ---------------- K2: gemm2 — wei = sigmoid(h@W2T+b2); r = 2e + 2*wei*(c-e) ----------------
// M=128, N=256; h LDS-staged depth-2 pipeline; combine via xs f32 LDS bounce (2 passes of 128 cols).

__global__ __launch_bounds__(512, 4)
void gemm2(const bf16* __restrict__ W2f, const float* __restrict__ b2sum,
           const bf16* __restrict__ h_ws, const bf16* __restrict__ c_ws, bf16* __restrict__ r_ws) {
  const int bid = blockIdx.x;            // 1024 blocks
  const int xcd = bid & 7, s = bid >> 3; // s: [tt(1)][nb(2)][mhi(4)]
  const int mb = xcd + 8 * (s & 15);     // nb-quad of one (mb,tt) shares an XCD
  const int nb = (s >> 4) & 3;           // 256-col quarter
  const int tt = s >> 6;
  const int b0 = mb * 128;
  const int tid = threadIdx.x;
  const int lane = tid & 63;
  const int wv = tid >> 6;               // 0..7
  const int wm = wv >> 1;                // 0..3: 32-row group
  const int wn2 = wv & 1;                // 0..1: 128-col half
  const int arow = lane & 15;
  const int q = lane >> 4;
  const int kgrp = q << 3;

  __shared__ __align__(16) char SM[67584];
  bf16 (*HB)[128][72] = reinterpret_cast<bf16 (*)[128][72]>(SM);   // 2 x 18,432 B
  float (*xs)[132] = reinterpret_cast<float (*)[132]>(SM);         // overlay post k-loop, 67,584 B

  const bf16* hbase = h_ws + ((size_t)tt * 16384 + b0) * 512;
  const int srow = tid >> 2, scg = tid & 3;

  bf16x8 hA0, hA1, hB0, hB1;
  auto LOADH_A = [&](int kc) {
    const bf16* p = hbase + (size_t)srow * 512 + kc * 64 + scg * 16;
    hA0 = *reinterpret_cast<const bf16x8*>(p);
    hA1 = *reinterpret_cast<const bf16x8*>(p + 8);
  };
  auto LOADH_B = [&](int kc) {
    const bf16* p = hbase + (size_t)srow * 512 + kc * 64 + scg * 16;
    hB0 = *reinterpret_cast<const bf16x8*>(p);
    hB1 = *reinterpret_cast<const bf16x8*>(p + 8);
  };
  auto WRITEH_A = [&](int buf) {
    *reinterpret_cast<bf16x8*>(&HB[buf][srow][scg * 16]) = hA0;
    *reinterpret_cast<bf16x8*>(&HB[buf][srow][scg * 16 + 8]) = hA1;
  };
  auto WRITEH_B = [&](int buf) {
    *reinterpret_cast<bf16x8*>(&HB[buf][srow][scg * 16]) = hB0;
    *reinterpret_cast<bf16x8*>(&HB[buf][srow][scg * 16 + 8]) = hB1;
  };

  f32x4 acc[2][8] = {};
  auto MFMA_CHUNK = [&](int kc, int buf) {
    #pragma unroll
    for (int kt = 0; kt < 2; ++kt) {
      bf16x8 a0 = *reinterpret_cast<const bf16x8*>(&HB[buf][wm * 32 + arow][kt * 32 + kgrp]);
      bf16x8 a1 = *reinterpret_cast<const bf16x8*>(&HB[buf][wm * 32 + 16 + arow][kt * 32 + kgrp]);
      #pragma unroll
      for (int u = 0; u < 8; ++u) {
        bf16x8 b = *reinterpret_cast<const bf16x8*>(
            W2f + (((size_t)((kc * 2 + kt) * 64 + nb * 16 + wn2 * 8 + u)) << 9) + lane * 8);
        acc[0][u] = MFMA(a0, b, acc[0][u]);
        acc[1][u] = MFMA(a1, b, acc[1][u]);
      }
    }
  };

  // prologue: HB[0]=chunk0; B holds c1; A holds c2 (in flight)
  LOADH_A(0); LOADH_B(1);
  WRITEH_A(0);
  LOADH_A(2);
  BAR();

  #pragma unroll 1
  for (int j = 0; j < 4; ++j) {
    const int c0 = 2 * j;
    WRITEH_B(1);
    if (c0 + 3 < 8) LOADH_B(c0 + 3);
    MFMA_CHUNK(c0, 0);
    BAR();
    if (c0 + 2 < 8) WRITEH_A(0);
    if (c0 + 4 < 8) LOADH_A(c0 + 4);
    MFMA_CHUNK(c0 + 1, 1);
    BAR();                                   // last iter: HB reads drained -> xs overlay safe
  }

  // ---- combine in two 128-col passes: xs = sigmoid(acc+b2) -> vectorized r ----
  #pragma unroll
  for (int hc = 0; hc < 2; ++hc) {
    if (wn2 == hc) {                         // wave-uniform
      #pragma unroll
      for (int u = 0; u < 8; ++u) {
        int lcol = u * 16 + arow;
        float b2 = b2sum[nb * 256 + hc * 128 + lcol];
        #pragma unroll
        for (int m = 0; m < 2; ++m) {
          #pragma unroll
          for (int i = 0; i < 4; ++i)
            xs[wm * 32 + m * 16 + q * 4 + i][lcol] = 1.f / (1.f + __expf(-(acc[m][u][i] + b2)));
        }
      }
    }
    __syncthreads();
    {
      int row = tid >> 2, sc = tid & 3;
      size_t ebase = (size_t)(b0 + row) * 2048 + (size_t)tt * 1024 + nb * 256 + hc * 128;
      size_t cbase = ((size_t)tt * 16384 + b0 + row) * 1024 + nb * 256 + hc * 128;
      #pragma unroll
      for (int g = 0; g < 4; ++g) {
        int c8 = g * 32 + sc * 8;
        bf16x8 ebv = *reinterpret_cast<const bf16x8*>(r_ws + ebase + c8);
        bf16x8 cv  = *reinterpret_cast<const bf16x8*>(c_ws + cbase + c8);
        f32x4 w0 = *reinterpret_cast<const f32x4*>(&xs[row][c8]);
        f32x4 w1 = *reinterpret_cast<const f32x4*>(&xs[row][c8 + 4]);
        bf16x8 rv;
        #pragma unroll
        for (int jj = 0; jj < 8; ++jj) {
          float e = (float)ebv[jj], c = (float)cv[jj];
          float w = (jj < 4) ? w0[jj] : w1[jj - 4];
          rv[jj] = (bf16)(2.f * (e + w * (c - e)));
        }
        *reinterpret_cast<bf16x8*>(r_ws + ebase + c8) = rv;
      }
    }
    __syncthreads();
  }
}

// ---------------- K3: final — out = sigmoid(relu(r@fw1T+fb1)@fw2T+fb2), M=64 ----------------

__global__ __launch_bounds__(512, 4)
void fused_final(const bf16* __restrict__ r_ws, const bf16* __restrict__ F1f,
                 const float* __restrict__ fb1, const float* __restrict__ fw2,
                 const float* __restrict__ fb2, float* __restrict__ out) {
  const int b0 = blockIdx.x * 64;
  const int tid = threadIdx.x;
  const int lane = tid & 63;
  const int wv = tid >> 6;
  const int arow = lane & 15;
  const int q    = lane >> 4;
  const int kgrp = q << 3;

  __shared__ bf16 RT[2][64][264];
  float (*H2)[260] = reinterpret_cast<float (*)[260]>(&RT[0][0][0]);

  bf16x8 sv[4];
  auto SLOAD = [&](int kc) {
    #pragma unroll
    for (int g = 0; g < 4; ++g) {
      int f = g * 512 + tid;
      int row = f >> 5, colg = f & 31;
      sv[g] = *reinterpret_cast<const bf16x8*>(r_ws + (size_t)(b0 + row) * 2048 + kc * 256 + colg * 8);
    }
  };
  auto SWRITE = [&](int buf) {
    #pragma unroll
    for (int g = 0; g < 4; ++g) {
      int f = g * 512 + tid;
      int row = f >> 5, colg = f & 31;
      *reinterpret_cast<bf16x8*>(&RT[buf][row][colg * 8]) = sv[g];
    }
  };

  SLOAD(0); SWRITE(0);
  __syncthreads();

  f32x4 acc[4][2] = {};
  #pragma unroll 1
  for (int kc = 0; kc < 8; ++kc) {
    if (kc < 7) SLOAD(kc + 1);
    #pragma unroll
    for (int ks = 0; ks < 8; ++ks) {
      int ksg = kc * 8 + ks;
      bf16x8 a[4];
      #pragma unroll
      for (int m = 0; m < 4; ++m)
        a[m] = *reinterpret_cast<const bf16x8*>(&RT[kc & 1][m * 16 + arow][ks * 32 + kgrp]);
      #pragma unroll
      for (int u = 0; u < 2; ++u) {
        bf16x8 b = *reinterpret_cast<const bf16x8*>(F1f + (((size_t)(ksg * 16 + wv * 2 + u)) << 9) + lane * 8);
        #pragma unroll
        for (int m = 0; m < 4; ++m)
          acc[m][u] = MFMA(a[m], b, acc[m][u]);
      }
    }
    if (kc < 7) SWRITE((kc + 1) & 1);
    __syncthreads();
  }

  #pragma unroll
  for (int u = 0; u < 2; ++u) {
    int col = (wv * 2 + u) * 16 + arow;
    float bb = fb1[col];
    #pragma unroll
    for (int m = 0; m < 4; ++m) {
      #pragma unroll
      for (int i2 = 0; i2 < 4; ++i2) {
        int row = m * 16 + q * 4 + i2;
        H2[row][col] = fmaxf(acc[m][u][i2] + bb, 0.f);
      }
    }
  }
  __syncthreads();

  int row = tid >> 3, sub = tid & 7;
  float p = 0.f;
  #pragma unroll
  for (int c = 0; c < 32; ++c) p += H2[row][sub * 32 + c] * fw2[sub * 32 + c];
  p += __shfl_xor(p, 1, 8);
  p += __shfl_xor(p, 2, 8);
  p += __shfl_xor(p, 4, 8);
  if (sub == 0) out[b0 + row] = 1.f / (1.f + __expf(-(p + fb2[0])));
}

// ---------------- launcher ----------------

extern "C" void kernel_launch(void* const* d_in, const int* in_sizes, int n_in,
                              void* d_out, int out_size, void* d_ws, size_t ws_size,
                              hipStream_t stream) {
  const float* name1 = (const float*)d_in[0];
  const float* type1 = (const float*)d_in[1];
  const float* coor1 = (const float*)d_in[2];
  const float* name2 = (const float*)d_in[3];
  const float* type2 = (const float*)d_in[4];
  const float* coor2 = (const float*)d_in[5];
  const float* cw    = (const float*)d_in[6];
  const float* cb    = (const float*)d_in[7];
  const float* l1w = (const float*)d_in[8];  const float* l1b = (const float*)d_in[9];
  const float* l1g = (const float*)d_in[10]; const float* l1be = (const float*)d_in[11];
  const float* l1m = (const float*)d_in[12]; const float* l1v = (const float*)d_in[13];
  const float* l2w = (const float*)d_in[14]; const float* l2b = (const float*)d_in[15];
  const float* l2g = (const float*)d_in[16]; const float* l2be = (const float*)d_in[17];
  const float* l2m = (const float*)d_in[18]; const float* l2v = (const float*)d_in[19];
  const float* g1w = (const float*)d_in[20]; const float* g1b = (const float*)d_in[21];
  const float* g1g = (const float*)d_in[22]; const float* g1be = (const float*)d_in[23];
  const float* g1m = (const float*)d_in[24]; const float* g1v = (const float*)d_in[25];
  const float* g2w = (const float*)d_in[26]; const float* g2b = (const float*)d_in[27];
  const float* g2g = (const float*)d_in[28]; const float* g2be = (const float*)d_in[29];
  const float* g2m = (const float*)d_in[30]; const float* g2v = (const float*)d_in[31];
  const float* fw1 = (const float*)d_in[32]; const float* fb1 = (const float*)d_in[33];
  const float* fw2 = (const float*)d_in[34]; const float* fb2 = (const float*)d_in[35];

  char* ws = (char*)d_ws;
  bf16*  W1f   = (bf16*)(ws + 0);          // 512*1088 bf16   = 1,114,112 B
  bf16*  W2f   = (bf16*)(ws + 1114112);    // 1024*512 bf16   = 1,048,576 B
  bf16*  CWf   = (bf16*)(ws + 2162688);    // 1024*64  bf16   =   131,072 B
  bf16*  F1f   = (bf16*)(ws + 2293760);    // 256*2048 bf16   = 1,048,576 B
  float* b1cat = (float*)(ws + 3342336);   // 512 f32
  float* b2sum = (float*)(ws + 3344384);   // 1024 f32
  bf16*  h_ws  = (bf16*)(ws + 3407872);    // [2][16384][512]  = 33,554,432 B
  bf16*  r_ws  = (bf16*)(ws + 36962304);   // [16384][2048]    = 67,108,864 B (holds e, then r)
  bf16*  c_ws  = (bf16*)(ws + 104071168);  // [2][16384][1024] = 67,108,864 B

  prep_w1main<<<2048, 256, 0, stream>>>(l1w, l1g, l1v, g1w, g1g, g1v, W1f);
  prep_w1tail<<<512, 512, 0, stream>>>(l1w, l1b, l1g, l1be, l1m, l1v,
                                       g1w, g1b, g1g, g1be, g1m, g1v, cw, cb, W1f, b1cat);
  prep_w2<<<2048, 256, 0, stream>>>(l2w, l2b, l2g, l2be, l2m, l2v,
                                    g2w, g2b, g2g, g2be, g2m, g2v, W2f, b2sum);
  prep_cwf<<<256, 256, 0, stream>>>(cw, cb, CWf);
  prep_f1f<<<2048, 256, 0, stream>>>(fw1, F1f);

  gemm1<<<512, 1024, 0, stream>>>(name1, type1, coor1, name2, type2, coor2,
                                  W1f, CWf, b1cat, h_ws, c_ws, r_ws);
  gemm2<<<1024, 512, 0, stream>>>(W2f, b2sum, h_ws, c_ws, r_ws);
  fused_final<<<256, 512, 0, stream>>>(r_ws, F1f, fb1, fw2, fb2, (float*)d_out);
}

// Round 9
// 323.572 us; speedup vs baseline: 1.7746x; 1.0812x over previous
//
#include <hip/hip_runtime.h>

typedef __bf16 bf16;
typedef __bf16 bf16x8 __attribute__((ext_vector_type(8)));
typedef __bf16 bf16x4 __attribute__((ext_vector_type(4)));
typedef float  f32x4  __attribute__((ext_vector_type(4)));

#define BN_EPS 1e-5f
#define MFMA(a, b, c) __builtin_amdgcn_mfma_f32_16x16x32_bf16((a), (b), (c), 0, 0, 0)
#define BAR() do { __builtin_amdgcn_sched_barrier(0); \
                   asm volatile("s_waitcnt lgkmcnt(0)" ::: "memory"); \
                   __builtin_amdgcn_s_barrier(); \
                   __builtin_amdgcn_sched_barrier(0); } while (0)

// Fragment-linear offset for MFMA B-operand matrix [N][K] (16x16x32 tiles):
// tile = (k/32)*ntiles + n/16 ; within tile: lane = ((k%32)/8)*16 + n%16, elem = k%8
__device__ __host__ __forceinline__ size_t frag_off(int n, int k, int ntiles) {
  return ((size_t)((k >> 5) * ntiles + (n >> 4)) << 9)
       + (size_t)((((k >> 3) & 3) << 4) + (n & 15)) * 8 + (k & 7);
}

// ---------------- prep: all elementwise weight transforms in ONE kernel ----------------

__global__ __launch_bounds__(256)
void prep_all(const float* __restrict__ l1w, const float* __restrict__ l1g, const float* __restrict__ l1v,
              const float* __restrict__ g1w, const float* __restrict__ g1g, const float* __restrict__ g1v,
              const float* __restrict__ l2w, const float* __restrict__ l2b, const float* __restrict__ l2g,
              const float* __restrict__ l2be, const float* __restrict__ l2m, const float* __restrict__ l2v,
              const float* __restrict__ g2w, const float* __restrict__ g2b, const float* __restrict__ g2g,
              const float* __restrict__ g2be, const float* __restrict__ g2m, const float* __restrict__ g2v,
              const float* __restrict__ cw, const float* __restrict__ cb,
              const float* __restrict__ fw1,
              bf16* __restrict__ W1f, bf16* __restrict__ W2f, bf16* __restrict__ CWf,
              bf16* __restrict__ F1f, float* __restrict__ b2sum) {
  int gid = blockIdx.x * 256 + threadIdx.x;
  if (gid < 524288) {                       // W1f main
    int n = gid >> 10, k = gid & 1023;
    float s, w;
    if (n < 256) { s = l1g[n] * rsqrtf(l1v[n] + BN_EPS); w = l1w[(size_t)n * 1024 + k]; }
    else { int nn = n - 256; s = g1g[nn] * rsqrtf(g1v[nn] + BN_EPS); w = g1w[(size_t)nn * 1024 + k]; }
    W1f[frag_off(n, k, 32)] = (bf16)(w * s);
  } else if (gid < 1048576) {               // W2f + b2sum
    int g2 = gid - 524288;
    int n = g2 >> 9, k = g2 & 511;
    float w;
    if (k < 256) { float s = l2g[n] * rsqrtf(l2v[n] + BN_EPS); w = l2w[(size_t)n * 256 + k] * s; }
    else { float s = g2g[n] * rsqrtf(g2v[n] + BN_EPS); w = g2w[(size_t)n * 256 + (k - 256)] * s; }
    W2f[frag_off(n, k, 64)] = (bf16)w;
    if (k == 0) {
      float sl = l2g[n] * rsqrtf(l2v[n] + BN_EPS), sg = g2g[n] * rsqrtf(g2v[n] + BN_EPS);
      b2sum[n] = sl * (l2b[n] - l2m[n]) + l2be[n] + sg * (g2b[n] - g2m[n]) + g2be[n];
    }
  } else if (gid < 1114112) {               // CWf
    int g3 = gid - 1048576;
    int n = g3 >> 6, kc = g3 & 63;
    float v = (kc < 48) ? cw[(size_t)n * 48 + kc] : (kc == 48 ? cb[n] : 0.f);
    CWf[frag_off(n, kc, 64)] = (bf16)v;
  } else {                                  // F1f
    int g4 = gid - 1114112;
    int n = g4 >> 11, k = g4 & 2047;
    F1f[frag_off(n, k, 16)] = (bf16)fw1[(size_t)n * 2048 + k];
  }
}

__global__ __launch_bounds__(512)
void prep_w1tail(const float* __restrict__ l1w, const float* __restrict__ l1b, const float* __restrict__ l1g,
                 const float* __restrict__ l1be, const float* __restrict__ l1m, const float* __restrict__ l1v,
                 const float* __restrict__ g1w, const float* __restrict__ g1b, const float* __restrict__ g1g,
                 const float* __restrict__ g1be, const float* __restrict__ g1m, const float* __restrict__ g1v,
                 const float* __restrict__ cw, const float* __restrict__ cb,
                 bf16* __restrict__ W1f, float* __restrict__ b1cat) {
  int n = blockIdx.x;
  int kc = threadIdx.x & 63, js = threadIdx.x >> 6;
  const float* wrow; float s, bb, mm, be;
  if (n < 256) { s = l1g[n] * rsqrtf(l1v[n] + BN_EPS); wrow = l1w + (size_t)n * 1024;
                 bb = l1b[n]; mm = l1m[n]; be = l1be[n]; }
  else { int nn = n - 256; s = g1g[nn] * rsqrtf(g1v[nn] + BN_EPS); wrow = g1w + (size_t)nn * 1024;
         bb = g1b[nn]; mm = g1m[nn]; be = g1be[nn]; }
  float a = 0.f;
  if (kc < 49) {
    #pragma unroll 4
    for (int jj = 0; jj < 128; ++jj) {
      int j = js * 128 + jj;
      float cv = (kc < 48) ? cw[(size_t)j * 48 + kc] : cb[j];
      a += wrow[j] * cv;
    }
  }
  __shared__ float red[8][64];
  red[js][kc] = a;
  __syncthreads();
  if (threadIdx.x < 64) {
    float v = 0.f;
    #pragma unroll
    for (int r = 0; r < 8; ++r) v += red[r][threadIdx.x];
    W1f[frag_off(n, 1024 + threadIdx.x, 32)] = (bf16)((threadIdx.x < 49) ? v * s : 0.f);
  }
  if (threadIdx.x == 0) b1cat[n] = s * (bb - mm) + be;
}

// ---------------- K0: gemm_c — c = [coor|1|0] @ CWfT, M=128 per block, write-stream bound ----------------

__global__ __launch_bounds__(512, 4)
void gemm_c(const float* __restrict__ coor1, const float* __restrict__ coor2,
            const bf16* __restrict__ CWf, bf16* __restrict__ c_ws) {
  const int bid = blockIdx.x;           // 256
  const int tt = bid >> 7, mb = bid & 127;
  const float* __restrict__ coor = tt ? coor2 : coor1;
  const int b0 = mb * 128;
  const int tid = threadIdx.x;
  const int lane = tid & 63;
  const int wv = tid >> 6;              // 0..7 : one 16-row m-tile each
  const int arow = lane & 15;
  const int q = lane >> 4;
  const int kgrp = q << 3;

  __shared__ __align__(16) bf16 hb[128][264];   // 67,584 B -> 2 blocks/CU

  // A fragments in-register (one-time 64 B/lane gather):
  // ca0: cols kgrp..kgrp+7 (always < 32 -> coor); ca1: cols 32+kgrp..+7 ([coor<48 | 1@48 | 0])
  const int row = wv * 16 + arow;
  bf16x8 ca0, ca1;
  {
    const float* cr = coor + (size_t)(b0 + row) * 48;
    float4 v0 = *reinterpret_cast<const float4*>(cr + kgrp);
    float4 v1 = *reinterpret_cast<const float4*>(cr + kgrp + 4);
    ca0[0] = (bf16)v0.x; ca0[1] = (bf16)v0.y; ca0[2] = (bf16)v0.z; ca0[3] = (bf16)v0.w;
    ca0[4] = (bf16)v1.x; ca0[5] = (bf16)v1.y; ca0[6] = (bf16)v1.z; ca0[7] = (bf16)v1.w;
    if (q < 2) {
      float4 w0 = *reinterpret_cast<const float4*>(cr + 32 + kgrp);
      float4 w1 = *reinterpret_cast<const float4*>(cr + 36 + kgrp);
      ca1[0] = (bf16)w0.x; ca1[1] = (bf16)w0.y; ca1[2] = (bf16)w0.z; ca1[3] = (bf16)w0.w;
      ca1[4] = (bf16)w1.x; ca1[5] = (bf16)w1.y; ca1[6] = (bf16)w1.z; ca1[7] = (bf16)w1.w;
    } else {
      #pragma unroll
      for (int e = 0; e < 8; ++e) ca1[e] = (bf16)0.f;
      if (q == 2) ca1[0] = (bf16)1.0f;   // col 48 = the bias column
    }
  }

  #pragma unroll 1
  for (int nc = 0; nc < 4; ++nc) {
    f32x4 cacc[16] = {};
    #pragma unroll
    for (int u = 0; u < 16; ++u) {
      int ntile = nc * 16 + u;
      bf16x8 b0f = *reinterpret_cast<const bf16x8*>(CWf + (((size_t)ntile) << 9) + lane * 8);
      bf16x8 b1f = *reinterpret_cast<const bf16x8*>(CWf + (((size_t)(64 + ntile)) << 9) + lane * 8);
      cacc[u] = MFMA(ca0, b0f, cacc[u]);
      cacc[u] = MFMA(ca1, b1f, cacc[u]);
    }
    #pragma unroll
    for (int u = 0; u < 16; ++u) {
      #pragma unroll
      for (int i = 0; i < 4; ++i)
        hb[wv * 16 + q * 4 + i][u * 16 + arow] = (bf16)cacc[u][i];
    }
    __syncthreads();
    #pragma unroll
    for (int g = 0; g < 8; ++g) {
      int idx = g * 512 + tid;
      int row2 = idx >> 5, cg = idx & 31;
      *reinterpret_cast<bf16x8*>(c_ws + ((size_t)tt * 16384 + b0 + row2) * 1024 + nc * 256 + cg * 8) =
        *reinterpret_cast<const bf16x8*>(&hb[row2][cg * 8]);
    }
    __syncthreads();
  }
}

// ---------------- K1: gemm1 — h = relu(e @ W1catT + b1cat); emits e (bf16) to r_ws ----------------
// M=128, N=256; 1024 thr; 17 phases of 64 k; depth-2 named-reg pipeline, raw barrier (no vmcnt drain).
// (R7-proven version, unchanged.)

__global__ __launch_bounds__(1024, 4)
void gemm1(const float* __restrict__ name1, const float* __restrict__ type1, const float* __restrict__ coor1,
           const float* __restrict__ name2, const float* __restrict__ type2, const float* __restrict__ coor2,
           const bf16* __restrict__ W1f, const float* __restrict__ b1cat,
           bf16* __restrict__ h_ws, bf16* __restrict__ r_ws) {
  const int bid = blockIdx.x;
  const int xcd = bid & 7, slot = bid >> 3;
  const int nb = slot & 1;
  const int lg = xcd * 32 + (slot >> 1);   // 0..255 bijective
  const int tt = lg >> 7;
  const int mb = lg & 127;
  const float* __restrict__ name = tt ? name2 : name1;
  const float* __restrict__ typ  = tt ? type2 : type1;
  const float* __restrict__ coor = tt ? coor2 : coor1;
  const int b0 = mb * 128;
  const int tid = threadIdx.x;
  const int lane = tid & 63;
  const int wv = tid >> 6;           // 0..15
  const int wm = wv >> 2;            // 0..3: 32-row group
  const int wn = wv & 3;             // 0..3
  const int arow = lane & 15;
  const int q = lane >> 4;
  const int kgrp = q << 3;

  __shared__ __align__(16) char SM[67584];
  bf16 (*EB)[128][72] = reinterpret_cast<bf16 (*)[128][72]>(SM);   // 2 bufs x 18,432 B
  bf16 (*hb)[264] = reinterpret_cast<bf16 (*)[264]>(SM);           // overlay after k-loop

  const int srow = tid >> 3;         // 0..127
  const int scg = tid & 7;

  const float4* name4 = reinterpret_cast<const float4*>(name);
  const float4* typ4  = reinterpret_cast<const float4*>(typ);
  const float4* coor4 = reinterpret_cast<const float4*>(coor);

  // two NAMED register sets (rule #20): A = even phases (+tail 16), B = odd phases
  float4 nA0, tA0, nA1, tA1, nB0, tB0, nB1, tB1;

  auto REGLOAD_A = [&](int pp) {
    if (pp < 16) {
      size_t base = (size_t)(b0 + srow) * 256 + (size_t)pp * 16 + scg;
      nA0 = name4[base];     tA0 = typ4[base];
      nA1 = name4[base + 8]; tA1 = typ4[base + 8];
    } else {                              // tail: [coor(48) | 1 | 0...]
      nA0 = coor4[(size_t)(b0 + srow) * 12 + scg];
      tA0 = make_float4(0.f, 0.f, 0.f, 0.f);
      int idx = 8 + scg;
      if (idx < 12)       nA1 = coor4[(size_t)(b0 + srow) * 12 + idx];
      else if (idx == 12) nA1 = make_float4(1.f, 0.f, 0.f, 0.f);
      else                nA1 = make_float4(0.f, 0.f, 0.f, 0.f);
      tA1 = make_float4(0.f, 0.f, 0.f, 0.f);
    }
  };
  auto REGLOAD_B = [&](int pp) {
    size_t base = (size_t)(b0 + srow) * 256 + (size_t)pp * 16 + scg;
    nB0 = name4[base];     tB0 = typ4[base];
    nB1 = name4[base + 8]; tB1 = typ4[base + 8];
  };
  auto PACK = [&](const float4& nv, const float4& tv) {
    bf16x4 e;
    e[0] = (bf16)(nv.x + tv.x); e[1] = (bf16)(nv.y + tv.y);
    e[2] = (bf16)(nv.z + tv.z); e[3] = (bf16)(nv.w + tv.w);
    return e;
  };
  auto WRITEB_A = [&](int buf) {
    *reinterpret_cast<bf16x4*>(&EB[buf][srow][scg * 4]) = PACK(nA0, tA0);
    *reinterpret_cast<bf16x4*>(&EB[buf][srow][32 + scg * 4]) = PACK(nA1, tA1);
  };
  auto WRITEB_B = [&](int buf) {
    *reinterpret_cast<bf16x4*>(&EB[buf][srow][scg * 4]) = PACK(nB0, tB0);
    *reinterpret_cast<bf16x4*>(&EB[buf][srow][32 + scg * 4]) = PACK(nB1, tB1);
  };
  auto EWRITE_A = [&](int pp) {
    size_t rb = (size_t)(b0 + srow) * 2048 + (size_t)tt * 1024 + pp * 64;
    *reinterpret_cast<bf16x4*>(r_ws + rb + scg * 4) = PACK(nA0, tA0);
    *reinterpret_cast<bf16x4*>(r_ws + rb + 32 + scg * 4) = PACK(nA1, tA1);
  };
  auto EWRITE_B = [&](int pp) {
    size_t rb = (size_t)(b0 + srow) * 2048 + (size_t)tt * 1024 + pp * 64;
    *reinterpret_cast<bf16x4*>(r_ws + rb + scg * 4) = PACK(nB0, tB0);
    *reinterpret_cast<bf16x4*>(r_ws + rb + 32 + scg * 4) = PACK(nB1, tB1);
  };

  f32x4 acc[2][4] = {};
  auto MFMA_PHASE = [&](int p, int buf) {
    #pragma unroll
    for (int ks2 = 0; ks2 < 2; ++ks2) {
      int kk = p * 2 + ks2;
      bf16x8 a0 = *reinterpret_cast<const bf16x8*>(&EB[buf][wm * 32 + arow][ks2 * 32 + kgrp]);
      bf16x8 a1 = *reinterpret_cast<const bf16x8*>(&EB[buf][wm * 32 + 16 + arow][ks2 * 32 + kgrp]);
      #pragma unroll
      for (int u = 0; u < 4; ++u) {
        bf16x8 b = *reinterpret_cast<const bf16x8*>(W1f + (((size_t)(kk * 32 + nb * 16 + wn * 4 + u)) << 9) + lane * 8);
        acc[0][u] = MFMA(a0, b, acc[0][u]);
        acc[1][u] = MFMA(a1, b, acc[1][u]);
      }
    }
  };

  // prologue
  REGLOAD_A(0); REGLOAD_B(1);
  WRITEB_A(0); EWRITE_A(0);
  REGLOAD_A(2);
  BAR();

  #pragma unroll 1
  for (int j = 0; j < 8; ++j) {
    const int p0 = 2 * j;
    WRITEB_B(1); EWRITE_B(p0 + 1);
    if (p0 + 3 < 16) REGLOAD_B(p0 + 3);
    MFMA_PHASE(p0, 0);
    BAR();
    WRITEB_A(0);
    if (p0 + 2 <= 15) EWRITE_A(p0 + 2);
    if (p0 + 4 <= 16) REGLOAD_A(p0 + 4);
    MFMA_PHASE(p0 + 1, 1);
    BAR();
  }
  MFMA_PHASE(16, 0);                          // coor tail
  __syncthreads();                            // full drain before hb overlay

  // ---- h = relu(acc + b1cat) via LDS bounce, then coalesced store ----
  #pragma unroll
  for (int u = 0; u < 4; ++u) {
    int col = (wn * 4 + u) * 16 + arow;
    float bb = b1cat[nb * 256 + col];
    #pragma unroll
    for (int m = 0; m < 2; ++m) {
      #pragma unroll
      for (int i = 0; i < 4; ++i)
        hb[wm * 32 + m * 16 + q * 4 + i][col] = (bf16)fmaxf(acc[m][u][i] + bb, 0.f);
    }
  }
  __syncthreads();

  #pragma unroll
  for (int g = 0; g < 4; ++g) {
    int idx = g * 1024 + tid;
    int row = idx >> 5, cg = idx & 31;
    *reinterpret_cast<bf16x8*>(h_ws + ((size_t)tt * 16384 + b0 + row) * 512 + nb * 256 + cg * 8) =
      *reinterpret_cast<const bf16x8*>(&hb[row][cg * 8]);
  }
}

// ---------------- K2: gemm2 — wei = sigmoid(h@W2T+b2); r = 2e + 2*wei*(c-e) ----------------
// M=128, N=256; A-fragments DIRECT from global h_ws (L2-hot, XCD-co-located nb-quad); no k-loop barriers.

__global__ __launch_bounds__(512, 4)
void gemm2(const bf16* __restrict__ W2f, const float* __restrict__ b2sum,
           const bf16* __restrict__ h_ws, const bf16* __restrict__ c_ws, bf16* __restrict__ r_ws) {
  const int bid = blockIdx.x;            // 1024 blocks
  const int xcd = bid & 7, s = bid >> 3; // s: [tt(1)][nb(2)][mhi(4)]
  const int mb = xcd + 8 * (s & 15);     // nb-quad of one (mb,tt) shares an XCD
  const int nb = (s >> 4) & 3;           // 256-col quarter
  const int tt = s >> 6;
  const int b0 = mb * 128;
  const int tid = threadIdx.x;
  const int lane = tid & 63;
  const int wv = tid >> 6;               // 0..7
  const int wm = wv >> 1;                // 0..3: 32-row group
  const int wn2 = wv & 1;                // 0..1: 128-col half
  const int arow = lane & 15;
  const int q = lane >> 4;
  const int kgrp = q << 3;

  __shared__ __align__(16) float xs[128][132];   // 67,584 B -> 2 blocks/CU

  const bf16* hbase = h_ws + ((size_t)tt * 16384 + b0) * 512;
  const bf16* ha0 = hbase + (size_t)(wm * 32 + arow) * 512 + kgrp;
  const bf16* ha1 = hbase + (size_t)(wm * 32 + 16 + arow) * 512 + kgrp;

  f32x4 acc[2][8] = {};
  #pragma unroll 4
  for (int ks = 0; ks < 16; ++ks) {
    bf16x8 a0 = *reinterpret_cast<const bf16x8*>(ha0 + ks * 32);
    bf16x8 a1 = *reinterpret_cast<const bf16x8*>(ha1 + ks * 32);
    #pragma unroll
    for (int u = 0; u < 8; ++u) {
      bf16x8 b = *reinterpret_cast<const bf16x8*>(
          W2f + (((size_t)(ks * 64 + nb * 16 + wn2 * 8 + u)) << 9) + lane * 8);
      acc[0][u] = MFMA(a0, b, acc[0][u]);
      acc[1][u] = MFMA(a1, b, acc[1][u]);
    }
  }

  // ---- combine in two 128-col passes: xs = sigmoid(acc+b2) -> vectorized r ----
  #pragma unroll
  for (int hc = 0; hc < 2; ++hc) {
    if (wn2 == hc) {                         // wave-uniform
      #pragma unroll
      for (int u = 0; u < 8; ++u) {
        int lcol = u * 16 + arow;
        float b2 = b2sum[nb * 256 + hc * 128 + lcol];
        #pragma unroll
        for (int m = 0; m < 2; ++m) {
          #pragma unroll
          for (int i = 0; i < 4; ++i)
            xs[wm * 32 + m * 16 + q * 4 + i][lcol] = 1.f / (1.f + __expf(-(acc[m][u][i] + b2)));
        }
      }
    }
    __syncthreads();
    {
      int row = tid >> 2, sc = tid & 3;
      size_t ebase = (size_t)(b0 + row) * 2048 + (size_t)tt * 1024 + nb * 256 + hc * 128;
      size_t cbase = ((size_t)tt * 16384 + b0 + row) * 1024 + nb * 256 + hc * 128;
      #pragma unroll
      for (int g = 0; g < 4; ++g) {
        int c8 = g * 32 + sc * 8;
        bf16x8 ebv = *reinterpret_cast<const bf16x8*>(r_ws + ebase + c8);
        bf16x8 cv  = *reinterpret_cast<const bf16x8*>(c_ws + cbase + c8);
        f32x4 w0 = *reinterpret_cast<const f32x4*>(&xs[row][c8]);
        f32x4 w1 = *reinterpret_cast<const f32x4*>(&xs[row][c8 + 4]);
        bf16x8 rv;
        #pragma unroll
        for (int jj = 0; jj < 8; ++jj) {
          float e = (float)ebv[jj], c = (float)cv[jj];
          float w = (jj < 4) ? w0[jj] : w1[jj - 4];
          rv[jj] = (bf16)(2.f * (e + w * (c - e)));
        }
        *reinterpret_cast<bf16x8*>(r_ws + ebase + c8) = rv;
      }
    }
    __syncthreads();
  }
}

// ---------------- K3: final — out = sigmoid(relu(r@fw1T+fb1)@fw2T+fb2), M=64 ----------------

__global__ __launch_bounds__(512, 4)
void fused_final(const bf16* __restrict__ r_ws, const bf16* __restrict__ F1f,
                 const float* __restrict__ fb1, const float* __restrict__ fw2,
                 const float* __restrict__ fb2, float* __restrict__ out) {
  const int b0 = blockIdx.x * 64;
  const int tid = threadIdx.x;
  const int lane = tid & 63;
  const int wv = tid >> 6;
  const int arow = lane & 15;
  const int q    = lane >> 4;
  const int kgrp = q << 3;

  __shared__ bf16 RT[2][64][264];
  float (*H2)[260] = reinterpret_cast<float (*)[260]>(&RT[0][0][0]);

  bf16x8 sv[4];
  auto SLOAD = [&](int kc) {
    #pragma unroll
    for (int g = 0; g < 4; ++g) {
      int f = g * 512 + tid;
      int row = f >> 5, colg = f & 31;
      sv[g] = *reinterpret_cast<const bf16x8*>(r_ws + (size_t)(b0 + row) * 2048 + kc * 256 + colg * 8);
    }
  };
  auto SWRITE = [&](int buf) {
    #pragma unroll
    for (int g = 0; g < 4; ++g) {
      int f = g * 512 + tid;
      int row = f >> 5, colg = f & 31;
      *reinterpret_cast<bf16x8*>(&RT[buf][row][colg * 8]) = sv[g];
    }
  };

  SLOAD(0); SWRITE(0);
  __syncthreads();

  f32x4 acc[4][2] = {};
  #pragma unroll 1
  for (int kc = 0; kc < 8; ++kc) {
    if (kc < 7) SLOAD(kc + 1);
    #pragma unroll
    for (int ks = 0; ks < 8; ++ks) {
      int ksg = kc * 8 + ks;
      bf16x8 a[4];
      #pragma unroll
      for (int m = 0; m < 4; ++m)
        a[m] = *reinterpret_cast<const bf16x8*>(&RT[kc & 1][m * 16 + arow][ks * 32 + kgrp]);
      #pragma unroll
      for (int u = 0; u < 2; ++u) {
        bf16x8 b = *reinterpret_cast<const bf16x8*>(F1f + (((size_t)(ksg * 16 + wv * 2 + u)) << 9) + lane * 8);
        #pragma unroll
        for (int m = 0; m < 4; ++m)
          acc[m][u] = MFMA(a[m], b, acc[m][u]);
      }
    }
    if (kc < 7) SWRITE((kc + 1) & 1);
    __syncthreads();
  }

  #pragma unroll
  for (int u = 0; u < 2; ++u) {
    int col = (wv * 2 + u) * 16 + arow;
    float bb = fb1[col];
    #pragma unroll
    for (int m = 0; m < 4; ++m) {
      #pragma unroll
      for (int i2 = 0; i2 < 4; ++i2) {
        int row = m * 16 + q * 4 + i2;
        H2[row][col] = fmaxf(acc[m][u][i2] + bb, 0.f);
      }
    }
  }
  __syncthreads();

  int row = tid >> 3, sub = tid & 7;
  float p = 0.f;
  #pragma unroll
  for (int c = 0; c < 32; ++c) p += H2[row][sub * 32 + c] * fw2[sub * 32 + c];
  p += __shfl_xor(p, 1, 8);
  p += __shfl_xor(p, 2, 8);
  p += __shfl_xor(p, 4, 8);
  if (sub == 0) out[b0 + row] = 1.f / (1.f + __expf(-(p + fb2[0])));
}

// ---------------- launcher ----------------

extern "C" void kernel_launch(void* const* d_in, const int* in_sizes, int n_in,
                              void* d_out, int out_size, void* d_ws, size_t ws_size,
                              hipStream_t stream) {
  const float* name1 = (const float*)d_in[0];
  const float* type1 = (const float*)d_in[1];
  const float* coor1 = (const float*)d_in[2];
  const float* name2 = (const float*)d_in[3];
  const float* type2 = (const float*)d_in[4];
  const float* coor2 = (const float*)d_in[5];
  const float* cw    = (const float*)d_in[6];
  const float* cb    = (const float*)d_in[7];
  const float* l1w = (const float*)d_in[8];  const float* l1b = (const float*)d_in[9];
  const float* l1g = (const float*)d_in[10]; const float* l1be = (const float*)d_in[11];
  const float* l1m = (const float*)d_in[12]; const float* l1v = (const float*)d_in[13];
  const float* l2w = (const float*)d_in[14]; const float* l2b = (const float*)d_in[15];
  const float* l2g = (const float*)d_in[16]; const float* l2be = (const float*)d_in[17];
  const float* l2m = (const float*)d_in[18]; const float* l2v = (const float*)d_in[19];
  const float* g1w = (const float*)d_in[20]; const float* g1b = (const float*)d_in[21];
  const float* g1g = (const float*)d_in[22]; const float* g1be = (const float*)d_in[23];
  const float* g1m = (const float*)d_in[24]; const float* g1v = (const float*)d_in[25];
  const float* g2w = (const float*)d_in[26]; const float* g2b = (const float*)d_in[27];
  const float* g2g = (const float*)d_in[28]; const float* g2be = (const float*)d_in[29];
  const float* g2m = (const float*)d_in[30]; const float* g2v = (const float*)d_in[31];
  const float* fw1 = (const float*)d_in[32]; const float* fb1 = (const float*)d_in[33];
  const float* fw2 = (const float*)d_in[34]; const float* fb2 = (const float*)d_in[35];

  char* ws = (char*)d_ws;
  bf16*  W1f   = (bf16*)(ws + 0);          // 512*1088 bf16   = 1,114,112 B
  bf16*  W2f   = (bf16*)(ws + 1114112);    // 1024*512 bf16   = 1,048,576 B
  bf16*  CWf   = (bf16*)(ws + 2162688);    // 1024*64  bf16   =   131,072 B
  bf16*  F1f   = (bf16*)(ws + 2293760);    // 256*2048 bf16   = 1,048,576 B
  float* b1cat = (float*)(ws + 3342336);   // 512 f32
  float* b2sum = (float*)(ws + 3344384);   // 1024 f32
  bf16*  h_ws  = (bf16*)(ws + 3407872);    // [2][16384][512]  = 33,554,432 B
  bf16*  r_ws  = (bf16*)(ws + 36962304);   // [16384][2048]    = 67,108,864 B (holds e, then r)
  bf16*  c_ws  = (bf16*)(ws + 104071168);  // [2][16384][1024] = 67,108,864 B

  prep_all<<<6400, 256, 0, stream>>>(l1w, l1g, l1v, g1w, g1g, g1v,
                                     l2w, l2b, l2g, l2be, l2m, l2v,
                                     g2w, g2b, g2g, g2be, g2m, g2v,
                                     cw, cb, fw1, W1f, W2f, CWf, F1f, b2sum);
  prep_w1tail<<<512, 512, 0, stream>>>(l1w, l1b, l1g, l1be, l1m, l1v,
                                       g1w, g1b, g1g, g1be, g1m, g1v, cw, cb, W1f, b1cat);

  gemm_c<<<256, 512, 0, stream>>>(coor1, coor2, CWf, c_ws);
  gemm1<<<512, 1024, 0, stream>>>(name1, type1, coor1, name2, type2, coor2,
                                  W1f, b1cat, h_ws, r_ws);
  gemm2<<<1024, 512, 0, stream>>>(W2f, b2sum, h_ws, c_ws, r_ws);
  fused_final<<<256, 512, 0, stream>>>(r_ws, F1f, fb1, fw2, fb2, (float*)d_out);
}

// Round 10
// 317.385 us; speedup vs baseline: 1.8092x; 1.0195x over previous
//
#include <hip/hip_runtime.h>

typedef __bf16 bf16;
typedef __bf16 bf16x8 __attribute__((ext_vector_type(8)));
typedef __bf16 bf16x4 __attribute__((ext_vector_type(4)));
typedef float  f32x4  __attribute__((ext_vector_type(4)));

#define BN_EPS 1e-5f
#define MFMA(a, b, c) __builtin_amdgcn_mfma_f32_16x16x32_bf16((a), (b), (c), 0, 0, 0)
#define BAR() do { __builtin_amdgcn_sched_barrier(0); \
                   asm volatile("s_waitcnt lgkmcnt(0)" ::: "memory"); \
                   __builtin_amdgcn_s_barrier(); \
                   __builtin_amdgcn_sched_barrier(0); } while (0)

// Fragment-linear offset for MFMA B-operand matrix [N][K] (16x16x32 tiles):
// tile = (k/32)*ntiles + n/16 ; within tile: lane = ((k%32)/8)*16 + n%16, elem = k%8
__device__ __host__ __forceinline__ size_t frag_off(int n, int k, int ntiles) {
  return ((size_t)((k >> 5) * ntiles + (n >> 4)) << 9)
       + (size_t)((((k >> 3) & 3) << 4) + (n & 15)) * 8 + (k & 7);
}

// ---------------- prep: all elementwise weight transforms in ONE kernel ----------------

__global__ __launch_bounds__(256)
void prep_all(const float* __restrict__ l1w, const float* __restrict__ l1g, const float* __restrict__ l1v,
              const float* __restrict__ g1w, const float* __restrict__ g1g, const float* __restrict__ g1v,
              const float* __restrict__ l2w, const float* __restrict__ l2b, const float* __restrict__ l2g,
              const float* __restrict__ l2be, const float* __restrict__ l2m, const float* __restrict__ l2v,
              const float* __restrict__ g2w, const float* __restrict__ g2b, const float* __restrict__ g2g,
              const float* __restrict__ g2be, const float* __restrict__ g2m, const float* __restrict__ g2v,
              const float* __restrict__ cw, const float* __restrict__ cb,
              const float* __restrict__ fw1,
              bf16* __restrict__ W1f, bf16* __restrict__ W2f, bf16* __restrict__ CWf,
              bf16* __restrict__ F1f, float* __restrict__ b2sum) {
  int gid = blockIdx.x * 256 + threadIdx.x;
  if (gid < 524288) {                       // W1f main
    int n = gid >> 10, k = gid & 1023;
    float s, w;
    if (n < 256) { s = l1g[n] * rsqrtf(l1v[n] + BN_EPS); w = l1w[(size_t)n * 1024 + k]; }
    else { int nn = n - 256; s = g1g[nn] * rsqrtf(g1v[nn] + BN_EPS); w = g1w[(size_t)nn * 1024 + k]; }
    W1f[frag_off(n, k, 32)] = (bf16)(w * s);
  } else if (gid < 1048576) {               // W2f + b2sum
    int g2 = gid - 524288;
    int n = g2 >> 9, k = g2 & 511;
    float w;
    if (k < 256) { float s = l2g[n] * rsqrtf(l2v[n] + BN_EPS); w = l2w[(size_t)n * 256 + k] * s; }
    else { float s = g2g[n] * rsqrtf(g2v[n] + BN_EPS); w = g2w[(size_t)n * 256 + (k - 256)] * s; }
    W2f[frag_off(n, k, 64)] = (bf16)w;
    if (k == 0) {
      float sl = l2g[n] * rsqrtf(l2v[n] + BN_EPS), sg = g2g[n] * rsqrtf(g2v[n] + BN_EPS);
      b2sum[n] = sl * (l2b[n] - l2m[n]) + l2be[n] + sg * (g2b[n] - g2m[n]) + g2be[n];
    }
  } else if (gid < 1114112) {               // CWf
    int g3 = gid - 1048576;
    int n = g3 >> 6, kc = g3 & 63;
    float v = (kc < 48) ? cw[(size_t)n * 48 + kc] : (kc == 48 ? cb[n] : 0.f);
    CWf[frag_off(n, kc, 64)] = (bf16)v;
  } else {                                  // F1f
    int g4 = gid - 1114112;
    int n = g4 >> 11, k = g4 & 2047;
    F1f[frag_off(n, k, 16)] = (bf16)fw1[(size_t)n * 2048 + k];
  }
}

__global__ __launch_bounds__(512)
void prep_w1tail(const float* __restrict__ l1w, const float* __restrict__ l1b, const float* __restrict__ l1g,
                 const float* __restrict__ l1be, const float* __restrict__ l1m, const float* __restrict__ l1v,
                 const float* __restrict__ g1w, const float* __restrict__ g1b, const float* __restrict__ g1g,
                 const float* __restrict__ g1be, const float* __restrict__ g1m, const float* __restrict__ g1v,
                 const float* __restrict__ cw, const float* __restrict__ cb,
                 bf16* __restrict__ W1f, float* __restrict__ b1cat) {
  int n = blockIdx.x;
  int kc = threadIdx.x & 63, js = threadIdx.x >> 6;
  const float* wrow; float s, bb, mm, be;
  if (n < 256) { s = l1g[n] * rsqrtf(l1v[n] + BN_EPS); wrow = l1w + (size_t)n * 1024;
                 bb = l1b[n]; mm = l1m[n]; be = l1be[n]; }
  else { int nn = n - 256; s = g1g[nn] * rsqrtf(g1v[nn] + BN_EPS); wrow = g1w + (size_t)nn * 1024;
         bb = g1b[nn]; mm = g1m[nn]; be = g1be[nn]; }
  float a = 0.f;
  if (kc < 49) {
    #pragma unroll 4
    for (int jj = 0; jj < 128; ++jj) {
      int j = js * 128 + jj;
      float cv = (kc < 48) ? cw[(size_t)j * 48 + kc] : cb[j];
      a += wrow[j] * cv;
    }
  }
  __shared__ float red[8][64];
  red[js][kc] = a;
  __syncthreads();
  if (threadIdx.x < 64) {
    float v = 0.f;
    #pragma unroll
    for (int r = 0; r < 8; ++r) v += red[r][threadIdx.x];
    W1f[frag_off(n, 1024 + threadIdx.x, 32)] = (bf16)((threadIdx.x < 49) ? v * s : 0.f);
  }
  if (threadIdx.x == 0) b1cat[n] = s * (bb - mm) + be;
}

// ---------------- K_e: e = bf16(name+typ) -> r_ws ; pure streaming ----------------

__global__ __launch_bounds__(256)
void ke(const float* __restrict__ name1, const float* __restrict__ type1,
        const float* __restrict__ name2, const float* __restrict__ type2,
        bf16* __restrict__ r_ws) {
  const int gid = blockIdx.x * 256 + threadIdx.x;   // 2048 * 256 = 524288 threads
  #pragma unroll 2
  for (int it = 0; it < 8; ++it) {
    int idx = it * 524288 + gid;          // 0 .. 4,194,303 vec8 slots
    int tt = idx >> 21;                   // uniform per it
    int r8 = idx & 2097151;
    int row = r8 >> 7, c8 = r8 & 127;
    const float* np = (tt ? name2 : name1) + (size_t)row * 1024 + c8 * 8;
    const float* tp = (tt ? type2 : type1) + (size_t)row * 1024 + c8 * 8;
    float4 n0 = *reinterpret_cast<const float4*>(np);
    float4 n1 = *reinterpret_cast<const float4*>(np + 4);
    float4 t0 = *reinterpret_cast<const float4*>(tp);
    float4 t1 = *reinterpret_cast<const float4*>(tp + 4);
    bf16x8 ev;
    ev[0] = (bf16)(n0.x + t0.x); ev[1] = (bf16)(n0.y + t0.y);
    ev[2] = (bf16)(n0.z + t0.z); ev[3] = (bf16)(n0.w + t0.w);
    ev[4] = (bf16)(n1.x + t1.x); ev[5] = (bf16)(n1.y + t1.y);
    ev[6] = (bf16)(n1.z + t1.z); ev[7] = (bf16)(n1.w + t1.w);
    *reinterpret_cast<bf16x8*>(r_ws + (size_t)row * 2048 + (size_t)tt * 1024 + c8 * 8) = ev;
  }
}

// ---------------- K0: gemm_c — c = [coor|1|0] @ CWfT, M=128 per block, write-stream bound ----------------

__global__ __launch_bounds__(512, 4)
void gemm_c(const float* __restrict__ coor1, const float* __restrict__ coor2,
            const bf16* __restrict__ CWf, bf16* __restrict__ c_ws) {
  const int bid = blockIdx.x;           // 256
  const int tt = bid >> 7, mb = bid & 127;
  const float* __restrict__ coor = tt ? coor2 : coor1;
  const int b0 = mb * 128;
  const int tid = threadIdx.x;
  const int lane = tid & 63;
  const int wv = tid >> 6;              // 0..7 : one 16-row m-tile each
  const int arow = lane & 15;
  const int q = lane >> 4;
  const int kgrp = q << 3;

  __shared__ __align__(16) bf16 hb[128][264];   // 67,584 B -> 2 blocks/CU

  const int row = wv * 16 + arow;
  bf16x8 ca0, ca1;
  {
    const float* cr = coor + (size_t)(b0 + row) * 48;
    float4 v0 = *reinterpret_cast<const float4*>(cr + kgrp);
    float4 v1 = *reinterpret_cast<const float4*>(cr + kgrp + 4);
    ca0[0] = (bf16)v0.x; ca0[1] = (bf16)v0.y; ca0[2] = (bf16)v0.z; ca0[3] = (bf16)v0.w;
    ca0[4] = (bf16)v1.x; ca0[5] = (bf16)v1.y; ca0[6] = (bf16)v1.z; ca0[7] = (bf16)v1.w;
    if (q < 2) {
      float4 w0 = *reinterpret_cast<const float4*>(cr + 32 + kgrp);
      float4 w1 = *reinterpret_cast<const float4*>(cr + 36 + kgrp);
      ca1[0] = (bf16)w0.x; ca1[1] = (bf16)w0.y; ca1[2] = (bf16)w0.z; ca1[3] = (bf16)w0.w;
      ca1[4] = (bf16)w1.x; ca1[5] = (bf16)w1.y; ca1[6] = (bf16)w1.z; ca1[7] = (bf16)w1.w;
    } else {
      #pragma unroll
      for (int e = 0; e < 8; ++e) ca1[e] = (bf16)0.f;
      if (q == 2) ca1[0] = (bf16)1.0f;   // col 48 = the bias column
    }
  }

  #pragma unroll 1
  for (int nc = 0; nc < 4; ++nc) {
    f32x4 cacc[16] = {};
    #pragma unroll
    for (int u = 0; u < 16; ++u) {
      int ntile = nc * 16 + u;
      bf16x8 b0f = *reinterpret_cast<const bf16x8*>(CWf + (((size_t)ntile) << 9) + lane * 8);
      bf16x8 b1f = *reinterpret_cast<const bf16x8*>(CWf + (((size_t)(64 + ntile)) << 9) + lane * 8);
      cacc[u] = MFMA(ca0, b0f, cacc[u]);
      cacc[u] = MFMA(ca1, b1f, cacc[u]);
    }
    #pragma unroll
    for (int u = 0; u < 16; ++u) {
      #pragma unroll
      for (int i = 0; i < 4; ++i)
        hb[wv * 16 + q * 4 + i][u * 16 + arow] = (bf16)cacc[u][i];
    }
    __syncthreads();
    #pragma unroll
    for (int g = 0; g < 8; ++g) {
      int idx = g * 512 + tid;
      int row2 = idx >> 5, cg = idx & 31;
      *reinterpret_cast<bf16x8*>(c_ws + ((size_t)tt * 16384 + b0 + row2) * 1024 + nc * 256 + cg * 8) =
        *reinterpret_cast<const bf16x8*>(&hb[row2][cg * 8]);
    }
    __syncthreads();
  }
}

// ---------------- K1: gemm1 — h = relu(e @ W1catT + b1cat); e read as bf16 from r_ws (L3-hot) ----------------
// M=128, N=256; 1024 thr; 17 phases of 64 k; depth-2 named-reg pipeline, raw barrier (no vmcnt drain).

__global__ __launch_bounds__(1024, 4)
void gemm1(const float* __restrict__ coor1, const float* __restrict__ coor2,
           const bf16* __restrict__ W1f, const float* __restrict__ b1cat,
           const bf16* __restrict__ e_ws, bf16* __restrict__ h_ws) {
  const int bid = blockIdx.x;
  const int xcd = bid & 7, slot = bid >> 3;
  const int nb = slot & 1;
  const int lg = xcd * 32 + (slot >> 1);   // 0..255 bijective
  const int tt = lg >> 7;
  const int mb = lg & 127;
  const float* __restrict__ coor = tt ? coor2 : coor1;
  const int b0 = mb * 128;
  const int tid = threadIdx.x;
  const int lane = tid & 63;
  const int wv = tid >> 6;           // 0..15
  const int wm = wv >> 2;            // 0..3: 32-row group
  const int wn = wv & 3;             // 0..3
  const int arow = lane & 15;
  const int q = lane >> 4;
  const int kgrp = q << 3;

  __shared__ __align__(16) char SM[67584];
  bf16 (*EB)[128][72] = reinterpret_cast<bf16 (*)[128][72]>(SM);   // 2 bufs x 18,432 B
  bf16 (*hb)[264] = reinterpret_cast<bf16 (*)[264]>(SM);           // overlay after k-loop

  const int srow = tid >> 3;         // 0..127
  const int scg = tid & 7;           // 16B chunk: cols scg*8..scg*8+7

  const bf16* ebase = e_ws + (size_t)b0 * 2048 + (size_t)tt * 1024 + (size_t)srow * 2048 + scg * 8;

  // two NAMED staging regs (rule #20): A = even phases (+tail 16), B = odd phases
  bf16x8 eA, eB;

  auto LOADE_A = [&](int pp) {
    if (pp < 16) {
      eA = *reinterpret_cast<const bf16x8*>(ebase + pp * 64);
    } else {                              // tail: [coor(48) | 1 | 0...]
      const float* cr = coor + (size_t)(b0 + srow) * 48;
      if (scg < 6) {
        float4 v0 = *reinterpret_cast<const float4*>(cr + scg * 8);
        float4 v1 = *reinterpret_cast<const float4*>(cr + scg * 8 + 4);
        eA[0] = (bf16)v0.x; eA[1] = (bf16)v0.y; eA[2] = (bf16)v0.z; eA[3] = (bf16)v0.w;
        eA[4] = (bf16)v1.x; eA[5] = (bf16)v1.y; eA[6] = (bf16)v1.z; eA[7] = (bf16)v1.w;
      } else {
        #pragma unroll
        for (int e = 0; e < 8; ++e) eA[e] = (bf16)0.f;
        if (scg == 6) eA[0] = (bf16)1.0f;   // col 48 = the bias column
      }
    }
  };
  auto LOADE_B = [&](int pp) {
    eB = *reinterpret_cast<const bf16x8*>(ebase + pp * 64);
  };
  auto WRITEE_A = [&](int buf) { *reinterpret_cast<bf16x8*>(&EB[buf][srow][scg * 8]) = eA; };
  auto WRITEE_B = [&](int buf) { *reinterpret_cast<bf16x8*>(&EB[buf][srow][scg * 8]) = eB; };

  f32x4 acc[2][4] = {};
  auto MFMA_PHASE = [&](int p, int buf) {
    #pragma unroll
    for (int ks2 = 0; ks2 < 2; ++ks2) {
      int kk = p * 2 + ks2;
      bf16x8 a0 = *reinterpret_cast<const bf16x8*>(&EB[buf][wm * 32 + arow][ks2 * 32 + kgrp]);
      bf16x8 a1 = *reinterpret_cast<const bf16x8*>(&EB[buf][wm * 32 + 16 + arow][ks2 * 32 + kgrp]);
      #pragma unroll
      for (int u = 0; u < 4; ++u) {
        bf16x8 b = *reinterpret_cast<const bf16x8*>(W1f + (((size_t)(kk * 32 + nb * 16 + wn * 4 + u)) << 9) + lane * 8);
        acc[0][u] = MFMA(a0, b, acc[0][u]);
        acc[1][u] = MFMA(a1, b, acc[1][u]);
      }
    }
  };

  // prologue: EB[0]=phase0 visible; B holds ph1; A holds ph2 (in flight)
  LOADE_A(0); LOADE_B(1);
  WRITEE_A(0);
  LOADE_A(2);
  BAR();

  #pragma unroll 1
  for (int j = 0; j < 8; ++j) {
    const int p0 = 2 * j;
    WRITEE_B(1);
    if (p0 + 3 < 16) LOADE_B(p0 + 3);
    MFMA_PHASE(p0, 0);
    BAR();                                   // EB[1] visible; loads stay in flight
    WRITEE_A(0);
    if (p0 + 4 <= 16) LOADE_A(p0 + 4);
    MFMA_PHASE(p0 + 1, 1);
    BAR();                                   // EB[0] visible (phase p0+2)
  }
  MFMA_PHASE(16, 0);                          // coor tail
  __syncthreads();                            // full drain before hb overlay

  // ---- h = relu(acc + b1cat) via LDS bounce, then coalesced store ----
  #pragma unroll
  for (int u = 0; u < 4; ++u) {
    int col = (wn * 4 + u) * 16 + arow;
    float bb = b1cat[nb * 256 + col];
    #pragma unroll
    for (int m = 0; m < 2; ++m) {
      #pragma unroll
      for (int i = 0; i < 4; ++i)
        hb[wm * 32 + m * 16 + q * 4 + i][col] = (bf16)fmaxf(acc[m][u][i] + bb, 0.f);
    }
  }
  __syncthreads();

  #pragma unroll
  for (int g = 0; g < 4; ++g) {
    int idx = g * 1024 + tid;
    int row = idx >> 5, cg = idx & 31;
    *reinterpret_cast<bf16x8*>(h_ws + ((size_t)tt * 16384 + b0 + row) * 512 + nb * 256 + cg * 8) =
      *reinterpret_cast<const bf16x8*>(&hb[row][cg * 8]);
  }
}

// ---------------- K2: gemm2 — wei = sigmoid(h@W2T+b2); r = 2e + 2*wei*(c-e) ----------------
// M=128, N=256; A-fragments DIRECT from global h_ws (L2-hot, XCD-co-located nb-quad); no k-loop barriers.

__global__ __launch_bounds__(512, 4)
void gemm2(const bf16* __restrict__ W2f, const float* __restrict__ b2sum,
           const bf16* __restrict__ h_ws, const bf16* __restrict__ c_ws, bf16* __restrict__ r_ws) {
  const int bid = blockIdx.x;            // 1024 blocks
  const int xcd = bid & 7, s = bid >> 3; // s: [tt(1)][nb(2)][mhi(4)]
  const int mb = xcd + 8 * (s & 15);     // nb-quad of one (mb,tt) shares an XCD
  const int nb = (s >> 4) & 3;           // 256-col quarter
  const int tt = s >> 6;
  const int b0 = mb * 128;
  const int tid = threadIdx.x;
  const int lane = tid & 63;
  const int wv = tid >> 6;               // 0..7
  const int wm = wv >> 1;                // 0..3: 32-row group
  const int wn2 = wv & 1;                // 0..1: 128-col half
  const int arow = lane & 15;
  const int q = lane >> 4;
  const int kgrp = q << 3;

  __shared__ __align__(16) float xs[128][132];   // 67,584 B -> 2 blocks/CU

  const bf16* hbase = h_ws + ((size_t)tt * 16384 + b0) * 512;
  const bf16* ha0 = hbase + (size_t)(wm * 32 + arow) * 512 + kgrp;
  const bf16* ha1 = hbase + (size_t)(wm * 32 + 16 + arow) * 512 + kgrp;

  f32x4 acc[2][8] = {};
  #pragma unroll 4
  for (int ks = 0; ks < 16; ++ks) {
    bf16x8 a0 = *reinterpret_cast<const bf16x8*>(ha0 + ks * 32);
    bf16x8 a1 = *reinterpret_cast<const bf16x8*>(ha1 + ks * 32);
    #pragma unroll
    for (int u = 0; u < 8; ++u) {
      bf16x8 b = *reinterpret_cast<const bf16x8*>(
          W2f + (((size_t)(ks * 64 + nb * 16 + wn2 * 8 + u)) << 9) + lane * 8);
      acc[0][u] = MFMA(a0, b, acc[0][u]);
      acc[1][u] = MFMA(a1, b, acc[1][u]);
    }
  }

  // ---- combine in two 128-col passes: xs = sigmoid(acc+b2) -> vectorized r ----
  #pragma unroll
  for (int hc = 0; hc < 2; ++hc) {
    if (wn2 == hc) {                         // wave-uniform
      #pragma unroll
      for (int u = 0; u < 8; ++u) {
        int lcol = u * 16 + arow;
        float b2 = b2sum[nb * 256 + hc * 128 + lcol];
        #pragma unroll
        for (int m = 0; m < 2; ++m) {
          #pragma unroll
          for (int i = 0; i < 4; ++i)
            xs[wm * 32 + m * 16 + q * 4 + i][lcol] = 1.f / (1.f + __expf(-(acc[m][u][i] + b2)));
        }
      }
    }
    __syncthreads();
    {
      int row = tid >> 2, sc = tid & 3;
      size_t ebase = (size_t)(b0 + row) * 2048 + (size_t)tt * 1024 + nb * 256 + hc * 128;
      size_t cbase = ((size_t)tt * 16384 + b0 + row) * 1024 + nb * 256 + hc * 128;
      #pragma unroll
      for (int g = 0; g < 4; ++g) {
        int c8 = g * 32 + sc * 8;
        bf16x8 ebv = *reinterpret_cast<const bf16x8*>(r_ws + ebase + c8);
        bf16x8 cv  = *reinterpret_cast<const bf16x8*>(c_ws + cbase + c8);
        f32x4 w0 = *reinterpret_cast<const f32x4*>(&xs[row][c8]);
        f32x4 w1 = *reinterpret_cast<const f32x4*>(&xs[row][c8 + 4]);
        bf16x8 rv;
        #pragma unroll
        for (int jj = 0; jj < 8; ++jj) {
          float e = (float)ebv[jj], c = (float)cv[jj];
          float w = (jj < 4) ? w0[jj] : w1[jj - 4];
          rv[jj] = (bf16)(2.f * (e + w * (c - e)));
        }
        *reinterpret_cast<bf16x8*>(r_ws + ebase + c8) = rv;
      }
    }
    __syncthreads();
  }
}

// ---------------- K3: final — out = sigmoid(relu(r@fw1T+fb1)@fw2T+fb2), M=64 ----------------

__global__ __launch_bounds__(512, 4)
void fused_final(const bf16* __restrict__ r_ws, const bf16* __restrict__ F1f,
                 const float* __restrict__ fb1, const float* __restrict__ fw2,
                 const float* __restrict__ fb2, float* __restrict__ out) {
  const int b0 = blockIdx.x * 64;
  const int tid = threadIdx.x;
  const int lane = tid & 63;
  const int wv = tid >> 6;
  const int arow = lane & 15;
  const int q    = lane >> 4;
  const int kgrp = q << 3;

  __shared__ bf16 RT[2][64][264];
  float (*H2)[260] = reinterpret_cast<float (*)[260]>(&RT[0][0][0]);

  bf16x8 sv[4];
  auto SLOAD = [&](int kc) {
    #pragma unroll
    for (int g = 0; g < 4; ++g) {
      int f = g * 512 + tid;
      int row = f >> 5, colg = f & 31;
      sv[g] = *reinterpret_cast<const bf16x8*>(r_ws + (size_t)(b0 + row) * 2048 + kc * 256 + colg * 8);
    }
  };
  auto SWRITE = [&](int buf) {
    #pragma unroll
    for (int g = 0; g < 4; ++g) {
      int f = g * 512 + tid;
      int row = f >> 5, colg = f & 31;
      *reinterpret_cast<bf16x8*>(&RT[buf][row][colg * 8]) = sv[g];
    }
  };

  SLOAD(0); SWRITE(0);
  __syncthreads();

  f32x4 acc[4][2] = {};
  #pragma unroll 1
  for (int kc = 0; kc < 8; ++kc) {
    if (kc < 7) SLOAD(kc + 1);
    #pragma unroll
    for (int ks = 0; ks < 8; ++ks) {
      int ksg = kc * 8 + ks;
      bf16x8 a[4];
      #pragma unroll
      for (int m = 0; m < 4; ++m)
        a[m] = *reinterpret_cast<const bf16x8*>(&RT[kc & 1][m * 16 + arow][ks * 32 + kgrp]);
      #pragma unroll
      for (int u = 0; u < 2; ++u) {
        bf16x8 b = *reinterpret_cast<const bf16x8*>(F1f + (((size_t)(ksg * 16 + wv * 2 + u)) << 9) + lane * 8);
        #pragma unroll
        for (int m = 0; m < 4; ++m)
          acc[m][u] = MFMA(a[m], b, acc[m][u]);
      }
    }
    if (kc < 7) SWRITE((kc + 1) & 1);
    __syncthreads();
  }

  #pragma unroll
  for (int u = 0; u < 2; ++u) {
    int col = (wv * 2 + u) * 16 + arow;
    float bb = fb1[col];
    #pragma unroll
    for (int m = 0; m < 4; ++m) {
      #pragma unroll
      for (int i2 = 0; i2 < 4; ++i2) {
        int row = m * 16 + q * 4 + i2;
        H2[row][col] = fmaxf(acc[m][u][i2] + bb, 0.f);
      }
    }
  }
  __syncthreads();

  int row = tid >> 3, sub = tid & 7;
  float p = 0.f;
  #pragma unroll
  for (int c = 0; c < 32; ++c) p += H2[row][sub * 32 + c] * fw2[sub * 32 + c];
  p += __shfl_xor(p, 1, 8);
  p += __shfl_xor(p, 2, 8);
  p += __shfl_xor(p, 4, 8);
  if (sub == 0) out[b0 + row] = 1.f / (1.f + __expf(-(p + fb2[0])));
}

// ---------------- launcher ----------------

extern "C" void kernel_launch(void* const* d_in, const int* in_sizes, int n_in,
                              void* d_out, int out_size, void* d_ws, size_t ws_size,
                              hipStream_t stream) {
  const float* name1 = (const float*)d_in[0];
  const float* type1 = (const float*)d_in[1];
  const float* coor1 = (const float*)d_in[2];
  const float* name2 = (const float*)d_in[3];
  const float* type2 = (const float*)d_in[4];
  const float* coor2 = (const float*)d_in[5];
  const float* cw    = (const float*)d_in[6];
  const float* cb    = (const float*)d_in[7];
  const float* l1w = (const float*)d_in[8];  const float* l1b = (const float*)d_in[9];
  const float* l1g = (const float*)d_in[10]; const float* l1be = (const float*)d_in[11];
  const float* l1m = (const float*)d_in[12]; const float* l1v = (const float*)d_in[13];
  const float* l2w = (const float*)d_in[14]; const float* l2b = (const float*)d_in[15];
  const float* l2g = (const float*)d_in[16]; const float* l2be = (const float*)d_in[17];
  const float* l2m = (const float*)d_in[18]; const float* l2v = (const float*)d_in[19];
  const float* g1w = (const float*)d_in[20]; const float* g1b = (const float*)d_in[21];
  const float* g1g = (const float*)d_in[22]; const float* g1be = (const float*)d_in[23];
  const float* g1m = (const float*)d_in[24]; const float* g1v = (const float*)d_in[25];
  const float* g2w = (const float*)d_in[26]; const float* g2b = (const float*)d_in[27];
  const float* g2g = (const float*)d_in[28]; const float* g2be = (const float*)d_in[29];
  const float* g2m = (const float*)d_in[30]; const float* g2v = (const float*)d_in[31];
  const float* fw1 = (const float*)d_in[32]; const float* fb1 = (const float*)d_in[33];
  const float* fw2 = (const float*)d_in[34]; const float* fb2 = (const float*)d_in[35];

  char* ws = (char*)d_ws;
  bf16*  W1f   = (bf16*)(ws + 0);          // 512*1088 bf16   = 1,114,112 B
  bf16*  W2f   = (bf16*)(ws + 1114112);    // 1024*512 bf16   = 1,048,576 B
  bf16*  CWf   = (bf16*)(ws + 2162688);    // 1024*64  bf16   =   131,072 B
  bf16*  F1f   = (bf16*)(ws + 2293760);    // 256*2048 bf16   = 1,048,576 B
  float* b1cat = (float*)(ws + 3342336);   // 512 f32
  float* b2sum = (float*)(ws + 3344384);   // 1024 f32
  bf16*  h_ws  = (bf16*)(ws + 3407872);    // [2][16384][512]  = 33,554,432 B
  bf16*  r_ws  = (bf16*)(ws + 36962304);   // [16384][2048]    = 67,108,864 B (holds e, then r)
  bf16*  c_ws  = (bf16*)(ws + 104071168);  // [2][16384][1024] = 67,108,864 B

  ke<<<2048, 256, 0, stream>>>(name1, type1, name2, type2, r_ws);
  prep_all<<<6400, 256, 0, stream>>>(l1w, l1g, l1v, g1w, g1g, g1v,
                                     l2w, l2b, l2g, l2be, l2m, l2v,
                                     g2w, g2b, g2g, g2be, g2m, g2v,
                                     cw, cb, fw1, W1f, W2f, CWf, F1f, b2sum);
  prep_w1tail<<<512, 512, 0, stream>>>(l1w, l1b, l1g, l1be, l1m, l1v,
                                       g1w, g1b, g1g, g1be, g1m, g1v, cw, cb, W1f, b1cat);

  gemm_c<<<256, 512, 0, stream>>>(coor1, coor2, CWf, c_ws);
  gemm1<<<512, 1024, 0, stream>>>(coor1, coor2, W1f, b1cat, r_ws, h_ws);
  gemm2<<<1024, 512, 0, stream>>>(W2f, b2sum, h_ws, c_ws, r_ws);
  fused_final<<<256, 512, 0, stream>>>(r_ws, F1f, fb1, fw2, fb2, (float*)d_out);
}

// Round 11
// 317.035 us; speedup vs baseline: 1.8112x; 1.0011x over previous
//
#include <hip/hip_runtime.h>

typedef __bf16 bf16;
typedef __bf16 bf16x8 __attribute__((ext_vector_type(8)));
typedef __bf16 bf16x4 __attribute__((ext_vector_type(4)));
typedef float  f32x4  __attribute__((ext_vector_type(4)));

#define BN_EPS 1e-5f
#define MFMA(a, b, c) __builtin_amdgcn_mfma_f32_16x16x32_bf16((a), (b), (c), 0, 0, 0)
#define BAR() do { __builtin_amdgcn_sched_barrier(0); \
                   asm volatile("s_waitcnt lgkmcnt(0)" ::: "memory"); \
                   __builtin_amdgcn_s_barrier(); \
                   __builtin_amdgcn_sched_barrier(0); } while (0)

// Fragment-linear offset for MFMA B-operand matrix [N][K] (16x16x32 tiles):
// tile = (k/32)*ntiles + n/16 ; within tile: lane = ((k%32)/8)*16 + n%16, elem = k%8
__device__ __host__ __forceinline__ size_t frag_off(int n, int k, int ntiles) {
  return ((size_t)((k >> 5) * ntiles + (n >> 4)) << 9)
       + (size_t)((((k >> 3) & 3) << 4) + (n & 15)) * 8 + (k & 7);
}

// ---------------- prep: all elementwise weight transforms in ONE kernel ----------------

__global__ __launch_bounds__(256)
void prep_all(const float* __restrict__ l1w, const float* __restrict__ l1g, const float* __restrict__ l1v,
              const float* __restrict__ g1w, const float* __restrict__ g1g, const float* __restrict__ g1v,
              const float* __restrict__ l2w, const float* __restrict__ l2b, const float* __restrict__ l2g,
              const float* __restrict__ l2be, const float* __restrict__ l2m, const float* __restrict__ l2v,
              const float* __restrict__ g2w, const float* __restrict__ g2b, const float* __restrict__ g2g,
              const float* __restrict__ g2be, const float* __restrict__ g2m, const float* __restrict__ g2v,
              const float* __restrict__ cw, const float* __restrict__ cb,
              const float* __restrict__ fw1,
              bf16* __restrict__ W1f, bf16* __restrict__ W2f, bf16* __restrict__ CWf,
              bf16* __restrict__ F1f, float* __restrict__ b2sum) {
  int gid = blockIdx.x * 256 + threadIdx.x;
  if (gid < 524288) {                       // W1f main
    int n = gid >> 10, k = gid & 1023;
    float s, w;
    if (n < 256) { s = l1g[n] * rsqrtf(l1v[n] + BN_EPS); w = l1w[(size_t)n * 1024 + k]; }
    else { int nn = n - 256; s = g1g[nn] * rsqrtf(g1v[nn] + BN_EPS); w = g1w[(size_t)nn * 1024 + k]; }
    W1f[frag_off(n, k, 32)] = (bf16)(w * s);
  } else if (gid < 1048576) {               // W2f + b2sum
    int g2 = gid - 524288;
    int n = g2 >> 9, k = g2 & 511;
    float w;
    if (k < 256) { float s = l2g[n] * rsqrtf(l2v[n] + BN_EPS); w = l2w[(size_t)n * 256 + k] * s; }
    else { float s = g2g[n] * rsqrtf(g2v[n] + BN_EPS); w = g2w[(size_t)n * 256 + (k - 256)] * s; }
    W2f[frag_off(n, k, 64)] = (bf16)w;
    if (k == 0) {
      float sl = l2g[n] * rsqrtf(l2v[n] + BN_EPS), sg = g2g[n] * rsqrtf(g2v[n] + BN_EPS);
      b2sum[n] = sl * (l2b[n] - l2m[n]) + l2be[n] + sg * (g2b[n] - g2m[n]) + g2be[n];
    }
  } else if (gid < 1114112) {               // CWf
    int g3 = gid - 1048576;
    int n = g3 >> 6, kc = g3 & 63;
    float v = (kc < 48) ? cw[(size_t)n * 48 + kc] : (kc == 48 ? cb[n] : 0.f);
    CWf[frag_off(n, kc, 64)] = (bf16)v;
  } else {                                  // F1f
    int g4 = gid - 1114112;
    int n = g4 >> 11, k = g4 & 2047;
    F1f[frag_off(n, k, 16)] = (bf16)fw1[(size_t)n * 2048 + k];
  }
}

__global__ __launch_bounds__(512)
void prep_w1tail(const float* __restrict__ l1w, const float* __restrict__ l1b, const float* __restrict__ l1g,
                 const float* __restrict__ l1be, const float* __restrict__ l1m, const float* __restrict__ l1v,
                 const float* __restrict__ g1w, const float* __restrict__ g1b, const float* __restrict__ g1g,
                 const float* __restrict__ g1be, const float* __restrict__ g1m, const float* __restrict__ g1v,
                 const float* __restrict__ cw, const float* __restrict__ cb,
                 bf16* __restrict__ W1f, float* __restrict__ b1cat) {
  int n = blockIdx.x;
  int kc = threadIdx.x & 63, js = threadIdx.x >> 6;
  const float* wrow; float s, bb, mm, be;
  if (n < 256) { s = l1g[n] * rsqrtf(l1v[n] + BN_EPS); wrow = l1w + (size_t)n * 1024;
                 bb = l1b[n]; mm = l1m[n]; be = l1be[n]; }
  else { int nn = n - 256; s = g1g[nn] * rsqrtf(g1v[nn] + BN_EPS); wrow = g1w + (size_t)nn * 1024;
         bb = g1b[nn]; mm = g1m[nn]; be = g1be[nn]; }
  float a = 0.f;
  if (kc < 49) {
    #pragma unroll 4
    for (int jj = 0; jj < 128; ++jj) {
      int j = js * 128 + jj;
      float cv = (kc < 48) ? cw[(size_t)j * 48 + kc] : cb[j];
      a += wrow[j] * cv;
    }
  }
  __shared__ float red[8][64];
  red[js][kc] = a;
  __syncthreads();
  if (threadIdx.x < 64) {
    float v = 0.f;
    #pragma unroll
    for (int r = 0; r < 8; ++r) v += red[r][threadIdx.x];
    W1f[frag_off(n, 1024 + threadIdx.x, 32)] = (bf16)((threadIdx.x < 49) ? v * s : 0.f);
  }
  if (threadIdx.x == 0) b1cat[n] = s * (bb - mm) + be;
}

// ---------------- K_e: e = bf16(name+typ) -> r_ws ; pure streaming ----------------

__global__ __launch_bounds__(256)
void ke(const float* __restrict__ name1, const float* __restrict__ type1,
        const float* __restrict__ name2, const float* __restrict__ type2,
        bf16* __restrict__ r_ws) {
  const int gid = blockIdx.x * 256 + threadIdx.x;   // 2048 * 256 = 524288 threads
  #pragma unroll 2
  for (int it = 0; it < 8; ++it) {
    int idx = it * 524288 + gid;          // 0 .. 4,194,303 vec8 slots
    int tt = idx >> 21;                   // uniform per it
    int r8 = idx & 2097151;
    int row = r8 >> 7, c8 = r8 & 127;
    const float* np = (tt ? name2 : name1) + (size_t)row * 1024 + c8 * 8;
    const float* tp = (tt ? type2 : type1) + (size_t)row * 1024 + c8 * 8;
    float4 n0 = *reinterpret_cast<const float4*>(np);
    float4 n1 = *reinterpret_cast<const float4*>(np + 4);
    float4 t0 = *reinterpret_cast<const float4*>(tp);
    float4 t1 = *reinterpret_cast<const float4*>(tp + 4);
    bf16x8 ev;
    ev[0] = (bf16)(n0.x + t0.x); ev[1] = (bf16)(n0.y + t0.y);
    ev[2] = (bf16)(n0.z + t0.z); ev[3] = (bf16)(n0.w + t0.w);
    ev[4] = (bf16)(n1.x + t1.x); ev[5] = (bf16)(n1.y + t1.y);
    ev[6] = (bf16)(n1.z + t1.z); ev[7] = (bf16)(n1.w + t1.w);
    *reinterpret_cast<bf16x8*>(r_ws + (size_t)row * 2048 + (size_t)tt * 1024 + c8 * 8) = ev;
  }
}

// ---------------- K0: gemm_c — c = [coor|1|0] @ CWfT, M=128 per block, write-stream bound ----------------

__global__ __launch_bounds__(512, 4)
void gemm_c(const float* __restrict__ coor1, const float* __restrict__ coor2,
            const bf16* __restrict__ CWf, bf16* __restrict__ c_ws) {
  const int bid = blockIdx.x;           // 256
  const int tt = bid >> 7, mb = bid & 127;
  const float* __restrict__ coor = tt ? coor2 : coor1;
  const int b0 = mb * 128;
  const int tid = threadIdx.x;
  const int lane = tid & 63;
  const int wv = tid >> 6;              // 0..7 : one 16-row m-tile each
  const int arow = lane & 15;
  const int q = lane >> 4;
  const int kgrp = q << 3;

  __shared__ __align__(16) bf16 hb[128][264];   // 67,584 B -> 2 blocks/CU

  const int row = wv * 16 + arow;
  bf16x8 ca0, ca1;
  {
    const float* cr = coor + (size_t)(b0 + row) * 48;
    float4 v0 = *reinterpret_cast<const float4*>(cr + kgrp);
    float4 v1 = *reinterpret_cast<const float4*>(cr + kgrp + 4);
    ca0[0] = (bf16)v0.x; ca0[1] = (bf16)v0.y; ca0[2] = (bf16)v0.z; ca0[3] = (bf16)v0.w;
    ca0[4] = (bf16)v1.x; ca0[5] = (bf16)v1.y; ca0[6] = (bf16)v1.z; ca0[7] = (bf16)v1.w;
    if (q < 2) {
      float4 w0 = *reinterpret_cast<const float4*>(cr + 32 + kgrp);
      float4 w1 = *reinterpret_cast<const float4*>(cr + 36 + kgrp);
      ca1[0] = (bf16)w0.x; ca1[1] = (bf16)w0.y; ca1[2] = (bf16)w0.z; ca1[3] = (bf16)w0.w;
      ca1[4] = (bf16)w1.x; ca1[5] = (bf16)w1.y; ca1[6] = (bf16)w1.z; ca1[7] = (bf16)w1.w;
    } else {
      #pragma unroll
      for (int e = 0; e < 8; ++e) ca1[e] = (bf16)0.f;
      if (q == 2) ca1[0] = (bf16)1.0f;   // col 48 = the bias column
    }
  }

  #pragma unroll 1
  for (int nc = 0; nc < 4; ++nc) {
    f32x4 cacc[16] = {};
    #pragma unroll
    for (int u = 0; u < 16; ++u) {
      int ntile = nc * 16 + u;
      bf16x8 b0f = *reinterpret_cast<const bf16x8*>(CWf + (((size_t)ntile) << 9) + lane * 8);
      bf16x8 b1f = *reinterpret_cast<const bf16x8*>(CWf + (((size_t)(64 + ntile)) << 9) + lane * 8);
      cacc[u] = MFMA(ca0, b0f, cacc[u]);
      cacc[u] = MFMA(ca1, b1f, cacc[u]);
    }
    #pragma unroll
    for (int u = 0; u < 16; ++u) {
      #pragma unroll
      for (int i = 0; i < 4; ++i)
        hb[wv * 16 + q * 4 + i][u * 16 + arow] = (bf16)cacc[u][i];
    }
    __syncthreads();
    #pragma unroll
    for (int g = 0; g < 8; ++g) {
      int idx = g * 512 + tid;
      int row2 = idx >> 5, cg = idx & 31;
      *reinterpret_cast<bf16x8*>(c_ws + ((size_t)tt * 16384 + b0 + row2) * 1024 + nc * 256 + cg * 8) =
        *reinterpret_cast<const bf16x8*>(&hb[row2][cg * 8]);
    }
    __syncthreads();
  }
}

// ---------------- K1: gemm1 — h = relu(e @ W1catT + b1cat); e read as bf16 from r_ws (L3-hot) ----------------
// M=128, N=256; 1024 thr; 17 phases of 64 k; depth-2 named-reg pipeline, raw barrier (no vmcnt drain).

__global__ __launch_bounds__(1024, 4)
void gemm1(const float* __restrict__ coor1, const float* __restrict__ coor2,
           const bf16* __restrict__ W1f, const float* __restrict__ b1cat,
           const bf16* __restrict__ e_ws, bf16* __restrict__ h_ws) {
  const int bid = blockIdx.x;
  const int xcd = bid & 7, slot = bid >> 3;
  const int nb = slot & 1;
  const int lg = xcd * 32 + (slot >> 1);   // 0..255 bijective
  const int tt = lg >> 7;
  const int mb = lg & 127;
  const float* __restrict__ coor = tt ? coor2 : coor1;
  const int b0 = mb * 128;
  const int tid = threadIdx.x;
  const int lane = tid & 63;
  const int wv = tid >> 6;           // 0..15
  const int wm = wv >> 2;            // 0..3: 32-row group
  const int wn = wv & 3;             // 0..3
  const int arow = lane & 15;
  const int q = lane >> 4;
  const int kgrp = q << 3;

  __shared__ __align__(16) char SM[67584];
  bf16 (*EB)[128][72] = reinterpret_cast<bf16 (*)[128][72]>(SM);   // 2 bufs x 18,432 B
  bf16 (*hb)[264] = reinterpret_cast<bf16 (*)[264]>(SM);           // overlay after k-loop

  const int srow = tid >> 3;         // 0..127
  const int scg = tid & 7;           // 16B chunk: cols scg*8..scg*8+7

  const bf16* ebase = e_ws + (size_t)b0 * 2048 + (size_t)tt * 1024 + (size_t)srow * 2048 + scg * 8;

  // two NAMED staging regs (rule #20): A = even phases (+tail 16), B = odd phases
  bf16x8 eA, eB;

  auto LOADE_A = [&](int pp) {
    if (pp < 16) {
      eA = *reinterpret_cast<const bf16x8*>(ebase + pp * 64);
    } else {                              // tail: [coor(48) | 1 | 0...]
      const float* cr = coor + (size_t)(b0 + srow) * 48;
      if (scg < 6) {
        float4 v0 = *reinterpret_cast<const float4*>(cr + scg * 8);
        float4 v1 = *reinterpret_cast<const float4*>(cr + scg * 8 + 4);
        eA[0] = (bf16)v0.x; eA[1] = (bf16)v0.y; eA[2] = (bf16)v0.z; eA[3] = (bf16)v0.w;
        eA[4] = (bf16)v1.x; eA[5] = (bf16)v1.y; eA[6] = (bf16)v1.z; eA[7] = (bf16)v1.w;
      } else {
        #pragma unroll
        for (int e = 0; e < 8; ++e) eA[e] = (bf16)0.f;
        if (scg == 6) eA[0] = (bf16)1.0f;   // col 48 = the bias column
      }
    }
  };
  auto LOADE_B = [&](int pp) {
    eB = *reinterpret_cast<const bf16x8*>(ebase + pp * 64);
  };
  auto WRITEE_A = [&](int buf) { *reinterpret_cast<bf16x8*>(&EB[buf][srow][scg * 8]) = eA; };
  auto WRITEE_B = [&](int buf) { *reinterpret_cast<bf16x8*>(&EB[buf][srow][scg * 8]) = eB; };

  f32x4 acc[2][4] = {};
  auto MFMA_PHASE = [&](int p, int buf) {
    #pragma unroll
    for (int ks2 = 0; ks2 < 2; ++ks2) {
      int kk = p * 2 + ks2;
      bf16x8 a0 = *reinterpret_cast<const bf16x8*>(&EB[buf][wm * 32 + arow][ks2 * 32 + kgrp]);
      bf16x8 a1 = *reinterpret_cast<const bf16x8*>(&EB[buf][wm * 32 + 16 + arow][ks2 * 32 + kgrp]);
      #pragma unroll
      for (int u = 0; u < 4; ++u) {
        bf16x8 b = *reinterpret_cast<const bf16x8*>(W1f + (((size_t)(kk * 32 + nb * 16 + wn * 4 + u)) << 9) + lane * 8);
        acc[0][u] = MFMA(a0, b, acc[0][u]);
        acc[1][u] = MFMA(a1, b, acc[1][u]);
      }
    }
  };

  // prologue: EB[0]=phase0 visible; B holds ph1; A holds ph2 (in flight)
  LOADE_A(0); LOADE_B(1);
  WRITEE_A(0);
  LOADE_A(2);
  BAR();

  #pragma unroll 1
  for (int j = 0; j < 8; ++j) {
    const int p0 = 2 * j;
    WRITEE_B(1);
    if (p0 + 3 < 16) LOADE_B(p0 + 3);
    MFMA_PHASE(p0, 0);
    BAR();                                   // EB[1] visible; loads stay in flight
    WRITEE_A(0);
    if (p0 + 4 <= 16) LOADE_A(p0 + 4);
    MFMA_PHASE(p0 + 1, 1);
    BAR();                                   // EB[0] visible (phase p0+2)
  }
  MFMA_PHASE(16, 0);                          // coor tail
  __syncthreads();                            // full drain before hb overlay

  // ---- h = relu(acc + b1cat) via LDS bounce, then coalesced store ----
  #pragma unroll
  for (int u = 0; u < 4; ++u) {
    int col = (wn * 4 + u) * 16 + arow;
    float bb = b1cat[nb * 256 + col];
    #pragma unroll
    for (int m = 0; m < 2; ++m) {
      #pragma unroll
      for (int i = 0; i < 4; ++i)
        hb[wm * 32 + m * 16 + q * 4 + i][col] = (bf16)fmaxf(acc[m][u][i] + bb, 0.f);
    }
  }
  __syncthreads();

  #pragma unroll
  for (int g = 0; g < 4; ++g) {
    int idx = g * 1024 + tid;
    int row = idx >> 5, cg = idx & 31;
    *reinterpret_cast<bf16x8*>(h_ws + ((size_t)tt * 16384 + b0 + row) * 512 + nb * 256 + cg * 8) =
      *reinterpret_cast<const bf16x8*>(&hb[row][cg * 8]);
  }
}

// ---------------- K2: gemm2 — wei = sigmoid(h@W2T+b2); r = 2e + 2*wei*(c-e) ----------------
// M=128, N=256; A-fragments DIRECT from global h_ws (L2-hot, XCD-co-located nb-quad); no k-loop barriers.

__global__ __launch_bounds__(512, 4)
void gemm2(const bf16* __restrict__ W2f, const float* __restrict__ b2sum,
           const bf16* __restrict__ h_ws, const bf16* __restrict__ c_ws, bf16* __restrict__ r_ws) {
  const int bid = blockIdx.x;            // 1024 blocks
  const int xcd = bid & 7, s = bid >> 3; // s: [tt(1)][nb(2)][mhi(4)]
  const int mb = xcd + 8 * (s & 15);     // nb-quad of one (mb,tt) shares an XCD
  const int nb = (s >> 4) & 3;           // 256-col quarter
  const int tt = s >> 6;
  const int b0 = mb * 128;
  const int tid = threadIdx.x;
  const int lane = tid & 63;
  const int wv = tid >> 6;               // 0..7
  const int wm = wv >> 1;                // 0..3: 32-row group
  const int wn2 = wv & 1;                // 0..1: 128-col half
  const int arow = lane & 15;
  const int q = lane >> 4;
  const int kgrp = q << 3;

  __shared__ __align__(16) float xs[128][132];   // 67,584 B -> 2 blocks/CU

  const bf16* hbase = h_ws + ((size_t)tt * 16384 + b0) * 512;
  const bf16* ha0 = hbase + (size_t)(wm * 32 + arow) * 512 + kgrp;
  const bf16* ha1 = hbase + (size_t)(wm * 32 + 16 + arow) * 512 + kgrp;

  f32x4 acc[2][8] = {};
  #pragma unroll 4
  for (int ks = 0; ks < 16; ++ks) {
    bf16x8 a0 = *reinterpret_cast<const bf16x8*>(ha0 + ks * 32);
    bf16x8 a1 = *reinterpret_cast<const bf16x8*>(ha1 + ks * 32);
    #pragma unroll
    for (int u = 0; u < 8; ++u) {
      bf16x8 b = *reinterpret_cast<const bf16x8*>(
          W2f + (((size_t)(ks * 64 + nb * 16 + wn2 * 8 + u)) << 9) + lane * 8);
      acc[0][u] = MFMA(a0, b, acc[0][u]);
      acc[1][u] = MFMA(a1, b, acc[1][u]);
    }
  }

  // ---- combine in two 128-col passes: xs = sigmoid(acc+b2) -> vectorized r ----
  #pragma unroll
  for (int hc = 0; hc < 2; ++hc) {
    if (wn2 == hc) {                         // wave-uniform
      #pragma unroll
      for (int u = 0; u < 8; ++u) {
        int lcol = u * 16 + arow;
        float b2 = b2sum[nb * 256 + hc * 128 + lcol];
        #pragma unroll
        for (int m = 0; m < 2; ++m) {
          #pragma unroll
          for (int i = 0; i < 4; ++i)
            xs[wm * 32 + m * 16 + q * 4 + i][lcol] = 1.f / (1.f + __expf(-(acc[m][u][i] + b2)));
        }
      }
    }
    __syncthreads();
    {
      int row = tid >> 2, sc = tid & 3;
      size_t ebase = (size_t)(b0 + row) * 2048 + (size_t)tt * 1024 + nb * 256 + hc * 128;
      size_t cbase = ((size_t)tt * 16384 + b0 + row) * 1024 + nb * 256 + hc * 128;
      #pragma unroll
      for (int g = 0; g < 4; ++g) {
        int c8 = g * 32 + sc * 8;
        bf16x8 ebv = *reinterpret_cast<const bf16x8*>(r_ws + ebase + c8);
        bf16x8 cv  = *reinterpret_cast<const bf16x8*>(c_ws + cbase + c8);
        f32x4 w0 = *reinterpret_cast<const f32x4*>(&xs[row][c8]);
        f32x4 w1 = *reinterpret_cast<const f32x4*>(&xs[row][c8 + 4]);
        bf16x8 rv;
        #pragma unroll
        for (int jj = 0; jj < 8; ++jj) {
          float e = (float)ebv[jj], c = (float)cv[jj];
          float w = (jj < 4) ? w0[jj] : w1[jj - 4];
          rv[jj] = (bf16)(2.f * (e + w * (c - e)));
        }
        *reinterpret_cast<bf16x8*>(r_ws + ebase + c8) = rv;
      }
    }
    __syncthreads();
  }
}

// ---------------- K3: final — out = sigmoid(relu(r@fw1T+fb1)@fw2T+fb2), M=64 ----------------

__global__ __launch_bounds__(512, 4)
void fused_final(const bf16* __restrict__ r_ws, const bf16* __restrict__ F1f,
                 const float* __restrict__ fb1, const float* __restrict__ fw2,
                 const float* __restrict__ fb2, float* __restrict__ out) {
  const int b0 = blockIdx.x * 64;
  const int tid = threadIdx.x;
  const int lane = tid & 63;
  const int wv = tid >> 6;
  const int arow = lane & 15;
  const int q    = lane >> 4;
  const int kgrp = q << 3;

  __shared__ bf16 RT[2][64][264];
  float (*H2)[260] = reinterpret_cast<float (*)[260]>(&RT[0][0][0]);

  bf16x8 sv[4];
  auto SLOAD = [&](int kc) {
    #pragma unroll
    for (int g = 0; g < 4; ++g) {
      int f = g * 512 + tid;
      int row = f >> 5, colg = f & 31;
      sv[g] = *reinterpret_cast<const bf16x8*>(r_ws + (size_t)(b0 + row) * 2048 + kc * 256 + colg * 8);
    }
  };
  auto SWRITE = [&](int buf) {
    #pragma unroll
    for (int g = 0; g < 4; ++g) {
      int f = g * 512 + tid;
      int row = f >> 5, colg = f & 31;
      *reinterpret_cast<bf16x8*>(&RT[buf][row][colg * 8]) = sv[g];
    }
  };

  SLOAD(0); SWRITE(0);
  __syncthreads();

  f32x4 acc[4][2] = {};
  #pragma unroll 1
  for (int kc = 0; kc < 8; ++kc) {
    if (kc < 7) SLOAD(kc + 1);
    #pragma unroll
    for (int ks = 0; ks < 8; ++ks) {
      int ksg = kc * 8 + ks;
      bf16x8 a[4];
      #pragma unroll
      for (int m = 0; m < 4; ++m)
        a[m] = *reinterpret_cast<const bf16x8*>(&RT[kc & 1][m * 16 + arow][ks * 32 + kgrp]);
      #pragma unroll
      for (int u = 0; u < 2; ++u) {
        bf16x8 b = *reinterpret_cast<const bf16x8*>(F1f + (((size_t)(ksg * 16 + wv * 2 + u)) << 9) + lane * 8);
        #pragma unroll
        for (int m = 0; m < 4; ++m)
          acc[m][u] = MFMA(a[m], b, acc[m][u]);
      }
    }
    if (kc < 7) SWRITE((kc + 1) & 1);
    __syncthreads();
  }

  #pragma unroll
  for (int u = 0; u < 2; ++u) {
    int col = (wv * 2 + u) * 16 + arow;
    float bb = fb1[col];
    #pragma unroll
    for (int m = 0; m < 4; ++m) {
      #pragma unroll
      for (int i2 = 0; i2 < 4; ++i2) {
        int row = m * 16 + q * 4 + i2;
        H2[row][col] = fmaxf(acc[m][u][i2] + bb, 0.f);
      }
    }
  }
  __syncthreads();

  int row = tid >> 3, sub = tid & 7;
  float p = 0.f;
  #pragma unroll
  for (int c = 0; c < 32; ++c) p += H2[row][sub * 32 + c] * fw2[sub * 32 + c];
  p += __shfl_xor(p, 1, 8);
  p += __shfl_xor(p, 2, 8);
  p += __shfl_xor(p, 4, 8);
  if (sub == 0) out[b0 + row] = 1.f / (1.f + __expf(-(p + fb2[0])));
}

// ---------------- launcher ----------------

extern "C" void kernel_launch(void* const* d_in, const int* in_sizes, int n_in,
                              void* d_out, int out_size, void* d_ws, size_t ws_size,
                              hipStream_t stream) {
  const float* name1 = (const float*)d_in[0];
  const float* type1 = (const float*)d_in[1];
  const float* coor1 = (const float*)d_in[2];
  const float* name2 = (const float*)d_in[3];
  const float* type2 = (const float*)d_in[4];
  const float* coor2 = (const float*)d_in[5];
  const float* cw    = (const float*)d_in[6];
  const float* cb    = (const float*)d_in[7];
  const float* l1w = (const float*)d_in[8];  const float* l1b = (const float*)d_in[9];
  const float* l1g = (const float*)d_in[10]; const float* l1be = (const float*)d_in[11];
  const float* l1m = (const float*)d_in[12]; const float* l1v = (const float*)d_in[13];
  const float* l2w = (const float*)d_in[14]; const float* l2b = (const float*)d_in[15];
  const float* l2g = (const float*)d_in[16]; const float* l2be = (const float*)d_in[17];
  const float* l2m = (const float*)d_in[18]; const float* l2v = (const float*)d_in[19];
  const float* g1w = (const float*)d_in[20]; const float* g1b = (const float*)d_in[21];
  const float* g1g = (const float*)d_in[22]; const float* g1be = (const float*)d_in[23];
  const float* g1m = (const float*)d_in[24]; const float* g1v = (const float*)d_in[25];
  const float* g2w = (const float*)d_in[26]; const float* g2b = (const float*)d_in[27];
  const float* g2g = (const float*)d_in[28]; const float* g2be = (const float*)d_in[29];
  const float* g2m = (const float*)d_in[30]; const float* g2v = (const float*)d_in[31];
  const float* fw1 = (const float*)d_in[32]; const float* fb1 = (const float*)d_in[33];
  const float* fw2 = (const float*)d_in[34]; const float* fb2 = (const float*)d_in[35];

  char* ws = (char*)d_ws;
  bf16*  W1f   = (bf16*)(ws + 0);          // 512*1088 bf16   = 1,114,112 B
  bf16*  W2f   = (bf16*)(ws + 1114112);    // 1024*512 bf16   = 1,048,576 B
  bf16*  CWf   = (bf16*)(ws + 2162688);    // 1024*64  bf16   =   131,072 B
  bf16*  F1f   = (bf16*)(ws + 2293760);    // 256*2048 bf16   = 1,048,576 B
  float* b1cat = (float*)(ws + 3342336);   // 512 f32
  float* b2sum = (float*)(ws + 3344384);   // 1024 f32
  bf16*  h_ws  = (bf16*)(ws + 3407872);    // [2][16384][512]  = 33,554,432 B
  bf16*  r_ws  = (bf16*)(ws + 36962304);   // [16384][2048]    = 67,108,864 B (holds e, then r)
  bf16*  c_ws  = (bf16*)(ws + 104071168);  // [2][16384][1024] = 67,108,864 B

  ke<<<2048, 256, 0, stream>>>(name1, type1, name2, type2, r_ws);
  prep_all<<<6400, 256, 0, stream>>>(l1w, l1g, l1v, g1w, g1g, g1v,
                                     l2w, l2b, l2g, l2be, l2m, l2v,
                                     g2w, g2b, g2g, g2be, g2m, g2v,
                                     cw, cb, fw1, W1f, W2f, CWf, F1f, b2sum);
  prep_w1tail<<<512, 512, 0, stream>>>(l1w, l1b, l1g, l1be, l1m, l1v,
                                       g1w, g1b, g1g, g1be, g1m, g1v, cw, cb, W1f, b1cat);

  gemm_c<<<256, 512, 0, stream>>>(coor1, coor2, CWf, c_ws);
  gemm1<<<512, 1024, 0, stream>>>(coor1, coor2, W1f, b1cat, r_ws, h_ws);
  gemm2<<<1024, 512, 0, stream>>>(W2f, b2sum, h_ws, c_ws, r_ws);
  fused_final<<<256, 512, 0, stream>>>(r_ws, F1f, fb1, fw2, fb2, (float*)d_out);
}